// Round 1
// baseline (1182.065 us; speedup 1.0000x reference)
//
#include <hip/hip_runtime.h>
#include <math.h>

// ---------------- helpers ----------------
__device__ __forceinline__ unsigned f2key(float f) {
    unsigned u = __float_as_uint(f);
    return (u & 0x80000000u) ? ~u : (u | 0x80000000u);
}
__device__ __forceinline__ float key2f(unsigned k) {
    unsigned u = (k & 0x80000000u) ? (k & 0x7fffffffu) : ~k;
    return __uint_as_float(u);
}

// ---------------- GEMM: C[M,N] = A[M,K] @ B[K,N] ----------------
// 64-row tile in LDS; each thread owns one column, NR rows.
// If score != nullptr: final-layer epilogue out = relu(tanh(score[r])*acc + bias[c]), write outN cols.
template<int K, int N>
__global__ __launch_bounds__(256) void gemm_tile(
    const float* __restrict__ A, const float* __restrict__ B,
    float* __restrict__ C, int M,
    const float* __restrict__ bias, const float* __restrict__ score, int outN)
{
    __shared__ float As[64 * K];
    const int tid = threadIdx.x;
    const int base = blockIdx.x * 64;
    for (int idx = tid; idx < 64 * K; idx += 256) {
        int r = idx / K, k = idx - r * K;
        int gr = base + r;
        As[idx] = (gr < M) ? A[(size_t)gr * K + k] : 0.f;
    }
    __syncthreads();
    constexpr int RSTEP = 256 / N;   // 256 % N == 0 required
    constexpr int NR = 64 / RSTEP;
    const int c = tid % N;
    const int r0 = tid / N;
    float acc[NR];
#pragma unroll
    for (int i = 0; i < NR; ++i) acc[i] = 0.f;
    const float4* As4 = reinterpret_cast<const float4*>(As);
    for (int k = 0; k < K; k += 4) {
        float b0 = B[(k + 0) * N + c];
        float b1 = B[(k + 1) * N + c];
        float b2 = B[(k + 2) * N + c];
        float b3 = B[(k + 3) * N + c];
#pragma unroll
        for (int i = 0; i < NR; ++i) {
            float4 a = As4[((r0 + i * RSTEP) * K + k) >> 2];
            acc[i] = fmaf(a.x, b0, acc[i]);
            acc[i] = fmaf(a.y, b1, acc[i]);
            acc[i] = fmaf(a.z, b2, acc[i]);
            acc[i] = fmaf(a.w, b3, acc[i]);
        }
    }
    if (score == nullptr) {
#pragma unroll
        for (int i = 0; i < NR; ++i) {
            int gr = base + r0 + i * RSTEP;
            if (gr < M) C[(size_t)gr * N + c] = acc[i];
        }
    } else {
        if (c < outN) {
#pragma unroll
            for (int i = 0; i < NR; ++i) {
                int gr = base + r0 + i * RSTEP;
                if (gr < M) {
                    float v = tanhf(score[gr]) * acc[i] + bias[c];
                    C[(size_t)gr * outN + c] = fmaxf(v, 0.f);
                }
            }
        }
    }
}

// ---------------- per-node dual dot: outa[i]=h[i].va, outb[i]=h[i].vb ----------------
template<int D>
__global__ __launch_bounds__(256) void node_dots(
    const float* __restrict__ h, const float* __restrict__ va, const float* __restrict__ vb,
    float* __restrict__ outa, float* __restrict__ outb, int n)
{
    int gthread = blockIdx.x * 256 + threadIdx.x;
    int node = gthread >> 6;
    int lane = threadIdx.x & 63;
    if (node >= n) return;
    float sa = 0.f, sb = 0.f;
#pragma unroll
    for (int f = lane; f < D; f += 64) {
        float hv = h[(size_t)node * D + f];
        sa += hv * va[f];
        sb += hv * vb[f];
    }
#pragma unroll
    for (int off = 32; off; off >>= 1) {
        sa += __shfl_xor(sa, off);
        sb += __shfl_xor(sb, off);
    }
    if (lane == 0) { outa[node] = sa; outb[node] = sb; }
}

// ---------------- per-layer init: out = bias row-broadcast; mkey=0; ssum=0 ----------------
__global__ __launch_bounds__(256) void init_layer(
    unsigned* __restrict__ mkey, float* __restrict__ ssum,
    float* __restrict__ outh, const float* __restrict__ b, int n, int D)
{
    long idx = (long)blockIdx.x * 256 + threadIdx.x;
    if (idx < (long)n * D) outh[idx] = b[idx % D];
    if (idx < n) { mkey[idx] = 0u; ssum[idx] = 0.f; }
}

// ---------------- edge pass 1: alpha = leaky_relu(as[src]+ad[dst]); atomic max into mkey[dst] ----------------
__global__ __launch_bounds__(256) void edge_alpha_max(
    const int* __restrict__ src, const int* __restrict__ dst,
    const float* __restrict__ asv, const float* __restrict__ adv,
    float* __restrict__ alpha, unsigned* __restrict__ mkey, int E, int n)
{
    int e = blockIdx.x * 256 + threadIdx.x;
    if (e >= E + n) return;
    int s_, d_;
    if (e < E) { s_ = src[e]; d_ = dst[e]; } else { s_ = d_ = e - E; }
    float a = asv[s_] + adv[d_];
    a = (a >= 0.f) ? a : 0.2f * a;
    alpha[e] = a;
    atomicMax(mkey + d_, f2key(a));
}

// ---------------- edge pass 2: e = exp(alpha - m[dst]); atomic sum into ssum[dst] ----------------
__global__ __launch_bounds__(256) void edge_expsum(
    const int* __restrict__ src, const int* __restrict__ dst,
    float* __restrict__ alpha, const unsigned* __restrict__ mkey,
    float* __restrict__ ssum, int E, int n)
{
    int e = blockIdx.x * 256 + threadIdx.x;
    if (e >= E + n) return;
    int d_ = (e < E) ? dst[e] : (e - E);
    float m = key2f(mkey[d_]);
    float ev = expf(alpha[e] - m);
    alpha[e] = ev;
    atomicAdd(ssum + d_, ev);
}

// ---------------- edge pass 3: out[dst] += h[src] * (e / (s[dst]+1e-16)) ----------------
template<int D>
__global__ __launch_bounds__(256) void edge_scatter(
    const int* __restrict__ src, const int* __restrict__ dst,
    const float* __restrict__ alpha, const float* __restrict__ ssum,
    const float* __restrict__ h, float* __restrict__ outh, int E, int n)
{
    long idx = (long)blockIdx.x * 256 + threadIdx.x;
    long tot = (long)(E + n) * D;
    if (idx >= tot) return;
    int e = (int)(idx / D);
    int f = (int)(idx - (long)e * D);
    int s_, d_;
    if (e < E) { s_ = src[e]; d_ = dst[e]; } else { s_ = d_ = e - E; }
    float coef = alpha[e] / (ssum[d_] + 1e-16f);
    atomicAdd(&outh[(size_t)d_ * D + f], h[(size_t)s_ * D + f] * coef);
}

// ---------------- relu in place ----------------
__global__ __launch_bounds__(256) void relu_k(float* __restrict__ p, long nelem)
{
    long i = (long)blockIdx.x * 256 + threadIdx.x;
    if (i < nelem) p[i] = fmaxf(p[i], 0.f);
}

// ---------------- pooling score ----------------
__global__ __launch_bounds__(256) void score_init(
    float* __restrict__ score, const float* __restrict__ rdot, const float* __restrict__ bp, int n)
{
    int i = blockIdx.x * 256 + threadIdx.x;
    if (i < n) score[i] = rdot[i] + bp[0];
}

__global__ __launch_bounds__(256) void score_edges(
    const int* __restrict__ src, const int* __restrict__ dst,
    const float* __restrict__ tdot, float* __restrict__ score, int E)
{
    int e = blockIdx.x * 256 + threadIdx.x;
    if (e < E) atomicAdd(score + dst[e], tdot[src[e]]);
}

// ---------------- pad Wl [128,10] -> [128,16], bl -> [16] ----------------
__global__ __launch_bounds__(256) void pad_wl(
    const float* __restrict__ Wl, const float* __restrict__ bl,
    float* __restrict__ Wlp, float* __restrict__ blp)
{
    int idx = blockIdx.x * 256 + threadIdx.x;
    if (idx < 128 * 16) {
        int k = idx >> 4, c = idx & 15;
        Wlp[idx] = (c < 10) ? Wl[k * 10 + c] : 0.f;
    }
    if (idx < 16) blp[idx] = (idx < 10) ? bl[idx] : 0.f;
}

extern "C" void kernel_launch(void* const* d_in, const int* in_sizes, int n_in,
                              void* d_out, int out_size, void* d_ws, size_t ws_size,
                              hipStream_t stream) {
    const float* x   = (const float*)d_in[0];
    const int*   ei  = (const int*)d_in[1];
    // d_in[2]=batch, d_in[3]=edge_attr: unused by reference
    const float* W1  = (const float*)d_in[4];
    const float* a1s = (const float*)d_in[5];
    const float* a1d = (const float*)d_in[6];
    const float* b1  = (const float*)d_in[7];
    const float* W2  = (const float*)d_in[8];
    const float* a2s = (const float*)d_in[9];
    const float* a2d = (const float*)d_in[10];
    const float* b2  = (const float*)d_in[11];
    const float* W3  = (const float*)d_in[12];
    const float* a3s = (const float*)d_in[13];
    const float* a3d = (const float*)d_in[14];
    const float* b3  = (const float*)d_in[15];
    const float* wpr = (const float*)d_in[16];
    const float* wpo = (const float*)d_in[17];
    const float* bp  = (const float*)d_in[18];
    const float* Wl  = (const float*)d_in[19];
    const float* bl  = (const float*)d_in[20];

    const int n = in_sizes[0] / 128;   // 40000
    const int E = in_sizes[1] / 2;     // 640000
    const int Esl = E + n;             // with self-loops
    const int* src = ei;
    const int* dst = ei + E;

    float* ws = (float*)d_ws;
    const size_t nd = (size_t)n * 128;
    float*    bufA  = ws;                       // [n,128] gemm output h
    float*    bufB  = bufA + nd;                // [n,128] aggregated output / next input
    float*    asv   = bufB + nd;                // [n]
    float*    adv   = asv + n;                  // [n]
    unsigned* mkey  = (unsigned*)(adv + n);     // [n]
    float*    ssum  = (float*)(mkey + n);       // [n]
    float*    score = ssum + n;                 // [n]
    float*    alpha = score + n;                // [E+n]
    float*    Wlp   = alpha + Esl;              // [128*16]
    float*    blp   = Wlp + 128 * 16;           // [16]

    const unsigned EB  = (unsigned)((Esl + 255) / 256);
    const unsigned MB  = (unsigned)((n + 63) / 64);

    // ---------- Layer 1: 128 -> 64 ----------
    gemm_tile<128, 64><<<MB, 256, 0, stream>>>(x, W1, bufA, n, nullptr, nullptr, 0);
    node_dots<64><<<(unsigned)(((size_t)n * 64 + 255) / 256), 256, 0, stream>>>(bufA, a1s, a1d, asv, adv, n);
    init_layer<<<(unsigned)(((size_t)n * 64 + 255) / 256), 256, 0, stream>>>(mkey, ssum, bufB, b1, n, 64);
    edge_alpha_max<<<EB, 256, 0, stream>>>(src, dst, asv, adv, alpha, mkey, E, n);
    edge_expsum<<<EB, 256, 0, stream>>>(src, dst, alpha, mkey, ssum, E, n);
    edge_scatter<64><<<(unsigned)(((size_t)Esl * 64 + 255) / 256), 256, 0, stream>>>(src, dst, alpha, ssum, bufA, bufB, E, n);
    relu_k<<<(unsigned)(((size_t)n * 64 + 255) / 256), 256, 0, stream>>>(bufB, (long)n * 64);

    // ---------- Layer 2: 64 -> 128 ----------
    gemm_tile<64, 128><<<MB, 256, 0, stream>>>(bufB, W2, bufA, n, nullptr, nullptr, 0);
    node_dots<128><<<(unsigned)(((size_t)n * 64 + 255) / 256), 256, 0, stream>>>(bufA, a2s, a2d, asv, adv, n);
    init_layer<<<(unsigned)((nd + 255) / 256), 256, 0, stream>>>(mkey, ssum, bufB, b2, n, 128);
    edge_alpha_max<<<EB, 256, 0, stream>>>(src, dst, asv, adv, alpha, mkey, E, n);
    edge_expsum<<<EB, 256, 0, stream>>>(src, dst, alpha, mkey, ssum, E, n);
    edge_scatter<128><<<(unsigned)(((size_t)Esl * 128 + 255) / 256), 256, 0, stream>>>(src, dst, alpha, ssum, bufA, bufB, E, n);
    relu_k<<<(unsigned)((nd + 255) / 256), 256, 0, stream>>>(bufB, (long)nd);

    // ---------- Layer 3: 128 -> 128 ----------
    gemm_tile<128, 128><<<MB, 256, 0, stream>>>(bufB, W3, bufA, n, nullptr, nullptr, 0);
    node_dots<128><<<(unsigned)(((size_t)n * 64 + 255) / 256), 256, 0, stream>>>(bufA, a3s, a3d, asv, adv, n);
    init_layer<<<(unsigned)((nd + 255) / 256), 256, 0, stream>>>(mkey, ssum, bufB, b3, n, 128);
    edge_alpha_max<<<EB, 256, 0, stream>>>(src, dst, asv, adv, alpha, mkey, E, n);
    edge_expsum<<<EB, 256, 0, stream>>>(src, dst, alpha, mkey, ssum, E, n);
    edge_scatter<128><<<(unsigned)(((size_t)Esl * 128 + 255) / 256), 256, 0, stream>>>(src, dst, alpha, ssum, bufA, bufB, E, n);
    relu_k<<<(unsigned)((nd + 255) / 256), 256, 0, stream>>>(bufB, (long)nd);

    // ---------- SAGPool score + final linear ----------
    // score = segsum(h[src].wp_rel) + h.wp_root + bp  (original edges only)
    node_dots<128><<<(unsigned)(((size_t)n * 64 + 255) / 256), 256, 0, stream>>>(bufB, wpr, wpo, asv, adv, n);
    score_init<<<(unsigned)((n + 255) / 256), 256, 0, stream>>>(score, adv, bp, n);
    score_edges<<<(unsigned)((E + 255) / 256), 256, 0, stream>>>(src, dst, asv, score, E);
    pad_wl<<<8, 256, 0, stream>>>(Wl, bl, Wlp, blp);
    // out = relu(tanh(score) * (h3 @ Wl) + bl)
    gemm_tile<128, 16><<<MB, 256, 0, stream>>>(bufB, Wlp, (float*)d_out, n, blp, score, 10);
}

// Round 3
// 509.342 us; speedup vs baseline: 2.3208x; 2.3208x over previous
//
#include <hip/hip_runtime.h>
#include <math.h>

// ---------------- GEMM: C[M,N] = A[M,K] @ B[K,N] ----------------
// 64-row tile in LDS; each thread owns one column, NR rows.
// If score != nullptr: final-layer epilogue out = relu(tanh(score[r])*acc + bias[c]), write outN cols.
template<int K, int N>
__global__ __launch_bounds__(256) void gemm_tile(
    const float* __restrict__ A, const float* __restrict__ B,
    float* __restrict__ C, int M,
    const float* __restrict__ bias, const float* __restrict__ score, int outN)
{
    __shared__ float As[64 * K];
    const int tid = threadIdx.x;
    const int base = blockIdx.x * 64;
    for (int idx = tid; idx < 64 * K; idx += 256) {
        int r = idx / K, k = idx - r * K;
        int gr = base + r;
        As[idx] = (gr < M) ? A[(size_t)gr * K + k] : 0.f;
    }
    __syncthreads();
    constexpr int RSTEP = 256 / N;   // 256 % N == 0 required
    constexpr int NR = 64 / RSTEP;
    const int c = tid % N;
    const int r0 = tid / N;
    float acc[NR];
#pragma unroll
    for (int i = 0; i < NR; ++i) acc[i] = 0.f;
    const float4* As4 = reinterpret_cast<const float4*>(As);
    for (int k = 0; k < K; k += 4) {
        float b0 = B[(k + 0) * N + c];
        float b1 = B[(k + 1) * N + c];
        float b2 = B[(k + 2) * N + c];
        float b3 = B[(k + 3) * N + c];
#pragma unroll
        for (int i = 0; i < NR; ++i) {
            float4 a = As4[((r0 + i * RSTEP) * K + k) >> 2];
            acc[i] = fmaf(a.x, b0, acc[i]);
            acc[i] = fmaf(a.y, b1, acc[i]);
            acc[i] = fmaf(a.z, b2, acc[i]);
            acc[i] = fmaf(a.w, b3, acc[i]);
        }
    }
    if (score == nullptr) {
#pragma unroll
        for (int i = 0; i < NR; ++i) {
            int gr = base + r0 + i * RSTEP;
            if (gr < M) C[(size_t)gr * N + c] = acc[i];
        }
    } else {
        if (c < outN) {
#pragma unroll
            for (int i = 0; i < NR; ++i) {
                int gr = base + r0 + i * RSTEP;
                if (gr < M) {
                    float v = tanhf(score[gr]) * acc[i] + bias[c];
                    C[(size_t)gr * outN + c] = fmaxf(v, 0.f);
                }
            }
        }
    }
}

// ---------------- per-node dual dot: outa[i]=h[i].va, outb[i]=h[i].vb ----------------
template<int D>
__global__ __launch_bounds__(256) void node_dots(
    const float* __restrict__ h, const float* __restrict__ va, const float* __restrict__ vb,
    float* __restrict__ outa, float* __restrict__ outb, int n)
{
    int gthread = blockIdx.x * 256 + threadIdx.x;
    int node = gthread >> 6;
    int lane = threadIdx.x & 63;
    if (node >= n) return;
    float sa = 0.f, sb = 0.f;
#pragma unroll
    for (int f = lane; f < D; f += 64) {
        float hv = h[(size_t)node * D + f];
        sa += hv * va[f];
        sb += hv * vb[f];
    }
#pragma unroll
    for (int off = 32; off; off >>= 1) {
        sa += __shfl_xor(sa, off);
        sb += __shfl_xor(sb, off);
    }
    if (lane == 0) { outa[node] = sa; outb[node] = sb; }
}

// ---------------- CSR build ----------------
__global__ __launch_bounds__(256) void zero_deg(int* __restrict__ deg, int n)
{
    int i = blockIdx.x * 256 + threadIdx.x;
    if (i < n) deg[i] = 0;
}

__global__ __launch_bounds__(256) void hist_deg(
    const int* __restrict__ dst, int* __restrict__ deg, int E, int n)
{
    int e = blockIdx.x * 256 + threadIdx.x;
    if (e >= E + n) return;
    int d = (e < E) ? dst[e] : (e - E);
    atomicAdd(deg + d, 1);
}

// one block of 1024 threads: exclusive scan of deg[n] -> row_start[n+1], cursor[n]
__global__ __launch_bounds__(1024) void scan_deg(
    const int* __restrict__ deg, int* __restrict__ row_start, int* __restrict__ cursor, int n)
{
    __shared__ int part[1024];
    const int t = threadIdx.x;
    const int chunk = (n + 1023) / 1024;
    const int lo = t * chunk;
    const int hi = min(n, lo + chunk);
    int mysum = 0;
    for (int i = lo; i < hi; ++i) mysum += deg[i];
    part[t] = mysum;
    __syncthreads();
    for (int off = 1; off < 1024; off <<= 1) {
        int v = (t >= off) ? part[t - off] : 0;
        __syncthreads();
        part[t] += v;
        __syncthreads();
    }
    int base = part[t] - mysum;  // exclusive prefix
    for (int i = lo; i < hi; ++i) {
        row_start[i] = base;
        cursor[i] = base;
        base += deg[i];
    }
    if (t == 1023) row_start[n] = part[1023];
}

__global__ __launch_bounds__(256) void fill_csr(
    const int* __restrict__ src, const int* __restrict__ dst,
    int* __restrict__ cursor, int* __restrict__ csr_src, int E, int n)
{
    int e = blockIdx.x * 256 + threadIdx.x;
    if (e >= E + n) return;
    int s, d;
    if (e < E) { s = src[e]; d = dst[e]; } else { s = d = e - E; }
    int pos = atomicAdd(cursor + d, 1);
    csr_src[pos] = s;
}

// ---------------- fused GAT aggregation: one wave per node ----------------
// out[i] = relu( sum_e softmax_e(leaky(asv[src]+adv[i])) * h[src] + bias )
template<int D>
__global__ __launch_bounds__(256) void gat_aggregate(
    const int* __restrict__ row_start, const int* __restrict__ csr_src,
    const float* __restrict__ asv, const float* __restrict__ adv,
    const float* __restrict__ h, const float* __restrict__ bias,
    float* __restrict__ out, int n)
{
    __shared__ float lds[4][128];
    const int node = (blockIdx.x * 256 + threadIdx.x) >> 6;
    const int lane = threadIdx.x & 63;
    const int w = threadIdx.x >> 6;
    if (node >= n) return;
    const int beg = row_start[node];
    const int deg = row_start[node + 1] - beg;
    const float advv = adv[node];
    const bool fast = (deg <= 128);

    // pass 1: max alpha
    float amax = -INFINITY;
    for (int j = lane; j < deg; j += 64) {
        float a = asv[csr_src[beg + j]] + advv;
        a = (a >= 0.f) ? a : 0.2f * a;
        amax = fmaxf(amax, a);
    }
#pragma unroll
    for (int off = 32; off; off >>= 1) amax = fmaxf(amax, __shfl_xor(amax, off));

    // pass 2: exp + sum (cache exp in LDS when deg<=128)
    float ssum = 0.f;
    for (int j = lane; j < deg; j += 64) {
        float a = asv[csr_src[beg + j]] + advv;
        a = (a >= 0.f) ? a : 0.2f * a;
        float ev = expf(a - amax);
        if (fast) lds[w][j] = ev;
        ssum += ev;
    }
#pragma unroll
    for (int off = 32; off; off >>= 1) ssum += __shfl_xor(ssum, off);
    const float inv = 1.f / (ssum + 1e-16f);

    // pass 3: weighted gather
    if constexpr (D == 128) {
        const float2* h2 = reinterpret_cast<const float2*>(h);
        float2 acc = {0.f, 0.f};
        for (int j = 0; j < deg; ++j) {
            int s = csr_src[beg + j];
            float coef;
            if (fast) coef = lds[w][j] * inv;
            else {
                float a = asv[s] + advv;
                a = (a >= 0.f) ? a : 0.2f * a;
                coef = expf(a - amax) * inv;
            }
            float2 hv = h2[(size_t)s * 64 + lane];
            acc.x = fmaf(hv.x, coef, acc.x);
            acc.y = fmaf(hv.y, coef, acc.y);
        }
        float2 o;
        o.x = fmaxf(acc.x + bias[2 * lane], 0.f);
        o.y = fmaxf(acc.y + bias[2 * lane + 1], 0.f);
        reinterpret_cast<float2*>(out)[(size_t)node * 64 + lane] = o;
    } else {
        float acc = 0.f;
        for (int j = 0; j < deg; ++j) {
            int s = csr_src[beg + j];
            float coef;
            if (fast) coef = lds[w][j] * inv;
            else {
                float a = asv[s] + advv;
                a = (a >= 0.f) ? a : 0.2f * a;
                coef = expf(a - amax) * inv;
            }
            acc = fmaf(h[(size_t)s * D + lane], coef, acc);
        }
        out[(size_t)node * D + lane] = fmaxf(acc + bias[lane], 0.f);
    }
}

// ---------------- pooling score via CSR (original edges only: subtract self-loop) ----------------
__global__ __launch_bounds__(256) void score_csr(
    const int* __restrict__ row_start, const int* __restrict__ csr_src,
    const float* __restrict__ ts, const float* __restrict__ td,
    const float* __restrict__ bp, float* __restrict__ score, int n)
{
    int i = blockIdx.x * 256 + threadIdx.x;
    if (i >= n) return;
    int beg = row_start[i], end = row_start[i + 1];
    float s = td[i] + bp[0] - ts[i];  // appended self-loop is not an original edge
    for (int j = beg; j < end; ++j) s += ts[csr_src[j]];
    score[i] = s;
}

// ---------------- pad Wl [128,10] -> [128,16], bl -> [16] ----------------
__global__ __launch_bounds__(256) void pad_wl(
    const float* __restrict__ Wl, const float* __restrict__ bl,
    float* __restrict__ Wlp, float* __restrict__ blp)
{
    int idx = blockIdx.x * 256 + threadIdx.x;
    if (idx < 128 * 16) {
        int k = idx >> 4, c = idx & 15;
        Wlp[idx] = (c < 10) ? Wl[k * 10 + c] : 0.f;
    }
    if (idx < 16) blp[idx] = (idx < 10) ? bl[idx] : 0.f;
}

extern "C" void kernel_launch(void* const* d_in, const int* in_sizes, int n_in,
                              void* d_out, int out_size, void* d_ws, size_t ws_size,
                              hipStream_t stream) {
    const float* x   = (const float*)d_in[0];
    const int*   ei  = (const int*)d_in[1];
    const float* W1  = (const float*)d_in[4];
    const float* a1s = (const float*)d_in[5];
    const float* a1d = (const float*)d_in[6];
    const float* b1  = (const float*)d_in[7];
    const float* W2  = (const float*)d_in[8];
    const float* a2s = (const float*)d_in[9];
    const float* a2d = (const float*)d_in[10];
    const float* b2  = (const float*)d_in[11];
    const float* W3  = (const float*)d_in[12];
    const float* a3s = (const float*)d_in[13];
    const float* a3d = (const float*)d_in[14];
    const float* b3  = (const float*)d_in[15];
    const float* wpr = (const float*)d_in[16];
    const float* wpo = (const float*)d_in[17];
    const float* bp  = (const float*)d_in[18];
    const float* Wl  = (const float*)d_in[19];
    const float* bl  = (const float*)d_in[20];

    const int n = in_sizes[0] / 128;   // 40000
    const int E = in_sizes[1] / 2;     // 640000
    const int Esl = E + n;
    const int* src = ei;
    const int* dst = ei + E;

    float* ws = (float*)d_ws;
    const size_t nd = (size_t)n * 128;
    float* bufA      = ws;                          // [n,128]
    float* bufB      = bufA + nd;                   // [n,128]
    float* asv       = bufB + nd;                   // [n]
    float* adv       = asv + n;                     // [n]
    float* score     = adv + n;                     // [n]
    int*   deg       = (int*)(score + n);           // [n]
    int*   row_start = deg + n;                     // [n+1]
    int*   cursor    = row_start + n + 1;           // [n]
    int*   csr_src   = cursor + n;                  // [Esl]
    float* Wlp       = (float*)(csr_src + Esl);     // [128*16]
    float* blp       = Wlp + 128 * 16;              // [16]

    const unsigned EB = (unsigned)((Esl + 255) / 256);
    const unsigned NB = (unsigned)((n + 255) / 256);
    const unsigned MB = (unsigned)((n + 63) / 64);
    const unsigned WB = (unsigned)(((size_t)n * 64 + 255) / 256);  // wave-per-node grids

    // ---------- CSR build (reused by all layers + score) ----------
    zero_deg<<<NB, 256, 0, stream>>>(deg, n);
    hist_deg<<<EB, 256, 0, stream>>>(dst, deg, E, n);
    scan_deg<<<1, 1024, 0, stream>>>(deg, row_start, cursor, n);
    fill_csr<<<EB, 256, 0, stream>>>(src, dst, cursor, csr_src, E, n);

    // ---------- Layer 1: 128 -> 64 ----------
    gemm_tile<128, 64><<<MB, 256, 0, stream>>>(x, W1, bufA, n, nullptr, nullptr, 0);
    node_dots<64><<<WB, 256, 0, stream>>>(bufA, a1s, a1d, asv, adv, n);
    gat_aggregate<64><<<WB, 256, 0, stream>>>(row_start, csr_src, asv, adv, bufA, b1, bufB, n);

    // ---------- Layer 2: 64 -> 128 ----------
    gemm_tile<64, 128><<<MB, 256, 0, stream>>>(bufB, W2, bufA, n, nullptr, nullptr, 0);
    node_dots<128><<<WB, 256, 0, stream>>>(bufA, a2s, a2d, asv, adv, n);
    gat_aggregate<128><<<WB, 256, 0, stream>>>(row_start, csr_src, asv, adv, bufA, b2, bufB, n);

    // ---------- Layer 3: 128 -> 128 ----------
    gemm_tile<128, 128><<<MB, 256, 0, stream>>>(bufB, W3, bufA, n, nullptr, nullptr, 0);
    node_dots<128><<<WB, 256, 0, stream>>>(bufA, a3s, a3d, asv, adv, n);
    gat_aggregate<128><<<WB, 256, 0, stream>>>(row_start, csr_src, asv, adv, bufA, b3, bufB, n);

    // ---------- SAGPool score + final linear ----------
    node_dots<128><<<WB, 256, 0, stream>>>(bufB, wpr, wpo, asv, adv, n);
    score_csr<<<NB, 256, 0, stream>>>(row_start, csr_src, asv, adv, bp, score, n);
    pad_wl<<<8, 256, 0, stream>>>(Wl, bl, Wlp, blp);
    gemm_tile<128, 16><<<MB, 256, 0, stream>>>(bufB, Wlp, (float*)d_out, n, blp, score, 10);
}

// Round 4
// 428.729 us; speedup vs baseline: 2.7571x; 1.1880x over previous
//
#include <hip/hip_runtime.h>
#include <math.h>

// ---------------- GEMM: C[M,N] = A[M,K] @ B[K,N] ----------------
template<int K, int N>
__global__ __launch_bounds__(256) void gemm_tile(
    const float* __restrict__ A, const float* __restrict__ B,
    float* __restrict__ C, int M,
    const float* __restrict__ bias, const float* __restrict__ score, int outN)
{
    __shared__ float As[64 * K];
    const int tid = threadIdx.x;
    const int base = blockIdx.x * 64;
    for (int idx = tid; idx < 64 * K; idx += 256) {
        int r = idx / K, k = idx - r * K;
        int gr = base + r;
        As[idx] = (gr < M) ? A[(size_t)gr * K + k] : 0.f;
    }
    __syncthreads();
    constexpr int RSTEP = 256 / N;   // 256 % N == 0 required
    constexpr int NR = 64 / RSTEP;
    const int c = tid % N;
    const int r0 = tid / N;
    float acc[NR];
#pragma unroll
    for (int i = 0; i < NR; ++i) acc[i] = 0.f;
    const float4* As4 = reinterpret_cast<const float4*>(As);
    for (int k = 0; k < K; k += 4) {
        float b0 = B[(k + 0) * N + c];
        float b1 = B[(k + 1) * N + c];
        float b2 = B[(k + 2) * N + c];
        float b3 = B[(k + 3) * N + c];
#pragma unroll
        for (int i = 0; i < NR; ++i) {
            float4 a = As4[((r0 + i * RSTEP) * K + k) >> 2];
            acc[i] = fmaf(a.x, b0, acc[i]);
            acc[i] = fmaf(a.y, b1, acc[i]);
            acc[i] = fmaf(a.z, b2, acc[i]);
            acc[i] = fmaf(a.w, b3, acc[i]);
        }
    }
    if (score == nullptr) {
#pragma unroll
        for (int i = 0; i < NR; ++i) {
            int gr = base + r0 + i * RSTEP;
            if (gr < M) C[(size_t)gr * N + c] = acc[i];
        }
    } else {
        if (c < outN) {
#pragma unroll
            for (int i = 0; i < NR; ++i) {
                int gr = base + r0 + i * RSTEP;
                if (gr < M) {
                    float v = tanhf(score[gr]) * acc[i] + bias[c];
                    C[(size_t)gr * outN + c] = fmaxf(v, 0.f);
                }
            }
        }
    }
}

// ---------------- per-node dual dot: outa[i]=h[i].va, outb[i]=h[i].vb ----------------
template<int D>
__global__ __launch_bounds__(256) void node_dots(
    const float* __restrict__ h, const float* __restrict__ va, const float* __restrict__ vb,
    float* __restrict__ outa, float* __restrict__ outb, int n)
{
    int gthread = blockIdx.x * 256 + threadIdx.x;
    int node = gthread >> 6;
    int lane = threadIdx.x & 63;
    if (node >= n) return;
    float sa = 0.f, sb = 0.f;
#pragma unroll
    for (int f = lane; f < D; f += 64) {
        float hv = h[(size_t)node * D + f];
        sa += hv * va[f];
        sb += hv * vb[f];
    }
#pragma unroll
    for (int off = 32; off; off >>= 1) {
        sa += __shfl_xor(sa, off);
        sb += __shfl_xor(sb, off);
    }
    if (lane == 0) { outa[node] = sa; outb[node] = sb; }
}

// ---------------- CSR build ----------------
__global__ __launch_bounds__(256) void zero_deg(int* __restrict__ deg, int n)
{
    int i = blockIdx.x * 256 + threadIdx.x;
    if (i < n) deg[i] = 0;
}

__global__ __launch_bounds__(256) void hist_deg(
    const int* __restrict__ dst, int* __restrict__ deg, int E, int n)
{
    int e = blockIdx.x * 256 + threadIdx.x;
    if (e >= E + n) return;
    int d = (e < E) ? dst[e] : (e - E);
    atomicAdd(deg + d, 1);
}

// ---------------- hierarchical scan: local -> blocksums -> add ----------------
// pass A: per-block LDS scan; row_start[i] = local exclusive prefix; blocksum[b] = block total
__global__ __launch_bounds__(256) void scan_local(
    const int* __restrict__ deg, int* __restrict__ row_start, int* __restrict__ blocksum, int n)
{
    __shared__ int s[256];
    const int t = threadIdx.x;
    const int i = blockIdx.x * 256 + t;
    int v = (i < n) ? deg[i] : 0;
    s[t] = v;
    __syncthreads();
#pragma unroll
    for (int off = 1; off < 256; off <<= 1) {
        int u = (t >= off) ? s[t - off] : 0;
        __syncthreads();
        s[t] += u;
        __syncthreads();
    }
    if (i < n) row_start[i] = s[t] - v;          // exclusive (local)
    if (t == 255) blocksum[blockIdx.x] = s[255];
}

// pass B: one block scans blocksums (nb <= 256) in place -> exclusive offsets
__global__ __launch_bounds__(256) void scan_blocks(int* __restrict__ blocksum, int nb)
{
    __shared__ int s[256];
    const int t = threadIdx.x;
    int v = (t < nb) ? blocksum[t] : 0;
    s[t] = v;
    __syncthreads();
#pragma unroll
    for (int off = 1; off < 256; off <<= 1) {
        int u = (t >= off) ? s[t - off] : 0;
        __syncthreads();
        s[t] += u;
        __syncthreads();
    }
    if (t < nb) blocksum[t] = s[t] - v;          // exclusive
}

// pass C: add block offset; fill cursor; row_start[n] = total (known = E+n)
__global__ __launch_bounds__(256) void scan_add(
    int* __restrict__ row_start, int* __restrict__ cursor,
    const int* __restrict__ blocksum, int n, int total)
{
    const int i = blockIdx.x * 256 + threadIdx.x;
    if (i < n) {
        int v = row_start[i] + blocksum[blockIdx.x];
        row_start[i] = v;
        cursor[i] = v;
    } else if (i == n) {
        row_start[n] = total;
    }
}

__global__ __launch_bounds__(256) void fill_csr(
    const int* __restrict__ src, const int* __restrict__ dst,
    int* __restrict__ cursor, int* __restrict__ csr_src, int E, int n)
{
    int e = blockIdx.x * 256 + threadIdx.x;
    if (e >= E + n) return;
    int s, d;
    if (e < E) { s = src[e]; d = dst[e]; } else { s = d = e - E; }
    int pos = atomicAdd(cursor + d, 1);
    csr_src[pos] = s;
}

// ---------------- fused GAT aggregation: one wave per node ----------------
template<int D>
__global__ __launch_bounds__(256) void gat_aggregate(
    const int* __restrict__ row_start, const int* __restrict__ csr_src,
    const float* __restrict__ asv, const float* __restrict__ adv,
    const float* __restrict__ h, const float* __restrict__ bias,
    float* __restrict__ out, int n)
{
    __shared__ float lds[4][128];
    const int node = (blockIdx.x * 256 + threadIdx.x) >> 6;
    const int lane = threadIdx.x & 63;
    const int w = threadIdx.x >> 6;
    if (node >= n) return;
    const int beg = row_start[node];
    const int deg = row_start[node + 1] - beg;
    const float advv = adv[node];
    const bool fast = (deg <= 128);

    // pass 1: max alpha
    float amax = -INFINITY;
    for (int j = lane; j < deg; j += 64) {
        float a = asv[csr_src[beg + j]] + advv;
        a = (a >= 0.f) ? a : 0.2f * a;
        amax = fmaxf(amax, a);
    }
#pragma unroll
    for (int off = 32; off; off >>= 1) amax = fmaxf(amax, __shfl_xor(amax, off));

    // pass 2: exp + sum (cache exp in LDS when deg<=128)
    float ssum = 0.f;
    for (int j = lane; j < deg; j += 64) {
        float a = asv[csr_src[beg + j]] + advv;
        a = (a >= 0.f) ? a : 0.2f * a;
        float ev = expf(a - amax);
        if (fast) lds[w][j] = ev;
        ssum += ev;
    }
#pragma unroll
    for (int off = 32; off; off >>= 1) ssum += __shfl_xor(ssum, off);
    const float inv = 1.f / (ssum + 1e-16f);

    // pass 3: weighted gather
    if constexpr (D == 128) {
        const float2* h2 = reinterpret_cast<const float2*>(h);
        float2 acc = {0.f, 0.f};
        for (int j = 0; j < deg; ++j) {
            int s = csr_src[beg + j];
            float coef;
            if (fast) coef = lds[w][j] * inv;
            else {
                float a = asv[s] + advv;
                a = (a >= 0.f) ? a : 0.2f * a;
                coef = expf(a - amax) * inv;
            }
            float2 hv = h2[(size_t)s * 64 + lane];
            acc.x = fmaf(hv.x, coef, acc.x);
            acc.y = fmaf(hv.y, coef, acc.y);
        }
        float2 o;
        o.x = fmaxf(acc.x + bias[2 * lane], 0.f);
        o.y = fmaxf(acc.y + bias[2 * lane + 1], 0.f);
        reinterpret_cast<float2*>(out)[(size_t)node * 64 + lane] = o;
    } else {
        float acc = 0.f;
        for (int j = 0; j < deg; ++j) {
            int s = csr_src[beg + j];
            float coef;
            if (fast) coef = lds[w][j] * inv;
            else {
                float a = asv[s] + advv;
                a = (a >= 0.f) ? a : 0.2f * a;
                coef = expf(a - amax) * inv;
            }
            acc = fmaf(h[(size_t)s * D + lane], coef, acc);
        }
        out[(size_t)node * D + lane] = fmaxf(acc + bias[lane], 0.f);
    }
}

// ---------------- pooling score via CSR (original edges only: subtract self-loop) ----------------
__global__ __launch_bounds__(256) void score_csr(
    const int* __restrict__ row_start, const int* __restrict__ csr_src,
    const float* __restrict__ ts, const float* __restrict__ td,
    const float* __restrict__ bp, float* __restrict__ score, int n)
{
    int i = blockIdx.x * 256 + threadIdx.x;
    if (i >= n) return;
    int beg = row_start[i], end = row_start[i + 1];
    float s = td[i] + bp[0] - ts[i];  // appended self-loop is not an original edge
    for (int j = beg; j < end; ++j) s += ts[csr_src[j]];
    score[i] = s;
}

// ---------------- pad Wl [128,10] -> [128,16], bl -> [16] ----------------
__global__ __launch_bounds__(256) void pad_wl(
    const float* __restrict__ Wl, const float* __restrict__ bl,
    float* __restrict__ Wlp, float* __restrict__ blp)
{
    int idx = blockIdx.x * 256 + threadIdx.x;
    if (idx < 128 * 16) {
        int k = idx >> 4, c = idx & 15;
        Wlp[idx] = (c < 10) ? Wl[k * 10 + c] : 0.f;
    }
    if (idx < 16) blp[idx] = (idx < 10) ? bl[idx] : 0.f;
}

extern "C" void kernel_launch(void* const* d_in, const int* in_sizes, int n_in,
                              void* d_out, int out_size, void* d_ws, size_t ws_size,
                              hipStream_t stream) {
    const float* x   = (const float*)d_in[0];
    const int*   ei  = (const int*)d_in[1];
    const float* W1  = (const float*)d_in[4];
    const float* a1s = (const float*)d_in[5];
    const float* a1d = (const float*)d_in[6];
    const float* b1  = (const float*)d_in[7];
    const float* W2  = (const float*)d_in[8];
    const float* a2s = (const float*)d_in[9];
    const float* a2d = (const float*)d_in[10];
    const float* b2  = (const float*)d_in[11];
    const float* W3  = (const float*)d_in[12];
    const float* a3s = (const float*)d_in[13];
    const float* a3d = (const float*)d_in[14];
    const float* b3  = (const float*)d_in[15];
    const float* wpr = (const float*)d_in[16];
    const float* wpo = (const float*)d_in[17];
    const float* bp  = (const float*)d_in[18];
    const float* Wl  = (const float*)d_in[19];
    const float* bl  = (const float*)d_in[20];

    const int n = in_sizes[0] / 128;   // 40000
    const int E = in_sizes[1] / 2;     // 640000
    const int Esl = E + n;
    const int* src = ei;
    const int* dst = ei + E;

    float* ws = (float*)d_ws;
    const size_t nd = (size_t)n * 128;
    float* bufA      = ws;                          // [n,128]
    float* bufB      = bufA + nd;                   // [n,128]
    float* asv       = bufB + nd;                   // [n]
    float* adv       = asv + n;                     // [n]
    float* score     = adv + n;                     // [n]
    int*   deg       = (int*)(score + n);           // [n]
    int*   row_start = deg + n;                     // [n+1]
    int*   cursor    = row_start + n + 1;           // [n]
    int*   blocksum  = cursor + n;                  // [<=256]
    int*   csr_src   = blocksum + 256;              // [Esl]
    float* Wlp       = (float*)(csr_src + Esl);     // [128*16]
    float* blp       = Wlp + 128 * 16;              // [16]

    const unsigned EB = (unsigned)((Esl + 255) / 256);
    const unsigned NB = (unsigned)((n + 255) / 256);        // 157
    const unsigned MB = (unsigned)((n + 63) / 64);
    const unsigned WB = (unsigned)(((size_t)n * 64 + 255) / 256);  // wave-per-node grids

    // ---------- CSR build (reused by all layers + score) ----------
    zero_deg<<<NB, 256, 0, stream>>>(deg, n);
    hist_deg<<<EB, 256, 0, stream>>>(dst, deg, E, n);
    scan_local<<<NB, 256, 0, stream>>>(deg, row_start, blocksum, n);
    scan_blocks<<<1, 256, 0, stream>>>(blocksum, (int)NB);
    scan_add<<<NB, 256, 0, stream>>>(row_start, cursor, blocksum, n, Esl);
    fill_csr<<<EB, 256, 0, stream>>>(src, dst, cursor, csr_src, E, n);

    // ---------- Layer 1: 128 -> 64 ----------
    gemm_tile<128, 64><<<MB, 256, 0, stream>>>(x, W1, bufA, n, nullptr, nullptr, 0);
    node_dots<64><<<WB, 256, 0, stream>>>(bufA, a1s, a1d, asv, adv, n);
    gat_aggregate<64><<<WB, 256, 0, stream>>>(row_start, csr_src, asv, adv, bufA, b1, bufB, n);

    // ---------- Layer 2: 64 -> 128 ----------
    gemm_tile<64, 128><<<MB, 256, 0, stream>>>(bufB, W2, bufA, n, nullptr, nullptr, 0);
    node_dots<128><<<WB, 256, 0, stream>>>(bufA, a2s, a2d, asv, adv, n);
    gat_aggregate<128><<<WB, 256, 0, stream>>>(row_start, csr_src, asv, adv, bufA, b2, bufB, n);

    // ---------- Layer 3: 128 -> 128 ----------
    gemm_tile<128, 128><<<MB, 256, 0, stream>>>(bufB, W3, bufA, n, nullptr, nullptr, 0);
    node_dots<128><<<WB, 256, 0, stream>>>(bufA, a3s, a3d, asv, adv, n);
    gat_aggregate<128><<<WB, 256, 0, stream>>>(row_start, csr_src, asv, adv, bufA, b3, bufB, n);

    // ---------- SAGPool score + final linear ----------
    node_dots<128><<<WB, 256, 0, stream>>>(bufB, wpr, wpo, asv, adv, n);
    score_csr<<<NB, 256, 0, stream>>>(row_start, csr_src, asv, adv, bp, score, n);
    pad_wl<<<8, 256, 0, stream>>>(Wl, bl, Wlp, blp);
    gemm_tile<128, 16><<<MB, 256, 0, stream>>>(bufB, Wlp, (float*)d_out, n, blp, score, 10);
}

// Round 5
// 366.580 us; speedup vs baseline: 3.2246x; 1.1695x over previous
//
#include <hip/hip_runtime.h>
#include <math.h>

// ---------------- GEMM: C[M,N] = A[M,K] @ B[K,N] ----------------
// 64-row tile in LDS; each thread owns one column, NR rows.
// score != nullptr: final-layer epilogue out = relu(tanh(score[r])*acc + bias[c]), outN cols.
// va != nullptr: also emit outa[r] = A_row . va, outb[r] = A_row . vb  (attention dots,
//   using va = W @ a_src so that (A@W).a == A.va — computed from the LDS A tile).
template<int K, int N>
__global__ __launch_bounds__(256) void gemm_tile(
    const float* __restrict__ A, const float* __restrict__ B,
    float* __restrict__ C, int M,
    const float* __restrict__ bias, const float* __restrict__ score, int outN,
    const float* __restrict__ va, const float* __restrict__ vb,
    float* __restrict__ outa, float* __restrict__ outb)
{
    __shared__ float As[64 * K];
    const int tid = threadIdx.x;
    const int base = blockIdx.x * 64;
    for (int idx = tid; idx < 64 * K; idx += 256) {
        int r = idx / K, k = idx - r * K;
        int gr = base + r;
        As[idx] = (gr < M) ? A[(size_t)gr * K + k] : 0.f;
    }
    __syncthreads();
    constexpr int RSTEP = 256 / N;   // 256 % N == 0 required
    constexpr int NR = 64 / RSTEP;
    const int c = tid % N;
    const int r0 = tid / N;
    float acc[NR];
#pragma unroll
    for (int i = 0; i < NR; ++i) acc[i] = 0.f;
    const float4* As4 = reinterpret_cast<const float4*>(As);
    for (int k = 0; k < K; k += 4) {
        float b0 = B[(k + 0) * N + c];
        float b1 = B[(k + 1) * N + c];
        float b2 = B[(k + 2) * N + c];
        float b3 = B[(k + 3) * N + c];
#pragma unroll
        for (int i = 0; i < NR; ++i) {
            float4 a = As4[((r0 + i * RSTEP) * K + k) >> 2];
            acc[i] = fmaf(a.x, b0, acc[i]);
            acc[i] = fmaf(a.y, b1, acc[i]);
            acc[i] = fmaf(a.z, b2, acc[i]);
            acc[i] = fmaf(a.w, b3, acc[i]);
        }
    }
    if (score == nullptr) {
#pragma unroll
        for (int i = 0; i < NR; ++i) {
            int gr = base + r0 + i * RSTEP;
            if (gr < M) C[(size_t)gr * N + c] = acc[i];
        }
    } else {
        if (c < outN) {
#pragma unroll
            for (int i = 0; i < NR; ++i) {
                int gr = base + r0 + i * RSTEP;
                if (gr < M) {
                    float v = tanhf(score[gr]) * acc[i] + bias[c];
                    C[(size_t)gr * outN + c] = fmaxf(v, 0.f);
                }
            }
        }
    }
    // fused attention dots: wave w reduces rows w*16..w*16+15 of the LDS tile
    if (va != nullptr) {
        const int w = tid >> 6;
        const int lane = tid & 63;
        for (int rr = 0; rr < 16; ++rr) {
            int r = w * 16 + rr;
            int gr = base + r;
            if (gr < M) {
                float sa = 0.f, sb = 0.f;
#pragma unroll
                for (int k = lane; k < K; k += 64) {
                    float av = As[r * K + k];
                    sa = fmaf(av, va[k], sa);
                    sb = fmaf(av, vb[k], sb);
                }
#pragma unroll
                for (int off = 32; off; off >>= 1) {
                    sa += __shfl_xor(sa, off);
                    sb += __shfl_xor(sb, off);
                }
                if (lane == 0) { outa[gr] = sa; outb[gr] = sb; }
            }
        }
    }
}

// ---------------- CSR build ----------------
__global__ __launch_bounds__(256) void zero_deg(int* __restrict__ deg, int n)
{
    int i = blockIdx.x * 256 + threadIdx.x;
    if (i < n) deg[i] = 0;
}

__global__ __launch_bounds__(256) void hist_deg(
    const int* __restrict__ dst, int* __restrict__ deg, int E, int n)
{
    int e = blockIdx.x * 256 + threadIdx.x;
    if (e >= E + n) return;
    int d = (e < E) ? dst[e] : (e - E);
    atomicAdd(deg + d, 1);
}

__global__ __launch_bounds__(256) void scan_local(
    const int* __restrict__ deg, int* __restrict__ row_start, int* __restrict__ blocksum, int n)
{
    __shared__ int s[256];
    const int t = threadIdx.x;
    const int i = blockIdx.x * 256 + t;
    int v = (i < n) ? deg[i] : 0;
    s[t] = v;
    __syncthreads();
#pragma unroll
    for (int off = 1; off < 256; off <<= 1) {
        int u = (t >= off) ? s[t - off] : 0;
        __syncthreads();
        s[t] += u;
        __syncthreads();
    }
    if (i < n) row_start[i] = s[t] - v;
    if (t == 255) blocksum[blockIdx.x] = s[255];
}

__global__ __launch_bounds__(256) void scan_blocks(int* __restrict__ blocksum, int nb)
{
    __shared__ int s[256];
    const int t = threadIdx.x;
    int v = (t < nb) ? blocksum[t] : 0;
    s[t] = v;
    __syncthreads();
#pragma unroll
    for (int off = 1; off < 256; off <<= 1) {
        int u = (t >= off) ? s[t - off] : 0;
        __syncthreads();
        s[t] += u;
        __syncthreads();
    }
    if (t < nb) blocksum[t] = s[t] - v;
}

__global__ __launch_bounds__(256) void scan_add(
    int* __restrict__ row_start, int* __restrict__ cursor,
    const int* __restrict__ blocksum, int n, int total)
{
    const int i = blockIdx.x * 256 + threadIdx.x;
    if (i < n) {
        int v = row_start[i] + blocksum[blockIdx.x];
        row_start[i] = v;
        cursor[i] = v;
    } else if (i == n) {
        row_start[n] = total;
    }
}

__global__ __launch_bounds__(256) void fill_csr(
    const int* __restrict__ src, const int* __restrict__ dst,
    int* __restrict__ cursor, int* __restrict__ csr_src, int E, int n)
{
    int e = blockIdx.x * 256 + threadIdx.x;
    if (e >= E + n) return;
    int s, d;
    if (e < E) { s = src[e]; d = dst[e]; } else { s = d = e - E; }
    int pos = atomicAdd(cursor + d, 1);
    csr_src[pos] = s;
}

// ---------------- fused GAT aggregation: one wave per node ----------------
// out[i] = relu( sum_e softmax_e(leaky(asv[src]+adv[i])) * h[src] + bias )
// POOL: also emit poolA[i] = out_row . wpr, poolB[i] = out_row . wpo
template<int D, bool POOL>
__global__ __launch_bounds__(256) void gat_aggregate(
    const int* __restrict__ row_start, const int* __restrict__ csr_src,
    const float* __restrict__ asv, const float* __restrict__ adv,
    const float* __restrict__ h, const float* __restrict__ bias,
    float* __restrict__ out,
    const float* __restrict__ wpr, const float* __restrict__ wpo,
    float* __restrict__ poolA, float* __restrict__ poolB, int n)
{
    __shared__ float lds_e[4][128];
    __shared__ int   lds_i[4][128];
    const int node = (blockIdx.x * 256 + threadIdx.x) >> 6;
    const int lane = threadIdx.x & 63;
    const int w = threadIdx.x >> 6;
    if (node >= n) return;
    const int beg = row_start[node];
    const int deg = row_start[node + 1] - beg;
    const float advv = adv[node];
    const bool fast = (deg <= 128);

    // pass 1: stage indices + alpha in LDS, running max
    float amax = -INFINITY;
    if (fast) {
        for (int j = lane; j < deg; j += 64) {
            int s = csr_src[beg + j];
            lds_i[w][j] = s;
            float a = asv[s] + advv;
            a = (a >= 0.f) ? a : 0.2f * a;
            lds_e[w][j] = a;
            amax = fmaxf(amax, a);
        }
    } else {
        for (int j = lane; j < deg; j += 64) {
            float a = asv[csr_src[beg + j]] + advv;
            a = (a >= 0.f) ? a : 0.2f * a;
            amax = fmaxf(amax, a);
        }
    }
#pragma unroll
    for (int off = 32; off; off >>= 1) amax = fmaxf(amax, __shfl_xor(amax, off));

    // pass 2: exp + sum
    float ssum = 0.f;
    if (fast) {
        for (int j = lane; j < deg; j += 64) {
            float ev = expf(lds_e[w][j] - amax);
            lds_e[w][j] = ev;
            ssum += ev;
        }
    } else {
        for (int j = lane; j < deg; j += 64) {
            float a = asv[csr_src[beg + j]] + advv;
            a = (a >= 0.f) ? a : 0.2f * a;
            ssum += expf(a - amax);
        }
    }
#pragma unroll
    for (int off = 32; off; off >>= 1) ssum += __shfl_xor(ssum, off);
    const float inv = 1.f / (ssum + 1e-16f);

    // pass 3: weighted gather, 4-deep MLP
    if constexpr (D == 128) {
        const float2* h2 = reinterpret_cast<const float2*>(h);
        float2 a0 = {0.f, 0.f}, a1 = {0.f, 0.f}, a2 = {0.f, 0.f}, a3 = {0.f, 0.f};
        int j = 0;
        if (fast) {
            for (; j + 4 <= deg; j += 4) {
                int s0 = lds_i[w][j], s1 = lds_i[w][j + 1], s2 = lds_i[w][j + 2], s3 = lds_i[w][j + 3];
                float c0 = lds_e[w][j] * inv, c1 = lds_e[w][j + 1] * inv;
                float c2 = lds_e[w][j + 2] * inv, c3 = lds_e[w][j + 3] * inv;
                float2 v0 = h2[(size_t)s0 * 64 + lane];
                float2 v1 = h2[(size_t)s1 * 64 + lane];
                float2 v2 = h2[(size_t)s2 * 64 + lane];
                float2 v3 = h2[(size_t)s3 * 64 + lane];
                a0.x = fmaf(v0.x, c0, a0.x); a0.y = fmaf(v0.y, c0, a0.y);
                a1.x = fmaf(v1.x, c1, a1.x); a1.y = fmaf(v1.y, c1, a1.y);
                a2.x = fmaf(v2.x, c2, a2.x); a2.y = fmaf(v2.y, c2, a2.y);
                a3.x = fmaf(v3.x, c3, a3.x); a3.y = fmaf(v3.y, c3, a3.y);
            }
            for (; j < deg; ++j) {
                int s = lds_i[w][j];
                float c = lds_e[w][j] * inv;
                float2 v = h2[(size_t)s * 64 + lane];
                a0.x = fmaf(v.x, c, a0.x); a0.y = fmaf(v.y, c, a0.y);
            }
        } else {
            for (; j < deg; ++j) {
                int s = csr_src[beg + j];
                float a = asv[s] + advv;
                a = (a >= 0.f) ? a : 0.2f * a;
                float c = expf(a - amax) * inv;
                float2 v = h2[(size_t)s * 64 + lane];
                a0.x = fmaf(v.x, c, a0.x); a0.y = fmaf(v.y, c, a0.y);
            }
        }
        float2 o;
        o.x = fmaxf(((a0.x + a1.x) + (a2.x + a3.x)) + bias[2 * lane], 0.f);
        o.y = fmaxf(((a0.y + a1.y) + (a2.y + a3.y)) + bias[2 * lane + 1], 0.f);
        reinterpret_cast<float2*>(out)[(size_t)node * 64 + lane] = o;
        if constexpr (POOL) {
            float pa = fmaf(o.x, wpr[2 * lane], o.y * wpr[2 * lane + 1]);
            float pb = fmaf(o.x, wpo[2 * lane], o.y * wpo[2 * lane + 1]);
#pragma unroll
            for (int off = 32; off; off >>= 1) {
                pa += __shfl_xor(pa, off);
                pb += __shfl_xor(pb, off);
            }
            if (lane == 0) { poolA[node] = pa; poolB[node] = pb; }
        }
    } else {
        float a0 = 0.f, a1 = 0.f, a2 = 0.f, a3 = 0.f;
        int j = 0;
        if (fast) {
            for (; j + 4 <= deg; j += 4) {
                int s0 = lds_i[w][j], s1 = lds_i[w][j + 1], s2 = lds_i[w][j + 2], s3 = lds_i[w][j + 3];
                float c0 = lds_e[w][j] * inv, c1 = lds_e[w][j + 1] * inv;
                float c2 = lds_e[w][j + 2] * inv, c3 = lds_e[w][j + 3] * inv;
                a0 = fmaf(h[(size_t)s0 * D + lane], c0, a0);
                a1 = fmaf(h[(size_t)s1 * D + lane], c1, a1);
                a2 = fmaf(h[(size_t)s2 * D + lane], c2, a2);
                a3 = fmaf(h[(size_t)s3 * D + lane], c3, a3);
            }
            for (; j < deg; ++j) {
                a0 = fmaf(h[(size_t)lds_i[w][j] * D + lane], lds_e[w][j] * inv, a0);
            }
        } else {
            for (; j < deg; ++j) {
                int s = csr_src[beg + j];
                float a = asv[s] + advv;
                a = (a >= 0.f) ? a : 0.2f * a;
                float c = expf(a - amax) * inv;
                a0 = fmaf(h[(size_t)s * D + lane], c, a0);
            }
        }
        out[(size_t)node * D + lane] = fmaxf(((a0 + a1) + (a2 + a3)) + bias[lane], 0.f);
    }
}

// ---------------- pooling score via CSR (original edges only: subtract self-loop) ----------------
__global__ __launch_bounds__(256) void score_csr(
    const int* __restrict__ row_start, const int* __restrict__ csr_src,
    const float* __restrict__ ts, const float* __restrict__ td,
    const float* __restrict__ bp, float* __restrict__ score, int n)
{
    int i = blockIdx.x * 256 + threadIdx.x;
    if (i >= n) return;
    int beg = row_start[i], end = row_start[i + 1];
    float s = td[i] + bp[0] - ts[i];  // appended self-loop is not an original edge
    for (int j = beg; j < end; ++j) s += ts[csr_src[j]];
    score[i] = s;
}

// ---------------- precompute: va_l = W_l @ a_ls, vb_l = W_l @ a_ld; pad Wl/bl ----------------
__global__ __launch_bounds__(256) void precompute(
    const float* __restrict__ W1, const float* __restrict__ a1s, const float* __restrict__ a1d,
    const float* __restrict__ W2, const float* __restrict__ a2s, const float* __restrict__ a2d,
    const float* __restrict__ W3, const float* __restrict__ a3s, const float* __restrict__ a3d,
    const float* __restrict__ Wl, const float* __restrict__ bl,
    float* __restrict__ va1, float* __restrict__ vb1,
    float* __restrict__ va2, float* __restrict__ vb2,
    float* __restrict__ va3, float* __restrict__ vb3,
    float* __restrict__ Wlp, float* __restrict__ blp)
{
    int t = blockIdx.x * 256 + threadIdx.x;
    if (t < 128) {
        float sa = 0.f, sb = 0.f;
        for (int j = 0; j < 64; ++j) {
            float w = W1[t * 64 + j];
            sa = fmaf(w, a1s[j], sa); sb = fmaf(w, a1d[j], sb);
        }
        va1[t] = sa; vb1[t] = sb;
    } else if (t < 192) {
        int k = t - 128;
        float sa = 0.f, sb = 0.f;
        for (int j = 0; j < 128; ++j) {
            float w = W2[k * 128 + j];
            sa = fmaf(w, a2s[j], sa); sb = fmaf(w, a2d[j], sb);
        }
        va2[k] = sa; vb2[k] = sb;
    } else if (t < 320) {
        int k = t - 192;
        float sa = 0.f, sb = 0.f;
        for (int j = 0; j < 128; ++j) {
            float w = W3[k * 128 + j];
            sa = fmaf(w, a3s[j], sa); sb = fmaf(w, a3d[j], sb);
        }
        va3[k] = sa; vb3[k] = sb;
    } else if (t < 320 + 2048) {
        int i = t - 320;
        int k = i >> 4, c = i & 15;
        Wlp[i] = (c < 10) ? Wl[k * 10 + c] : 0.f;
    } else if (t < 320 + 2048 + 16) {
        int c = t - (320 + 2048);
        blp[c] = (c < 10) ? bl[c] : 0.f;
    }
}

extern "C" void kernel_launch(void* const* d_in, const int* in_sizes, int n_in,
                              void* d_out, int out_size, void* d_ws, size_t ws_size,
                              hipStream_t stream) {
    const float* x   = (const float*)d_in[0];
    const int*   ei  = (const int*)d_in[1];
    const float* W1  = (const float*)d_in[4];
    const float* a1s = (const float*)d_in[5];
    const float* a1d = (const float*)d_in[6];
    const float* b1  = (const float*)d_in[7];
    const float* W2  = (const float*)d_in[8];
    const float* a2s = (const float*)d_in[9];
    const float* a2d = (const float*)d_in[10];
    const float* b2  = (const float*)d_in[11];
    const float* W3  = (const float*)d_in[12];
    const float* a3s = (const float*)d_in[13];
    const float* a3d = (const float*)d_in[14];
    const float* b3  = (const float*)d_in[15];
    const float* wpr = (const float*)d_in[16];
    const float* wpo = (const float*)d_in[17];
    const float* bp  = (const float*)d_in[18];
    const float* Wl  = (const float*)d_in[19];
    const float* bl  = (const float*)d_in[20];

    const int n = in_sizes[0] / 128;   // 40000
    const int E = in_sizes[1] / 2;     // 640000
    const int Esl = E + n;
    const int* src = ei;
    const int* dst = ei + E;

    float* ws = (float*)d_ws;
    const size_t nd = (size_t)n * 128;
    float* bufA      = ws;                          // [n,128]
    float* bufB      = bufA + nd;                   // [n,128]
    float* asv       = bufB + nd;                   // [n]
    float* adv       = asv + n;                     // [n]
    float* tsv       = adv + n;                     // [n] pooled dots (separate from asv: read/write race)
    float* tdv       = tsv + n;                     // [n]
    float* score     = tdv + n;                     // [n]
    int*   deg       = (int*)(score + n);           // [n]
    int*   row_start = deg + n;                     // [n+1]
    int*   cursor    = row_start + n + 1;           // [n]
    int*   blocksum  = cursor + n;                  // [<=256]
    int*   csr_src   = blocksum + 256;              // [Esl]
    float* va1       = (float*)(csr_src + Esl);     // [128]
    float* vb1       = va1 + 128;                   // [128]
    float* va2       = vb1 + 128;                   // [64]
    float* vb2       = va2 + 64;                    // [64]
    float* va3       = vb2 + 64;                    // [128]
    float* vb3       = va3 + 128;                   // [128]
    float* Wlp       = vb3 + 128;                   // [128*16]
    float* blp       = Wlp + 128 * 16;              // [16]

    const unsigned EB = (unsigned)((Esl + 255) / 256);
    const unsigned NB = (unsigned)((n + 255) / 256);
    const unsigned MB = (unsigned)((n + 63) / 64);
    const unsigned WB = (unsigned)(((size_t)n * 64 + 255) / 256);

    // ---------- precompute + CSR build ----------
    precompute<<<10, 256, 0, stream>>>(W1, a1s, a1d, W2, a2s, a2d, W3, a3s, a3d, Wl, bl,
                                       va1, vb1, va2, vb2, va3, vb3, Wlp, blp);
    zero_deg<<<NB, 256, 0, stream>>>(deg, n);
    hist_deg<<<EB, 256, 0, stream>>>(dst, deg, E, n);
    scan_local<<<NB, 256, 0, stream>>>(deg, row_start, blocksum, n);
    scan_blocks<<<1, 256, 0, stream>>>(blocksum, (int)NB);
    scan_add<<<NB, 256, 0, stream>>>(row_start, cursor, blocksum, n, Esl);
    fill_csr<<<EB, 256, 0, stream>>>(src, dst, cursor, csr_src, E, n);

    // ---------- Layer 1: 128 -> 64 ----------
    gemm_tile<128, 64><<<MB, 256, 0, stream>>>(x, W1, bufA, n, nullptr, nullptr, 0, va1, vb1, asv, adv);
    gat_aggregate<64, false><<<WB, 256, 0, stream>>>(row_start, csr_src, asv, adv, bufA, b1, bufB,
                                                     nullptr, nullptr, nullptr, nullptr, n);

    // ---------- Layer 2: 64 -> 128 ----------
    gemm_tile<64, 128><<<MB, 256, 0, stream>>>(bufB, W2, bufA, n, nullptr, nullptr, 0, va2, vb2, asv, adv);
    gat_aggregate<128, false><<<WB, 256, 0, stream>>>(row_start, csr_src, asv, adv, bufA, b2, bufB,
                                                      nullptr, nullptr, nullptr, nullptr, n);

    // ---------- Layer 3: 128 -> 128 (+ fused pooling dots) ----------
    gemm_tile<128, 128><<<MB, 256, 0, stream>>>(bufB, W3, bufA, n, nullptr, nullptr, 0, va3, vb3, asv, adv);
    gat_aggregate<128, true><<<WB, 256, 0, stream>>>(row_start, csr_src, asv, adv, bufA, b3, bufB,
                                                     wpr, wpo, tsv, tdv, n);

    // ---------- SAGPool score + final linear ----------
    score_csr<<<NB, 256, 0, stream>>>(row_start, csr_src, tsv, tdv, bp, score, n);
    gemm_tile<128, 16><<<MB, 256, 0, stream>>>(bufB, Wlp, (float*)d_out, n, blp, score, 10,
                                               nullptr, nullptr, nullptr, nullptr);
}

// Round 6
// 353.881 us; speedup vs baseline: 3.3403x; 1.0359x over previous
//
#include <hip/hip_runtime.h>
#include <math.h>

// ---------------- GEMM: C[M,N] = A[M,K] @ B[K,N] ----------------
// 64-row tile in LDS; col-tiled across gridDim.y (NT cols per block).
// Per-thread: NR rows x 1 col, B loads software-pipelined one k-chunk ahead.
// score != nullptr: epilogue out = relu(tanh(score[r])*acc + bias[c]), outN cols.
// va != nullptr (y==0 only): outa[r] = A_row.va, outb[r] = A_row.vb from the LDS tile.
template<int K, int N, int NT>
__global__ __launch_bounds__(256) void gemm_tile(
    const float* __restrict__ A, const float* __restrict__ B,
    float* __restrict__ C, int M,
    const float* __restrict__ bias, const float* __restrict__ score, int outN,
    const float* __restrict__ va, const float* __restrict__ vb,
    float* __restrict__ outa, float* __restrict__ outb)
{
    static_assert(256 % NT == 0, "NT must divide 256");
    __shared__ float As[64 * K];
    const int tid = threadIdx.x;
    const int base = blockIdx.x * 64;
    for (int idx = tid; idx < 64 * K; idx += 256) {
        int r = idx / K, k = idx - r * K;
        int gr = base + r;
        As[idx] = (gr < M) ? A[(size_t)gr * K + k] : 0.f;
    }
    __syncthreads();
    constexpr int RSTEP = 256 / NT;
    constexpr int NR = 64 / RSTEP;
    const int c = tid % NT;
    const int r0 = tid / NT;
    const int col = blockIdx.y * NT + c;
    float acc[NR];
#pragma unroll
    for (int i = 0; i < NR; ++i) acc[i] = 0.f;
    const float4* As4 = reinterpret_cast<const float4*>(As);
    const float* Bc = B + col;
    float b0 = Bc[0 * N], b1 = Bc[1 * N], b2 = Bc[2 * N], b3 = Bc[3 * N];
    for (int k = 0; k < K; k += 4) {
        const int kn = (k + 4 < K) ? (k + 4) : k;   // last iter: dummy reload
        float n0 = Bc[(kn + 0) * N];
        float n1 = Bc[(kn + 1) * N];
        float n2 = Bc[(kn + 2) * N];
        float n3 = Bc[(kn + 3) * N];
#pragma unroll
        for (int i = 0; i < NR; ++i) {
            float4 a = As4[((r0 + i * RSTEP) * K + k) >> 2];
            acc[i] = fmaf(a.x, b0, acc[i]);
            acc[i] = fmaf(a.y, b1, acc[i]);
            acc[i] = fmaf(a.z, b2, acc[i]);
            acc[i] = fmaf(a.w, b3, acc[i]);
        }
        b0 = n0; b1 = n1; b2 = n2; b3 = n3;
    }
    if (score == nullptr) {
#pragma unroll
        for (int i = 0; i < NR; ++i) {
            int gr = base + r0 + i * RSTEP;
            if (gr < M) C[(size_t)gr * N + col] = acc[i];
        }
    } else {
        if (col < outN) {
#pragma unroll
            for (int i = 0; i < NR; ++i) {
                int gr = base + r0 + i * RSTEP;
                if (gr < M) {
                    float v = tanhf(score[gr]) * acc[i] + bias[col];
                    C[(size_t)gr * outN + col] = fmaxf(v, 0.f);
                }
            }
        }
    }
    // fused attention dots (one col-block only): wave w reduces rows w*16..w*16+15
    if (va != nullptr && blockIdx.y == 0) {
        const int w = tid >> 6;
        const int lane = tid & 63;
        for (int rr = 0; rr < 16; ++rr) {
            int r = w * 16 + rr;
            int gr = base + r;
            if (gr < M) {
                float sa = 0.f, sb = 0.f;
#pragma unroll
                for (int k = lane; k < K; k += 64) {
                    float av = As[r * K + k];
                    sa = fmaf(av, va[k], sa);
                    sb = fmaf(av, vb[k], sb);
                }
#pragma unroll
                for (int off = 32; off; off >>= 1) {
                    sa += __shfl_xor(sa, off);
                    sb += __shfl_xor(sb, off);
                }
                if (lane == 0) { outa[gr] = sa; outb[gr] = sb; }
            }
        }
    }
}

// ---------------- CSR build ----------------
__global__ __launch_bounds__(256) void hist_deg(
    const int* __restrict__ dst, int* __restrict__ deg, int E, int n)
{
    int e = blockIdx.x * 256 + threadIdx.x;
    if (e >= E + n) return;
    int d = (e < E) ? dst[e] : (e - E);
    atomicAdd(deg + d, 1);
}

__global__ __launch_bounds__(256) void scan_local(
    const int* __restrict__ deg, int* __restrict__ row_start, int* __restrict__ blocksum, int n)
{
    __shared__ int s[256];
    const int t = threadIdx.x;
    const int i = blockIdx.x * 256 + t;
    int v = (i < n) ? deg[i] : 0;
    s[t] = v;
    __syncthreads();
#pragma unroll
    for (int off = 1; off < 256; off <<= 1) {
        int u = (t >= off) ? s[t - off] : 0;
        __syncthreads();
        s[t] += u;
        __syncthreads();
    }
    if (i < n) row_start[i] = s[t] - v;
    if (t == 255) blocksum[blockIdx.x] = s[255];
}

__global__ __launch_bounds__(256) void scan_blocks(int* __restrict__ blocksum, int nb)
{
    __shared__ int s[256];
    const int t = threadIdx.x;
    int v = (t < nb) ? blocksum[t] : 0;
    s[t] = v;
    __syncthreads();
#pragma unroll
    for (int off = 1; off < 256; off <<= 1) {
        int u = (t >= off) ? s[t - off] : 0;
        __syncthreads();
        s[t] += u;
        __syncthreads();
    }
    if (t < nb) blocksum[t] = s[t] - v;
}

__global__ __launch_bounds__(256) void scan_add(
    int* __restrict__ row_start, int* __restrict__ cursor,
    const int* __restrict__ blocksum, int n, int total)
{
    const int i = blockIdx.x * 256 + threadIdx.x;
    if (i < n) {
        int v = row_start[i] + blocksum[blockIdx.x];
        row_start[i] = v;
        cursor[i] = v;
    } else if (i == n) {
        row_start[n] = total;
    }
}

__global__ __launch_bounds__(256) void fill_csr(
    const int* __restrict__ src, const int* __restrict__ dst,
    int* __restrict__ cursor, int* __restrict__ csr_src, int E, int n)
{
    int e = blockIdx.x * 256 + threadIdx.x;
    if (e >= E + n) return;
    int s, d;
    if (e < E) { s = src[e]; d = dst[e]; } else { s = d = e - E; }
    int pos = atomicAdd(cursor + d, 1);
    csr_src[pos] = s;
}

// ---------------- fused GAT aggregation: one wave per node ----------------
template<int D, bool POOL>
__global__ __launch_bounds__(256) void gat_aggregate(
    const int* __restrict__ row_start, const int* __restrict__ csr_src,
    const float* __restrict__ asv, const float* __restrict__ adv,
    const float* __restrict__ h, const float* __restrict__ bias,
    float* __restrict__ out,
    const float* __restrict__ wpr, const float* __restrict__ wpo,
    float* __restrict__ poolA, float* __restrict__ poolB, int n)
{
    __shared__ float lds_e[4][128];
    __shared__ int   lds_i[4][128];
    const int node = (blockIdx.x * 256 + threadIdx.x) >> 6;
    const int lane = threadIdx.x & 63;
    const int w = threadIdx.x >> 6;
    if (node >= n) return;
    const int beg = row_start[node];
    const int deg = row_start[node + 1] - beg;
    const float advv = adv[node];
    const bool fast = (deg <= 128);

    float amax = -INFINITY;
    if (fast) {
        for (int j = lane; j < deg; j += 64) {
            int s = csr_src[beg + j];
            lds_i[w][j] = s;
            float a = asv[s] + advv;
            a = (a >= 0.f) ? a : 0.2f * a;
            lds_e[w][j] = a;
            amax = fmaxf(amax, a);
        }
    } else {
        for (int j = lane; j < deg; j += 64) {
            float a = asv[csr_src[beg + j]] + advv;
            a = (a >= 0.f) ? a : 0.2f * a;
            amax = fmaxf(amax, a);
        }
    }
#pragma unroll
    for (int off = 32; off; off >>= 1) amax = fmaxf(amax, __shfl_xor(amax, off));

    float ssum = 0.f;
    if (fast) {
        for (int j = lane; j < deg; j += 64) {
            float ev = expf(lds_e[w][j] - amax);
            lds_e[w][j] = ev;
            ssum += ev;
        }
    } else {
        for (int j = lane; j < deg; j += 64) {
            float a = asv[csr_src[beg + j]] + advv;
            a = (a >= 0.f) ? a : 0.2f * a;
            ssum += expf(a - amax);
        }
    }
#pragma unroll
    for (int off = 32; off; off >>= 1) ssum += __shfl_xor(ssum, off);
    const float inv = 1.f / (ssum + 1e-16f);

    if constexpr (D == 128) {
        const float2* h2 = reinterpret_cast<const float2*>(h);
        float2 a0 = {0.f, 0.f}, a1 = {0.f, 0.f}, a2 = {0.f, 0.f}, a3 = {0.f, 0.f};
        int j = 0;
        if (fast) {
            for (; j + 4 <= deg; j += 4) {
                int s0 = lds_i[w][j], s1 = lds_i[w][j + 1], s2 = lds_i[w][j + 2], s3 = lds_i[w][j + 3];
                float c0 = lds_e[w][j] * inv, c1 = lds_e[w][j + 1] * inv;
                float c2 = lds_e[w][j + 2] * inv, c3 = lds_e[w][j + 3] * inv;
                float2 v0 = h2[(size_t)s0 * 64 + lane];
                float2 v1 = h2[(size_t)s1 * 64 + lane];
                float2 v2 = h2[(size_t)s2 * 64 + lane];
                float2 v3 = h2[(size_t)s3 * 64 + lane];
                a0.x = fmaf(v0.x, c0, a0.x); a0.y = fmaf(v0.y, c0, a0.y);
                a1.x = fmaf(v1.x, c1, a1.x); a1.y = fmaf(v1.y, c1, a1.y);
                a2.x = fmaf(v2.x, c2, a2.x); a2.y = fmaf(v2.y, c2, a2.y);
                a3.x = fmaf(v3.x, c3, a3.x); a3.y = fmaf(v3.y, c3, a3.y);
            }
            for (; j < deg; ++j) {
                int s = lds_i[w][j];
                float c = lds_e[w][j] * inv;
                float2 v = h2[(size_t)s * 64 + lane];
                a0.x = fmaf(v.x, c, a0.x); a0.y = fmaf(v.y, c, a0.y);
            }
        } else {
            for (; j < deg; ++j) {
                int s = csr_src[beg + j];
                float a = asv[s] + advv;
                a = (a >= 0.f) ? a : 0.2f * a;
                float c = expf(a - amax) * inv;
                float2 v = h2[(size_t)s * 64 + lane];
                a0.x = fmaf(v.x, c, a0.x); a0.y = fmaf(v.y, c, a0.y);
            }
        }
        float2 o;
        o.x = fmaxf(((a0.x + a1.x) + (a2.x + a3.x)) + bias[2 * lane], 0.f);
        o.y = fmaxf(((a0.y + a1.y) + (a2.y + a3.y)) + bias[2 * lane + 1], 0.f);
        reinterpret_cast<float2*>(out)[(size_t)node * 64 + lane] = o;
        if constexpr (POOL) {
            float pa = fmaf(o.x, wpr[2 * lane], o.y * wpr[2 * lane + 1]);
            float pb = fmaf(o.x, wpo[2 * lane], o.y * wpo[2 * lane + 1]);
#pragma unroll
            for (int off = 32; off; off >>= 1) {
                pa += __shfl_xor(pa, off);
                pb += __shfl_xor(pb, off);
            }
            if (lane == 0) { poolA[node] = pa; poolB[node] = pb; }
        }
    } else {
        float a0 = 0.f, a1 = 0.f, a2 = 0.f, a3 = 0.f;
        int j = 0;
        if (fast) {
            for (; j + 4 <= deg; j += 4) {
                int s0 = lds_i[w][j], s1 = lds_i[w][j + 1], s2 = lds_i[w][j + 2], s3 = lds_i[w][j + 3];
                float c0 = lds_e[w][j] * inv, c1 = lds_e[w][j + 1] * inv;
                float c2 = lds_e[w][j + 2] * inv, c3 = lds_e[w][j + 3] * inv;
                a0 = fmaf(h[(size_t)s0 * D + lane], c0, a0);
                a1 = fmaf(h[(size_t)s1 * D + lane], c1, a1);
                a2 = fmaf(h[(size_t)s2 * D + lane], c2, a2);
                a3 = fmaf(h[(size_t)s3 * D + lane], c3, a3);
            }
            for (; j < deg; ++j) {
                a0 = fmaf(h[(size_t)lds_i[w][j] * D + lane], lds_e[w][j] * inv, a0);
            }
        } else {
            for (; j < deg; ++j) {
                int s = csr_src[beg + j];
                float a = asv[s] + advv;
                a = (a >= 0.f) ? a : 0.2f * a;
                float c = expf(a - amax) * inv;
                a0 = fmaf(h[(size_t)s * D + lane], c, a0);
            }
        }
        out[(size_t)node * D + lane] = fmaxf(((a0 + a1) + (a2 + a3)) + bias[lane], 0.f);
    }
}

// ---------------- pooling score via CSR (original edges only: subtract self-loop) ----------------
__global__ __launch_bounds__(256) void score_csr(
    const int* __restrict__ row_start, const int* __restrict__ csr_src,
    const float* __restrict__ ts, const float* __restrict__ td,
    const float* __restrict__ bp, float* __restrict__ score, int n)
{
    int i = blockIdx.x * 256 + threadIdx.x;
    if (i >= n) return;
    int beg = row_start[i], end = row_start[i + 1];
    float s = td[i] + bp[0] - ts[i];
    for (int j = beg; j < end; ++j) s += ts[csr_src[j]];
    score[i] = s;
}

// ---------------- precompute: va_l = W_l @ a; pad Wl/bl; zero deg ----------------
__global__ __launch_bounds__(256) void precompute(
    const float* __restrict__ W1, const float* __restrict__ a1s, const float* __restrict__ a1d,
    const float* __restrict__ W2, const float* __restrict__ a2s, const float* __restrict__ a2d,
    const float* __restrict__ W3, const float* __restrict__ a3s, const float* __restrict__ a3d,
    const float* __restrict__ Wl, const float* __restrict__ bl,
    float* __restrict__ va1, float* __restrict__ vb1,
    float* __restrict__ va2, float* __restrict__ vb2,
    float* __restrict__ va3, float* __restrict__ vb3,
    float* __restrict__ Wlp, float* __restrict__ blp,
    int* __restrict__ deg, int n)
{
    int t = blockIdx.x * 256 + threadIdx.x;
    if (t < n) deg[t] = 0;
    if (t < 128) {
        float sa = 0.f, sb = 0.f;
        for (int j = 0; j < 64; ++j) {
            float w = W1[t * 64 + j];
            sa = fmaf(w, a1s[j], sa); sb = fmaf(w, a1d[j], sb);
        }
        va1[t] = sa; vb1[t] = sb;
    } else if (t < 192) {
        int k = t - 128;
        float sa = 0.f, sb = 0.f;
        for (int j = 0; j < 128; ++j) {
            float w = W2[k * 128 + j];
            sa = fmaf(w, a2s[j], sa); sb = fmaf(w, a2d[j], sb);
        }
        va2[k] = sa; vb2[k] = sb;
    } else if (t < 320) {
        int k = t - 192;
        float sa = 0.f, sb = 0.f;
        for (int j = 0; j < 128; ++j) {
            float w = W3[k * 128 + j];
            sa = fmaf(w, a3s[j], sa); sb = fmaf(w, a3d[j], sb);
        }
        va3[k] = sa; vb3[k] = sb;
    } else if (t < 320 + 2048) {
        int i = t - 320;
        int k = i >> 4, c = i & 15;
        Wlp[i] = (c < 10) ? Wl[k * 10 + c] : 0.f;
    } else if (t < 320 + 2048 + 16) {
        int c = t - (320 + 2048);
        blp[c] = (c < 10) ? bl[c] : 0.f;
    }
}

extern "C" void kernel_launch(void* const* d_in, const int* in_sizes, int n_in,
                              void* d_out, int out_size, void* d_ws, size_t ws_size,
                              hipStream_t stream) {
    const float* x   = (const float*)d_in[0];
    const int*   ei  = (const int*)d_in[1];
    const float* W1  = (const float*)d_in[4];
    const float* a1s = (const float*)d_in[5];
    const float* a1d = (const float*)d_in[6];
    const float* b1  = (const float*)d_in[7];
    const float* W2  = (const float*)d_in[8];
    const float* a2s = (const float*)d_in[9];
    const float* a2d = (const float*)d_in[10];
    const float* b2  = (const float*)d_in[11];
    const float* W3  = (const float*)d_in[12];
    const float* a3s = (const float*)d_in[13];
    const float* a3d = (const float*)d_in[14];
    const float* b3  = (const float*)d_in[15];
    const float* wpr = (const float*)d_in[16];
    const float* wpo = (const float*)d_in[17];
    const float* bp  = (const float*)d_in[18];
    const float* Wl  = (const float*)d_in[19];
    const float* bl  = (const float*)d_in[20];

    const int n = in_sizes[0] / 128;   // 40000
    const int E = in_sizes[1] / 2;     // 640000
    const int Esl = E + n;
    const int* src = ei;
    const int* dst = ei + E;

    float* ws = (float*)d_ws;
    const size_t nd = (size_t)n * 128;
    float* bufA      = ws;                          // [n,128]
    float* bufB      = bufA + nd;                   // [n,128]
    float* asv       = bufB + nd;                   // [n]
    float* adv       = asv + n;                     // [n]
    float* tsv       = adv + n;                     // [n]
    float* tdv       = tsv + n;                     // [n]
    float* score     = tdv + n;                     // [n]
    int*   deg       = (int*)(score + n);           // [n]
    int*   row_start = deg + n;                     // [n+1]
    int*   cursor    = row_start + n + 1;           // [n]
    int*   blocksum  = cursor + n;                  // [<=256]
    int*   csr_src   = blocksum + 256;              // [Esl]
    float* va1       = (float*)(csr_src + Esl);     // [128]
    float* vb1       = va1 + 128;                   // [128]
    float* va2       = vb1 + 128;                   // [64]
    float* vb2       = va2 + 64;                    // [64]
    float* va3       = vb2 + 64;                    // [128]
    float* vb3       = va3 + 128;                   // [128]
    float* Wlp       = vb3 + 128;                   // [128*16]
    float* blp       = Wlp + 128 * 16;              // [16]

    const unsigned EB = (unsigned)((Esl + 255) / 256);
    const unsigned NB = (unsigned)((n + 255) / 256);
    const unsigned MB = (unsigned)((n + 63) / 64);
    const unsigned WB = (unsigned)(((size_t)n * 64 + 255) / 256);

    // ---------- precompute (+deg zero) + CSR build ----------
    precompute<<<NB, 256, 0, stream>>>(W1, a1s, a1d, W2, a2s, a2d, W3, a3s, a3d, Wl, bl,
                                       va1, vb1, va2, vb2, va3, vb3, Wlp, blp, deg, n);
    hist_deg<<<EB, 256, 0, stream>>>(dst, deg, E, n);
    scan_local<<<NB, 256, 0, stream>>>(deg, row_start, blocksum, n);
    scan_blocks<<<1, 256, 0, stream>>>(blocksum, (int)NB);
    scan_add<<<NB, 256, 0, stream>>>(row_start, cursor, blocksum, n, Esl);
    fill_csr<<<EB, 256, 0, stream>>>(src, dst, cursor, csr_src, E, n);

    // ---------- Layer 1: 128 -> 64 ----------
    gemm_tile<128, 64, 64><<<dim3(MB, 1), 256, 0, stream>>>(
        x, W1, bufA, n, nullptr, nullptr, 0, va1, vb1, asv, adv);
    gat_aggregate<64, false><<<WB, 256, 0, stream>>>(row_start, csr_src, asv, adv, bufA, b1, bufB,
                                                     nullptr, nullptr, nullptr, nullptr, n);

    // ---------- Layer 2: 64 -> 128 ----------
    gemm_tile<64, 128, 64><<<dim3(MB, 2), 256, 0, stream>>>(
        bufB, W2, bufA, n, nullptr, nullptr, 0, va2, vb2, asv, adv);
    gat_aggregate<128, false><<<WB, 256, 0, stream>>>(row_start, csr_src, asv, adv, bufA, b2, bufB,
                                                      nullptr, nullptr, nullptr, nullptr, n);

    // ---------- Layer 3: 128 -> 128 (+ fused pooling dots) ----------
    gemm_tile<128, 128, 64><<<dim3(MB, 2), 256, 0, stream>>>(
        bufB, W3, bufA, n, nullptr, nullptr, 0, va3, vb3, asv, adv);
    gat_aggregate<128, true><<<WB, 256, 0, stream>>>(row_start, csr_src, asv, adv, bufA, b3, bufB,
                                                     wpr, wpo, tsv, tdv, n);

    // ---------- SAGPool score + final linear ----------
    score_csr<<<NB, 256, 0, stream>>>(row_start, csr_src, tsv, tdv, bp, score, n);
    gemm_tile<128, 16, 16><<<dim3(MB, 1), 256, 0, stream>>>(
        bufB, Wlp, (float*)d_out, n, blp, score, 10, nullptr, nullptr, nullptr, nullptr);
}

// Round 7
// 333.650 us; speedup vs baseline: 3.5428x; 1.0606x over previous
//
#include <hip/hip_runtime.h>
#include <math.h>

// ---------------- register-tiled GEMM: C[M,N] = A[M,K] @ B[K,N] ----------------
// BM=64 rows/block, full N per block, 128 threads, per-thread MR x 8 micro-tile.
// A staged transposed in LDS (AsT[k][r], stride 68), B staged [k][c]. KC=32 k-chunks.
// va != nullptr: fused attention dots outa[r]=A_row.va, outb[r]=A_row.vb.
template<int K, int N>
__global__ __launch_bounds__(128) void gemm_rt(
    const float* __restrict__ A, const float* __restrict__ B,
    float* __restrict__ C, int M,
    const float* __restrict__ va, const float* __restrict__ vb,
    float* __restrict__ outa, float* __restrict__ outb)
{
    constexpr int KC = 32;           // k-chunk
    constexpr int NC = K / KC;       // chunks
    constexpr int TC = N / 8;        // thread-cols (16 or 8)
    constexpr int TR = 128 / TC;     // thread-rows (8 or 16)
    constexpr int MR = 64 / TR;      // rows per thread (8 or 4)
    constexpr int KT = KC / TC;      // k-slice per tc for dots (2 or 4)
    constexpr int AST = 68;          // AsT row stride (pad: banks spread, 16B aligned)

    __shared__ float AsT[KC * AST];
    __shared__ float Bs[KC * N];

    const int tid = threadIdx.x;
    const int base = blockIdx.x * 64;
    const int tc = tid % TC;
    const int tr = tid / TC;
    const int sq = tid & 7;          // staging: k-quad 0..7
    const int sr = tid >> 3;         // staging: row 0..15 (+16,+32,+48)

    float acc[MR][8];
#pragma unroll
    for (int m = 0; m < MR; ++m)
#pragma unroll
        for (int j = 0; j < 8; ++j) acc[m][j] = 0.f;
    float sa[MR], sb[MR];
#pragma unroll
    for (int m = 0; m < MR; ++m) { sa[m] = 0.f; sb[m] = 0.f; }

    for (int ch = 0; ch < NC; ++ch) {
        const int k0 = ch * KC;
        // stage A transposed: 64 rows x 32 k
#pragma unroll
        for (int rr = sr; rr < 64; rr += 16) {
            int gr = base + rr;
            float4 av = (gr < M) ? *(const float4*)(A + (size_t)gr * K + k0 + 4 * sq)
                                 : make_float4(0.f, 0.f, 0.f, 0.f);
            AsT[(4 * sq + 0) * AST + rr] = av.x;
            AsT[(4 * sq + 1) * AST + rr] = av.y;
            AsT[(4 * sq + 2) * AST + rr] = av.z;
            AsT[(4 * sq + 3) * AST + rr] = av.w;
        }
        // stage B: 32 k x N
#pragma unroll
        for (int t = tid; t < KC * N / 4; t += 128) {
            int f = t * 4;
            int k = f / N, c = f % N;
            *(float4*)(Bs + k * N + c) = *(const float4*)(B + (size_t)(k0 + k) * N + c);
        }
        __syncthreads();

#pragma unroll 4
        for (int kk = 0; kk < KC; ++kk) {
            const float* ap = AsT + kk * AST + MR * tr;
            const float* bp = Bs + kk * N + 8 * tc;
            float4 b0 = *(const float4*)(bp);
            float4 b1 = *(const float4*)(bp + 4);
            float4 a0 = *(const float4*)(ap);
#pragma unroll
            for (int m = 0; m < 4; ++m) {
                float av = ((const float*)&a0)[m];
                acc[m][0] = fmaf(av, b0.x, acc[m][0]);
                acc[m][1] = fmaf(av, b0.y, acc[m][1]);
                acc[m][2] = fmaf(av, b0.z, acc[m][2]);
                acc[m][3] = fmaf(av, b0.w, acc[m][3]);
                acc[m][4] = fmaf(av, b1.x, acc[m][4]);
                acc[m][5] = fmaf(av, b1.y, acc[m][5]);
                acc[m][6] = fmaf(av, b1.z, acc[m][6]);
                acc[m][7] = fmaf(av, b1.w, acc[m][7]);
            }
            if constexpr (MR == 8) {
                float4 a1 = *(const float4*)(ap + 4);
#pragma unroll
                for (int m = 0; m < 4; ++m) {
                    float av = ((const float*)&a1)[m];
                    acc[m + 4][0] = fmaf(av, b0.x, acc[m + 4][0]);
                    acc[m + 4][1] = fmaf(av, b0.y, acc[m + 4][1]);
                    acc[m + 4][2] = fmaf(av, b0.z, acc[m + 4][2]);
                    acc[m + 4][3] = fmaf(av, b0.w, acc[m + 4][3]);
                    acc[m + 4][4] = fmaf(av, b1.x, acc[m + 4][4]);
                    acc[m + 4][5] = fmaf(av, b1.y, acc[m + 4][5]);
                    acc[m + 4][6] = fmaf(av, b1.z, acc[m + 4][6]);
                    acc[m + 4][7] = fmaf(av, b1.w, acc[m + 4][7]);
                }
            }
        }
        // fused attention-dot partials from AsT (tc-partitioned k)
        if (va != nullptr) {
#pragma unroll
            for (int kl = 0; kl < KT; ++kl) {
                int k = tc * KT + kl;
                float av_ = va[k0 + k];
                float bv_ = vb[k0 + k];
#pragma unroll
                for (int m = 0; m < MR; ++m) {
                    float aval = AsT[k * AST + MR * tr + m];
                    sa[m] = fmaf(aval, av_, sa[m]);
                    sb[m] = fmaf(aval, bv_, sb[m]);
                }
            }
        }
        __syncthreads();
    }

    // epilogue: C write
#pragma unroll
    for (int m = 0; m < MR; ++m) {
        int gr = base + MR * tr + m;
        if (gr < M) {
            float4 o0 = make_float4(acc[m][0], acc[m][1], acc[m][2], acc[m][3]);
            float4 o1 = make_float4(acc[m][4], acc[m][5], acc[m][6], acc[m][7]);
            *(float4*)(C + (size_t)gr * N + 8 * tc) = o0;
            *(float4*)(C + (size_t)gr * N + 8 * tc + 4) = o1;
        }
    }
    // dots: reduce across tc lanes, write once
    if (va != nullptr) {
#pragma unroll
        for (int m = 0; m < MR; ++m) {
#pragma unroll
            for (int off = TC / 2; off; off >>= 1) {
                sa[m] += __shfl_xor(sa[m], off);
                sb[m] += __shfl_xor(sb[m], off);
            }
        }
        if (tc == 0) {
#pragma unroll
            for (int m = 0; m < MR; ++m) {
                int gr = base + MR * tr + m;
                if (gr < M) { outa[gr] = sa[m]; outb[gr] = sb[m]; }
            }
        }
    }
}

// ---------------- small GEMM (final layer): old style, N=16 cols ----------------
// epilogue: out = relu(tanh(score[r])*acc + bias[c]), write outN cols.
template<int K, int N, int NT>
__global__ __launch_bounds__(256) void gemm_tile(
    const float* __restrict__ A, const float* __restrict__ B,
    float* __restrict__ C, int M,
    const float* __restrict__ bias, const float* __restrict__ score, int outN)
{
    __shared__ float As[64 * K];
    const int tid = threadIdx.x;
    const int base = blockIdx.x * 64;
    for (int idx = tid; idx < 64 * K; idx += 256) {
        int r = idx / K, k = idx - r * K;
        int gr = base + r;
        As[idx] = (gr < M) ? A[(size_t)gr * K + k] : 0.f;
    }
    __syncthreads();
    constexpr int RSTEP = 256 / NT;
    constexpr int NR = 64 / RSTEP;
    const int c = tid % NT;
    const int r0 = tid / NT;
    float acc[NR];
#pragma unroll
    for (int i = 0; i < NR; ++i) acc[i] = 0.f;
    const float4* As4 = reinterpret_cast<const float4*>(As);
    const float* Bc = B + c;
    float b0 = Bc[0 * N], b1 = Bc[1 * N], b2 = Bc[2 * N], b3 = Bc[3 * N];
    for (int k = 0; k < K; k += 4) {
        const int kn = (k + 4 < K) ? (k + 4) : k;
        float n0 = Bc[(kn + 0) * N];
        float n1 = Bc[(kn + 1) * N];
        float n2 = Bc[(kn + 2) * N];
        float n3 = Bc[(kn + 3) * N];
#pragma unroll
        for (int i = 0; i < NR; ++i) {
            float4 a = As4[((r0 + i * RSTEP) * K + k) >> 2];
            acc[i] = fmaf(a.x, b0, acc[i]);
            acc[i] = fmaf(a.y, b1, acc[i]);
            acc[i] = fmaf(a.z, b2, acc[i]);
            acc[i] = fmaf(a.w, b3, acc[i]);
        }
        b0 = n0; b1 = n1; b2 = n2; b3 = n3;
    }
    if (c < outN) {
#pragma unroll
        for (int i = 0; i < NR; ++i) {
            int gr = base + r0 + i * RSTEP;
            if (gr < M) {
                float v = tanhf(score[gr]) * acc[i] + bias[c];
                C[(size_t)gr * outN + c] = fmaxf(v, 0.f);
            }
        }
    }
}

// ---------------- CSR build ----------------
__global__ __launch_bounds__(256) void hist_deg(
    const int* __restrict__ dst, int* __restrict__ deg, int E, int n)
{
    int e = blockIdx.x * 256 + threadIdx.x;
    if (e >= E + n) return;
    int d = (e < E) ? dst[e] : (e - E);
    atomicAdd(deg + d, 1);
}

__global__ __launch_bounds__(256) void scan_local(
    const int* __restrict__ deg, int* __restrict__ row_start, int* __restrict__ blocksum, int n)
{
    __shared__ int s[256];
    const int t = threadIdx.x;
    const int i = blockIdx.x * 256 + t;
    int v = (i < n) ? deg[i] : 0;
    s[t] = v;
    __syncthreads();
#pragma unroll
    for (int off = 1; off < 256; off <<= 1) {
        int u = (t >= off) ? s[t - off] : 0;
        __syncthreads();
        s[t] += u;
        __syncthreads();
    }
    if (i < n) row_start[i] = s[t] - v;
    if (t == 255) blocksum[blockIdx.x] = s[255];
}

__global__ __launch_bounds__(256) void scan_blocks(int* __restrict__ blocksum, int nb)
{
    __shared__ int s[256];
    const int t = threadIdx.x;
    int v = (t < nb) ? blocksum[t] : 0;
    s[t] = v;
    __syncthreads();
#pragma unroll
    for (int off = 1; off < 256; off <<= 1) {
        int u = (t >= off) ? s[t - off] : 0;
        __syncthreads();
        s[t] += u;
        __syncthreads();
    }
    if (t < nb) blocksum[t] = s[t] - v;
}

__global__ __launch_bounds__(256) void scan_add(
    int* __restrict__ row_start, int* __restrict__ cursor,
    const int* __restrict__ blocksum, int n, int total)
{
    const int i = blockIdx.x * 256 + threadIdx.x;
    if (i < n) {
        int v = row_start[i] + blocksum[blockIdx.x];
        row_start[i] = v;
        cursor[i] = v;
    } else if (i == n) {
        row_start[n] = total;
    }
}

__global__ __launch_bounds__(256) void fill_csr(
    const int* __restrict__ src, const int* __restrict__ dst,
    int* __restrict__ cursor, int* __restrict__ csr_src, int E, int n)
{
    int e = blockIdx.x * 256 + threadIdx.x;
    if (e >= E + n) return;
    int s, d;
    if (e < E) { s = src[e]; d = dst[e]; } else { s = d = e - E; }
    int pos = atomicAdd(cursor + d, 1);
    csr_src[pos] = s;
}

// ---------------- fused GAT aggregation: one wave per node ----------------
template<int D, bool POOL>
__global__ __launch_bounds__(256) void gat_aggregate(
    const int* __restrict__ row_start, const int* __restrict__ csr_src,
    const float* __restrict__ asv, const float* __restrict__ adv,
    const float* __restrict__ h, const float* __restrict__ bias,
    float* __restrict__ out,
    const float* __restrict__ wpr, const float* __restrict__ wpo,
    float* __restrict__ poolA, float* __restrict__ poolB, int n)
{
    __shared__ float lds_e[4][128];
    __shared__ int   lds_i[4][128];
    const int node = (blockIdx.x * 256 + threadIdx.x) >> 6;
    const int lane = threadIdx.x & 63;
    const int w = threadIdx.x >> 6;
    if (node >= n) return;
    const int beg = row_start[node];
    const int deg = row_start[node + 1] - beg;
    const float advv = adv[node];
    const bool fast = (deg <= 128);

    float amax = -INFINITY;
    if (fast) {
        for (int j = lane; j < deg; j += 64) {
            int s = csr_src[beg + j];
            lds_i[w][j] = s;
            float a = asv[s] + advv;
            a = (a >= 0.f) ? a : 0.2f * a;
            lds_e[w][j] = a;
            amax = fmaxf(amax, a);
        }
    } else {
        for (int j = lane; j < deg; j += 64) {
            float a = asv[csr_src[beg + j]] + advv;
            a = (a >= 0.f) ? a : 0.2f * a;
            amax = fmaxf(amax, a);
        }
    }
#pragma unroll
    for (int off = 32; off; off >>= 1) amax = fmaxf(amax, __shfl_xor(amax, off));

    float ssum = 0.f;
    if (fast) {
        for (int j = lane; j < deg; j += 64) {
            float ev = expf(lds_e[w][j] - amax);
            lds_e[w][j] = ev;
            ssum += ev;
        }
    } else {
        for (int j = lane; j < deg; j += 64) {
            float a = asv[csr_src[beg + j]] + advv;
            a = (a >= 0.f) ? a : 0.2f * a;
            ssum += expf(a - amax);
        }
    }
#pragma unroll
    for (int off = 32; off; off >>= 1) ssum += __shfl_xor(ssum, off);
    const float inv = 1.f / (ssum + 1e-16f);

    if constexpr (D == 128) {
        const float2* h2 = reinterpret_cast<const float2*>(h);
        float2 a0 = {0.f, 0.f}, a1 = {0.f, 0.f}, a2 = {0.f, 0.f}, a3 = {0.f, 0.f};
        int j = 0;
        if (fast) {
            for (; j + 4 <= deg; j += 4) {
                int s0 = lds_i[w][j], s1 = lds_i[w][j + 1], s2 = lds_i[w][j + 2], s3 = lds_i[w][j + 3];
                float c0 = lds_e[w][j] * inv, c1 = lds_e[w][j + 1] * inv;
                float c2 = lds_e[w][j + 2] * inv, c3 = lds_e[w][j + 3] * inv;
                float2 v0 = h2[(size_t)s0 * 64 + lane];
                float2 v1 = h2[(size_t)s1 * 64 + lane];
                float2 v2 = h2[(size_t)s2 * 64 + lane];
                float2 v3 = h2[(size_t)s3 * 64 + lane];
                a0.x = fmaf(v0.x, c0, a0.x); a0.y = fmaf(v0.y, c0, a0.y);
                a1.x = fmaf(v1.x, c1, a1.x); a1.y = fmaf(v1.y, c1, a1.y);
                a2.x = fmaf(v2.x, c2, a2.x); a2.y = fmaf(v2.y, c2, a2.y);
                a3.x = fmaf(v3.x, c3, a3.x); a3.y = fmaf(v3.y, c3, a3.y);
            }
            for (; j < deg; ++j) {
                int s = lds_i[w][j];
                float c = lds_e[w][j] * inv;
                float2 v = h2[(size_t)s * 64 + lane];
                a0.x = fmaf(v.x, c, a0.x); a0.y = fmaf(v.y, c, a0.y);
            }
        } else {
            for (; j < deg; ++j) {
                int s = csr_src[beg + j];
                float a = asv[s] + advv;
                a = (a >= 0.f) ? a : 0.2f * a;
                float c = expf(a - amax) * inv;
                float2 v = h2[(size_t)s * 64 + lane];
                a0.x = fmaf(v.x, c, a0.x); a0.y = fmaf(v.y, c, a0.y);
            }
        }
        float2 o;
        o.x = fmaxf(((a0.x + a1.x) + (a2.x + a3.x)) + bias[2 * lane], 0.f);
        o.y = fmaxf(((a0.y + a1.y) + (a2.y + a3.y)) + bias[2 * lane + 1], 0.f);
        reinterpret_cast<float2*>(out)[(size_t)node * 64 + lane] = o;
        if constexpr (POOL) {
            float pa = fmaf(o.x, wpr[2 * lane], o.y * wpr[2 * lane + 1]);
            float pb = fmaf(o.x, wpo[2 * lane], o.y * wpo[2 * lane + 1]);
#pragma unroll
            for (int off = 32; off; off >>= 1) {
                pa += __shfl_xor(pa, off);
                pb += __shfl_xor(pb, off);
            }
            if (lane == 0) { poolA[node] = pa; poolB[node] = pb; }
        }
    } else {
        float a0 = 0.f, a1 = 0.f, a2 = 0.f, a3 = 0.f;
        int j = 0;
        if (fast) {
            for (; j + 4 <= deg; j += 4) {
                int s0 = lds_i[w][j], s1 = lds_i[w][j + 1], s2 = lds_i[w][j + 2], s3 = lds_i[w][j + 3];
                float c0 = lds_e[w][j] * inv, c1 = lds_e[w][j + 1] * inv;
                float c2 = lds_e[w][j + 2] * inv, c3 = lds_e[w][j + 3] * inv;
                a0 = fmaf(h[(size_t)s0 * D + lane], c0, a0);
                a1 = fmaf(h[(size_t)s1 * D + lane], c1, a1);
                a2 = fmaf(h[(size_t)s2 * D + lane], c2, a2);
                a3 = fmaf(h[(size_t)s3 * D + lane], c3, a3);
            }
            for (; j < deg; ++j) {
                a0 = fmaf(h[(size_t)lds_i[w][j] * D + lane], lds_e[w][j] * inv, a0);
            }
        } else {
            for (; j < deg; ++j) {
                int s = csr_src[beg + j];
                float a = asv[s] + advv;
                a = (a >= 0.f) ? a : 0.2f * a;
                float c = expf(a - amax) * inv;
                a0 = fmaf(h[(size_t)s * D + lane], c, a0);
            }
        }
        out[(size_t)node * D + lane] = fmaxf(((a0 + a1) + (a2 + a3)) + bias[lane], 0.f);
    }
}

// ---------------- pooling score via CSR ----------------
__global__ __launch_bounds__(256) void score_csr(
    const int* __restrict__ row_start, const int* __restrict__ csr_src,
    const float* __restrict__ ts, const float* __restrict__ td,
    const float* __restrict__ bp, float* __restrict__ score, int n)
{
    int i = blockIdx.x * 256 + threadIdx.x;
    if (i >= n) return;
    int beg = row_start[i], end = row_start[i + 1];
    float s = td[i] + bp[0] - ts[i];
    for (int j = beg; j < end; ++j) s += ts[csr_src[j]];
    score[i] = s;
}

// ---------------- precompute: va_l = W_l @ a; pad Wl/bl; zero deg ----------------
__global__ __launch_bounds__(256) void precompute(
    const float* __restrict__ W1, const float* __restrict__ a1s, const float* __restrict__ a1d,
    const float* __restrict__ W2, const float* __restrict__ a2s, const float* __restrict__ a2d,
    const float* __restrict__ W3, const float* __restrict__ a3s, const float* __restrict__ a3d,
    const float* __restrict__ Wl, const float* __restrict__ bl,
    float* __restrict__ va1, float* __restrict__ vb1,
    float* __restrict__ va2, float* __restrict__ vb2,
    float* __restrict__ va3, float* __restrict__ vb3,
    float* __restrict__ Wlp, float* __restrict__ blp,
    int* __restrict__ deg, int n)
{
    int t = blockIdx.x * 256 + threadIdx.x;
    if (t < n) deg[t] = 0;
    if (t < 128) {
        float sa = 0.f, sb = 0.f;
        for (int j = 0; j < 64; ++j) {
            float w = W1[t * 64 + j];
            sa = fmaf(w, a1s[j], sa); sb = fmaf(w, a1d[j], sb);
        }
        va1[t] = sa; vb1[t] = sb;
    } else if (t < 192) {
        int k = t - 128;
        float sa = 0.f, sb = 0.f;
        for (int j = 0; j < 128; ++j) {
            float w = W2[k * 128 + j];
            sa = fmaf(w, a2s[j], sa); sb = fmaf(w, a2d[j], sb);
        }
        va2[k] = sa; vb2[k] = sb;
    } else if (t < 320) {
        int k = t - 192;
        float sa = 0.f, sb = 0.f;
        for (int j = 0; j < 128; ++j) {
            float w = W3[k * 128 + j];
            sa = fmaf(w, a3s[j], sa); sb = fmaf(w, a3d[j], sb);
        }
        va3[k] = sa; vb3[k] = sb;
    } else if (t < 320 + 2048) {
        int i = t - 320;
        int k = i >> 4, c = i & 15;
        Wlp[i] = (c < 10) ? Wl[k * 10 + c] : 0.f;
    } else if (t < 320 + 2048 + 16) {
        int c = t - (320 + 2048);
        blp[c] = (c < 10) ? bl[c] : 0.f;
    }
}

extern "C" void kernel_launch(void* const* d_in, const int* in_sizes, int n_in,
                              void* d_out, int out_size, void* d_ws, size_t ws_size,
                              hipStream_t stream) {
    const float* x   = (const float*)d_in[0];
    const int*   ei  = (const int*)d_in[1];
    const float* W1  = (const float*)d_in[4];
    const float* a1s = (const float*)d_in[5];
    const float* a1d = (const float*)d_in[6];
    const float* b1  = (const float*)d_in[7];
    const float* W2  = (const float*)d_in[8];
    const float* a2s = (const float*)d_in[9];
    const float* a2d = (const float*)d_in[10];
    const float* b2  = (const float*)d_in[11];
    const float* W3  = (const float*)d_in[12];
    const float* a3s = (const float*)d_in[13];
    const float* a3d = (const float*)d_in[14];
    const float* b3  = (const float*)d_in[15];
    const float* wpr = (const float*)d_in[16];
    const float* wpo = (const float*)d_in[17];
    const float* bp  = (const float*)d_in[18];
    const float* Wl  = (const float*)d_in[19];
    const float* bl  = (const float*)d_in[20];

    const int n = in_sizes[0] / 128;   // 40000
    const int E = in_sizes[1] / 2;     // 640000
    const int Esl = E + n;
    const int* src = ei;
    const int* dst = ei + E;

    float* ws = (float*)d_ws;
    const size_t nd = (size_t)n * 128;
    float* bufA      = ws;                          // [n,128]
    float* bufB      = bufA + nd;                   // [n,128]
    float* asv       = bufB + nd;                   // [n]
    float* adv       = asv + n;                     // [n]
    float* tsv       = adv + n;                     // [n]
    float* tdv       = tsv + n;                     // [n]
    float* score     = tdv + n;                     // [n]
    int*   deg       = (int*)(score + n);           // [n]
    int*   row_start = deg + n;                     // [n+1]
    int*   cursor    = row_start + n + 1;           // [n]
    int*   blocksum  = cursor + n;                  // [<=256]
    int*   csr_src   = blocksum + 256;              // [Esl]
    float* va1       = (float*)(csr_src + Esl);     // [128]
    float* vb1       = va1 + 128;                   // [128]
    float* va2       = vb1 + 128;                   // [64]
    float* vb2       = va2 + 64;                    // [64]
    float* va3       = vb2 + 64;                    // [128]
    float* vb3       = va3 + 128;                   // [128]
    float* Wlp       = vb3 + 128;                   // [128*16]
    float* blp       = Wlp + 128 * 16;              // [16]

    const unsigned EB = (unsigned)((Esl + 255) / 256);
    const unsigned NB = (unsigned)((n + 255) / 256);
    const unsigned MB = (unsigned)((n + 63) / 64);   // 625
    const unsigned WB = (unsigned)(((size_t)n * 64 + 255) / 256);

    // ---------- precompute (+deg zero) + CSR build ----------
    precompute<<<NB, 256, 0, stream>>>(W1, a1s, a1d, W2, a2s, a2d, W3, a3s, a3d, Wl, bl,
                                       va1, vb1, va2, vb2, va3, vb3, Wlp, blp, deg, n);
    hist_deg<<<EB, 256, 0, stream>>>(dst, deg, E, n);
    scan_local<<<NB, 256, 0, stream>>>(deg, row_start, blocksum, n);
    scan_blocks<<<1, 256, 0, stream>>>(blocksum, (int)NB);
    scan_add<<<NB, 256, 0, stream>>>(row_start, cursor, blocksum, n, Esl);
    fill_csr<<<EB, 256, 0, stream>>>(src, dst, cursor, csr_src, E, n);

    // ---------- Layer 1: 128 -> 64 ----------
    gemm_rt<128, 64><<<MB, 128, 0, stream>>>(x, W1, bufA, n, va1, vb1, asv, adv);
    gat_aggregate<64, false><<<WB, 256, 0, stream>>>(row_start, csr_src, asv, adv, bufA, b1, bufB,
                                                     nullptr, nullptr, nullptr, nullptr, n);

    // ---------- Layer 2: 64 -> 128 ----------
    gemm_rt<64, 128><<<MB, 128, 0, stream>>>(bufB, W2, bufA, n, va2, vb2, asv, adv);
    gat_aggregate<128, false><<<WB, 256, 0, stream>>>(row_start, csr_src, asv, adv, bufA, b2, bufB,
                                                      nullptr, nullptr, nullptr, nullptr, n);

    // ---------- Layer 3: 128 -> 128 (+ fused pooling dots) ----------
    gemm_rt<128, 128><<<MB, 128, 0, stream>>>(bufB, W3, bufA, n, va3, vb3, asv, adv);
    gat_aggregate<128, true><<<WB, 256, 0, stream>>>(row_start, csr_src, asv, adv, bufA, b3, bufB,
                                                     wpr, wpo, tsv, tdv, n);

    // ---------- SAGPool score + final linear ----------
    score_csr<<<NB, 256, 0, stream>>>(row_start, csr_src, tsv, tdv, bp, score, n);
    gemm_tile<128, 16, 16><<<MB, 256, 0, stream>>>(bufB, Wlp, (float*)d_out, n, blp, score, 10);
}

// Round 8
// 332.011 us; speedup vs baseline: 3.5603x; 1.0049x over previous
//
#include <hip/hip_runtime.h>
#include <math.h>

// ---------------- register-tiled GEMM: C[M,N] = A[M,K] @ B[K,N] ----------------
template<int K, int N>
__global__ __launch_bounds__(128) void gemm_rt(
    const float* __restrict__ A, const float* __restrict__ B,
    float* __restrict__ C, int M,
    const float* __restrict__ va, const float* __restrict__ vb,
    float* __restrict__ outa, float* __restrict__ outb)
{
    constexpr int KC = 32;
    constexpr int NC = K / KC;
    constexpr int TC = N / 8;
    constexpr int TR = 128 / TC;
    constexpr int MR = 64 / TR;
    constexpr int KT = KC / TC;
    constexpr int AST = 68;

    __shared__ float AsT[KC * AST];
    __shared__ float Bs[KC * N];

    const int tid = threadIdx.x;
    const int base = blockIdx.x * 64;
    const int tc = tid % TC;
    const int tr = tid / TC;
    const int sq = tid & 7;
    const int sr = tid >> 3;

    float acc[MR][8];
#pragma unroll
    for (int m = 0; m < MR; ++m)
#pragma unroll
        for (int j = 0; j < 8; ++j) acc[m][j] = 0.f;
    float sa[MR], sb[MR];
#pragma unroll
    for (int m = 0; m < MR; ++m) { sa[m] = 0.f; sb[m] = 0.f; }

    for (int ch = 0; ch < NC; ++ch) {
        const int k0 = ch * KC;
#pragma unroll
        for (int rr = sr; rr < 64; rr += 16) {
            int gr = base + rr;
            float4 av = (gr < M) ? *(const float4*)(A + (size_t)gr * K + k0 + 4 * sq)
                                 : make_float4(0.f, 0.f, 0.f, 0.f);
            AsT[(4 * sq + 0) * AST + rr] = av.x;
            AsT[(4 * sq + 1) * AST + rr] = av.y;
            AsT[(4 * sq + 2) * AST + rr] = av.z;
            AsT[(4 * sq + 3) * AST + rr] = av.w;
        }
#pragma unroll
        for (int t = tid; t < KC * N / 4; t += 128) {
            int f = t * 4;
            int k = f / N, c = f % N;
            *(float4*)(Bs + k * N + c) = *(const float4*)(B + (size_t)(k0 + k) * N + c);
        }
        __syncthreads();

#pragma unroll 4
        for (int kk = 0; kk < KC; ++kk) {
            const float* ap = AsT + kk * AST + MR * tr;
            const float* bp = Bs + kk * N + 8 * tc;
            float4 b0 = *(const float4*)(bp);
            float4 b1 = *(const float4*)(bp + 4);
            float4 a0 = *(const float4*)(ap);
#pragma unroll
            for (int m = 0; m < 4; ++m) {
                float av = ((const float*)&a0)[m];
                acc[m][0] = fmaf(av, b0.x, acc[m][0]);
                acc[m][1] = fmaf(av, b0.y, acc[m][1]);
                acc[m][2] = fmaf(av, b0.z, acc[m][2]);
                acc[m][3] = fmaf(av, b0.w, acc[m][3]);
                acc[m][4] = fmaf(av, b1.x, acc[m][4]);
                acc[m][5] = fmaf(av, b1.y, acc[m][5]);
                acc[m][6] = fmaf(av, b1.z, acc[m][6]);
                acc[m][7] = fmaf(av, b1.w, acc[m][7]);
            }
            if constexpr (MR == 8) {
                float4 a1 = *(const float4*)(ap + 4);
#pragma unroll
                for (int m = 0; m < 4; ++m) {
                    float av = ((const float*)&a1)[m];
                    acc[m + 4][0] = fmaf(av, b0.x, acc[m + 4][0]);
                    acc[m + 4][1] = fmaf(av, b0.y, acc[m + 4][1]);
                    acc[m + 4][2] = fmaf(av, b0.z, acc[m + 4][2]);
                    acc[m + 4][3] = fmaf(av, b0.w, acc[m + 4][3]);
                    acc[m + 4][4] = fmaf(av, b1.x, acc[m + 4][4]);
                    acc[m + 4][5] = fmaf(av, b1.y, acc[m + 4][5]);
                    acc[m + 4][6] = fmaf(av, b1.z, acc[m + 4][6]);
                    acc[m + 4][7] = fmaf(av, b1.w, acc[m + 4][7]);
                }
            }
        }
        if (va != nullptr) {
#pragma unroll
            for (int kl = 0; kl < KT; ++kl) {
                int k = tc * KT + kl;
                float av_ = va[k0 + k];
                float bv_ = vb[k0 + k];
#pragma unroll
                for (int m = 0; m < MR; ++m) {
                    float aval = AsT[k * AST + MR * tr + m];
                    sa[m] = fmaf(aval, av_, sa[m]);
                    sb[m] = fmaf(aval, bv_, sb[m]);
                }
            }
        }
        __syncthreads();
    }

#pragma unroll
    for (int m = 0; m < MR; ++m) {
        int gr = base + MR * tr + m;
        if (gr < M) {
            float4 o0 = make_float4(acc[m][0], acc[m][1], acc[m][2], acc[m][3]);
            float4 o1 = make_float4(acc[m][4], acc[m][5], acc[m][6], acc[m][7]);
            *(float4*)(C + (size_t)gr * N + 8 * tc) = o0;
            *(float4*)(C + (size_t)gr * N + 8 * tc + 4) = o1;
        }
    }
    if (va != nullptr) {
#pragma unroll
        for (int m = 0; m < MR; ++m) {
#pragma unroll
            for (int off = TC / 2; off; off >>= 1) {
                sa[m] += __shfl_xor(sa[m], off);
                sb[m] += __shfl_xor(sb[m], off);
            }
        }
        if (tc == 0) {
#pragma unroll
            for (int m = 0; m < MR; ++m) {
                int gr = base + MR * tr + m;
                if (gr < M) { outa[gr] = sa[m]; outb[gr] = sb[m]; }
            }
        }
    }
}

// ---------------- small GEMM (final layer) ----------------
template<int K, int N, int NT>
__global__ __launch_bounds__(256) void gemm_tile(
    const float* __restrict__ A, const float* __restrict__ B,
    float* __restrict__ C, int M,
    const float* __restrict__ bias, const float* __restrict__ score, int outN)
{
    __shared__ float As[64 * K];
    const int tid = threadIdx.x;
    const int base = blockIdx.x * 64;
    for (int idx = tid; idx < 64 * K; idx += 256) {
        int r = idx / K, k = idx - r * K;
        int gr = base + r;
        As[idx] = (gr < M) ? A[(size_t)gr * K + k] : 0.f;
    }
    __syncthreads();
    constexpr int RSTEP = 256 / NT;
    constexpr int NR = 64 / RSTEP;
    const int c = tid % NT;
    const int r0 = tid / NT;
    float acc[NR];
#pragma unroll
    for (int i = 0; i < NR; ++i) acc[i] = 0.f;
    const float4* As4 = reinterpret_cast<const float4*>(As);
    const float* Bc = B + c;
    float b0 = Bc[0 * N], b1 = Bc[1 * N], b2 = Bc[2 * N], b3 = Bc[3 * N];
    for (int k = 0; k < K; k += 4) {
        const int kn = (k + 4 < K) ? (k + 4) : k;
        float n0 = Bc[(kn + 0) * N];
        float n1 = Bc[(kn + 1) * N];
        float n2 = Bc[(kn + 2) * N];
        float n3 = Bc[(kn + 3) * N];
#pragma unroll
        for (int i = 0; i < NR; ++i) {
            float4 a = As4[((r0 + i * RSTEP) * K + k) >> 2];
            acc[i] = fmaf(a.x, b0, acc[i]);
            acc[i] = fmaf(a.y, b1, acc[i]);
            acc[i] = fmaf(a.z, b2, acc[i]);
            acc[i] = fmaf(a.w, b3, acc[i]);
        }
        b0 = n0; b1 = n1; b2 = n2; b3 = n3;
    }
    if (c < outN) {
#pragma unroll
        for (int i = 0; i < NR; ++i) {
            int gr = base + r0 + i * RSTEP;
            if (gr < M) {
                float v = tanhf(score[gr]) * acc[i] + bias[c];
                C[(size_t)gr * outN + c] = fmaxf(v, 0.f);
            }
        }
    }
}

// ---------------- CSR build ----------------
__global__ __launch_bounds__(256) void hist_deg(
    const int* __restrict__ dst, int* __restrict__ deg, int E, int n)
{
    int e = blockIdx.x * 256 + threadIdx.x;
    if (e >= E + n) return;
    int d = (e < E) ? dst[e] : (e - E);
    atomicAdd(deg + d, 1);
}

__global__ __launch_bounds__(256) void scan_local(
    const int* __restrict__ deg, int* __restrict__ row_start, int* __restrict__ blocksum, int n)
{
    __shared__ int s[256];
    const int t = threadIdx.x;
    const int i = blockIdx.x * 256 + t;
    int v = (i < n) ? deg[i] : 0;
    s[t] = v;
    __syncthreads();
#pragma unroll
    for (int off = 1; off < 256; off <<= 1) {
        int u = (t >= off) ? s[t - off] : 0;
        __syncthreads();
        s[t] += u;
        __syncthreads();
    }
    if (i < n) row_start[i] = s[t] - v;
    if (t == 255) blocksum[blockIdx.x] = s[255];
}

__global__ __launch_bounds__(256) void scan_blocks(int* __restrict__ blocksum, int nb)
{
    __shared__ int s[256];
    const int t = threadIdx.x;
    int v = (t < nb) ? blocksum[t] : 0;
    s[t] = v;
    __syncthreads();
#pragma unroll
    for (int off = 1; off < 256; off <<= 1) {
        int u = (t >= off) ? s[t - off] : 0;
        __syncthreads();
        s[t] += u;
        __syncthreads();
    }
    if (t < nb) blocksum[t] = s[t] - v;
}

__global__ __launch_bounds__(256) void scan_add(
    int* __restrict__ row_start, int* __restrict__ cursor,
    const int* __restrict__ blocksum, int n, int total)
{
    const int i = blockIdx.x * 256 + threadIdx.x;
    if (i < n) {
        int v = row_start[i] + blocksum[blockIdx.x];
        row_start[i] = v;
        cursor[i] = v;
    } else if (i == n) {
        row_start[n] = total;
    }
}

__global__ __launch_bounds__(256) void fill_csr(
    const int* __restrict__ src, const int* __restrict__ dst,
    int* __restrict__ cursor, int* __restrict__ csr_src, int E, int n)
{
    int e = blockIdx.x * 256 + threadIdx.x;
    if (e >= E + n) return;
    int s, d;
    if (e < E) { s = src[e]; d = dst[e]; } else { s = d = e - E; }
    int pos = atomicAdd(cursor + d, 1);
    csr_src[pos] = s;
}

// ---------------- fused GAT aggregation: one wave per node ----------------
// fast path pass-3: wave split into row-groups, float4 loads, 8 edges in flight.
template<int D, bool POOL>
__global__ __launch_bounds__(256) void gat_aggregate(
    const int* __restrict__ row_start, const int* __restrict__ csr_src,
    const float* __restrict__ asv, const float* __restrict__ adv,
    const float* __restrict__ h, const float* __restrict__ bias,
    float* __restrict__ out,
    const float* __restrict__ wpr, const float* __restrict__ wpo,
    float* __restrict__ poolA, float* __restrict__ poolB, int n)
{
    __shared__ float lds_e[4][128];
    __shared__ int   lds_i[4][128];
    const int node = (blockIdx.x * 256 + threadIdx.x) >> 6;
    const int lane = threadIdx.x & 63;
    const int w = threadIdx.x >> 6;
    if (node >= n) return;
    const int beg = row_start[node];
    const int deg = row_start[node + 1] - beg;
    const float advv = adv[node];
    const bool fast = (deg <= 128);

    // pass 1: stage indices + alpha in LDS, running max
    float amax = -INFINITY;
    if (fast) {
        for (int j = lane; j < deg; j += 64) {
            int s = csr_src[beg + j];
            lds_i[w][j] = s;
            float a = asv[s] + advv;
            a = (a >= 0.f) ? a : 0.2f * a;
            lds_e[w][j] = a;
            amax = fmaxf(amax, a);
        }
    } else {
        for (int j = lane; j < deg; j += 64) {
            float a = asv[csr_src[beg + j]] + advv;
            a = (a >= 0.f) ? a : 0.2f * a;
            amax = fmaxf(amax, a);
        }
    }
#pragma unroll
    for (int off = 32; off; off >>= 1) amax = fmaxf(amax, __shfl_xor(amax, off));

    // pass 2: exp + sum
    float ssum = 0.f;
    if (fast) {
        for (int j = lane; j < deg; j += 64) {
            float ev = expf(lds_e[w][j] - amax);
            lds_e[w][j] = ev;
            ssum += ev;
        }
    } else {
        for (int j = lane; j < deg; j += 64) {
            float a = asv[csr_src[beg + j]] + advv;
            a = (a >= 0.f) ? a : 0.2f * a;
            ssum += expf(a - amax);
        }
    }
#pragma unroll
    for (int off = 32; off; off >>= 1) ssum += __shfl_xor(ssum, off);
    const float inv = 1.f / (ssum + 1e-16f);

    // pass 3
    if (fast) {
        if constexpr (D == 128) {
            // 2 row-groups of 32 lanes; lane covers features 4*fl..4*fl+3
            const float4* h4 = reinterpret_cast<const float4*>(h);
            const int half = lane >> 5;
            const int fl = lane & 31;
            float4 a0 = {0,0,0,0}, a1 = {0,0,0,0}, a2 = {0,0,0,0}, a3 = {0,0,0,0};
            int j = 0;
            for (; j + 8 <= deg; j += 8) {
                int e0 = j + half, e1 = j + 2 + half, e2 = j + 4 + half, e3 = j + 6 + half;
                int s0 = lds_i[w][e0], s1 = lds_i[w][e1], s2 = lds_i[w][e2], s3 = lds_i[w][e3];
                float c0 = lds_e[w][e0] * inv, c1 = lds_e[w][e1] * inv;
                float c2 = lds_e[w][e2] * inv, c3 = lds_e[w][e3] * inv;
                float4 v0 = h4[(size_t)s0 * 32 + fl];
                float4 v1 = h4[(size_t)s1 * 32 + fl];
                float4 v2 = h4[(size_t)s2 * 32 + fl];
                float4 v3 = h4[(size_t)s3 * 32 + fl];
                a0.x = fmaf(v0.x, c0, a0.x); a0.y = fmaf(v0.y, c0, a0.y);
                a0.z = fmaf(v0.z, c0, a0.z); a0.w = fmaf(v0.w, c0, a0.w);
                a1.x = fmaf(v1.x, c1, a1.x); a1.y = fmaf(v1.y, c1, a1.y);
                a1.z = fmaf(v1.z, c1, a1.z); a1.w = fmaf(v1.w, c1, a1.w);
                a2.x = fmaf(v2.x, c2, a2.x); a2.y = fmaf(v2.y, c2, a2.y);
                a2.z = fmaf(v2.z, c2, a2.z); a2.w = fmaf(v2.w, c2, a2.w);
                a3.x = fmaf(v3.x, c3, a3.x); a3.y = fmaf(v3.y, c3, a3.y);
                a3.z = fmaf(v3.z, c3, a3.z); a3.w = fmaf(v3.w, c3, a3.w);
            }
            for (; j < deg; j += 2) {
                int e = j + half;
                bool ok = (e < deg);
                int s = lds_i[w][ok ? e : 0];
                float c = ok ? lds_e[w][e] * inv : 0.f;
                float4 v = h4[(size_t)s * 32 + fl];
                a0.x = fmaf(v.x, c, a0.x); a0.y = fmaf(v.y, c, a0.y);
                a0.z = fmaf(v.z, c, a0.z); a0.w = fmaf(v.w, c, a0.w);
            }
            float4 t;
            t.x = (a0.x + a1.x) + (a2.x + a3.x);
            t.y = (a0.y + a1.y) + (a2.y + a3.y);
            t.z = (a0.z + a1.z) + (a2.z + a3.z);
            t.w = (a0.w + a1.w) + (a2.w + a3.w);
            t.x += __shfl_xor(t.x, 32);
            t.y += __shfl_xor(t.y, 32);
            t.z += __shfl_xor(t.z, 32);
            t.w += __shfl_xor(t.w, 32);
            const float4 b4 = reinterpret_cast<const float4*>(bias)[fl];
            float4 o;
            o.x = fmaxf(t.x + b4.x, 0.f);
            o.y = fmaxf(t.y + b4.y, 0.f);
            o.z = fmaxf(t.z + b4.z, 0.f);
            o.w = fmaxf(t.w + b4.w, 0.f);
            if (half == 0)
                reinterpret_cast<float4*>(out)[(size_t)node * 32 + fl] = o;
            if constexpr (POOL) {
                const float4 r4 = reinterpret_cast<const float4*>(wpr)[fl];
                const float4 q4 = reinterpret_cast<const float4*>(wpo)[fl];
                float pa = o.x * r4.x + o.y * r4.y + o.z * r4.z + o.w * r4.w;
                float pb = o.x * q4.x + o.y * q4.y + o.z * q4.z + o.w * q4.w;
#pragma unroll
                for (int off = 16; off; off >>= 1) {
                    pa += __shfl_xor(pa, off);
                    pb += __shfl_xor(pb, off);
                }
                if (lane == 0) { poolA[node] = pa; poolB[node] = pb; }
            }
        } else {
            // D=64: 4 row-groups of 16 lanes
            const float4* h4 = reinterpret_cast<const float4*>(h);
            const int q = lane >> 4;
            const int fl = lane & 15;
            float4 a0 = {0,0,0,0}, a1 = {0,0,0,0};
            int j = 0;
            for (; j + 8 <= deg; j += 8) {
                int e0 = j + q, e1 = j + 4 + q;
                int s0 = lds_i[w][e0], s1 = lds_i[w][e1];
                float c0 = lds_e[w][e0] * inv, c1 = lds_e[w][e1] * inv;
                float4 v0 = h4[(size_t)s0 * 16 + fl];
                float4 v1 = h4[(size_t)s1 * 16 + fl];
                a0.x = fmaf(v0.x, c0, a0.x); a0.y = fmaf(v0.y, c0, a0.y);
                a0.z = fmaf(v0.z, c0, a0.z); a0.w = fmaf(v0.w, c0, a0.w);
                a1.x = fmaf(v1.x, c1, a1.x); a1.y = fmaf(v1.y, c1, a1.y);
                a1.z = fmaf(v1.z, c1, a1.z); a1.w = fmaf(v1.w, c1, a1.w);
            }
            for (; j < deg; j += 4) {
                int e = j + q;
                bool ok = (e < deg);
                int s = lds_i[w][ok ? e : 0];
                float c = ok ? lds_e[w][e] * inv : 0.f;
                float4 v = h4[(size_t)s * 16 + fl];
                a0.x = fmaf(v.x, c, a0.x); a0.y = fmaf(v.y, c, a0.y);
                a0.z = fmaf(v.z, c, a0.z); a0.w = fmaf(v.w, c, a0.w);
            }
            float4 t;
            t.x = a0.x + a1.x; t.y = a0.y + a1.y; t.z = a0.z + a1.z; t.w = a0.w + a1.w;
            t.x += __shfl_xor(t.x, 16); t.x += __shfl_xor(t.x, 32);
            t.y += __shfl_xor(t.y, 16); t.y += __shfl_xor(t.y, 32);
            t.z += __shfl_xor(t.z, 16); t.z += __shfl_xor(t.z, 32);
            t.w += __shfl_xor(t.w, 16); t.w += __shfl_xor(t.w, 32);
            const float4 b4 = reinterpret_cast<const float4*>(bias)[fl];
            float4 o;
            o.x = fmaxf(t.x + b4.x, 0.f);
            o.y = fmaxf(t.y + b4.y, 0.f);
            o.z = fmaxf(t.z + b4.z, 0.f);
            o.w = fmaxf(t.w + b4.w, 0.f);
            if (q == 0)
                reinterpret_cast<float4*>(out)[(size_t)node * 16 + fl] = o;
        }
    } else {
        // slow path (deg > 128): per-lane scalar loop, old feature mapping
        if constexpr (D == 128) {
            const float2* h2 = reinterpret_cast<const float2*>(h);
            float2 a0 = {0.f, 0.f};
            for (int j = 0; j < deg; ++j) {
                int s = csr_src[beg + j];
                float a = asv[s] + advv;
                a = (a >= 0.f) ? a : 0.2f * a;
                float c = expf(a - amax) * inv;
                float2 v = h2[(size_t)s * 64 + lane];
                a0.x = fmaf(v.x, c, a0.x); a0.y = fmaf(v.y, c, a0.y);
            }
            float2 o;
            o.x = fmaxf(a0.x + bias[2 * lane], 0.f);
            o.y = fmaxf(a0.y + bias[2 * lane + 1], 0.f);
            reinterpret_cast<float2*>(out)[(size_t)node * 64 + lane] = o;
            if constexpr (POOL) {
                float pa = fmaf(o.x, wpr[2 * lane], o.y * wpr[2 * lane + 1]);
                float pb = fmaf(o.x, wpo[2 * lane], o.y * wpo[2 * lane + 1]);
#pragma unroll
                for (int off = 32; off; off >>= 1) {
                    pa += __shfl_xor(pa, off);
                    pb += __shfl_xor(pb, off);
                }
                if (lane == 0) { poolA[node] = pa; poolB[node] = pb; }
            }
        } else {
            float a0 = 0.f;
            for (int j = 0; j < deg; ++j) {
                int s = csr_src[beg + j];
                float a = asv[s] + advv;
                a = (a >= 0.f) ? a : 0.2f * a;
                float c = expf(a - amax) * inv;
                a0 = fmaf(h[(size_t)s * D + lane], c, a0);
            }
            out[(size_t)node * D + lane] = fmaxf(a0 + bias[lane], 0.f);
        }
    }
}

// ---------------- pooling score via CSR ----------------
__global__ __launch_bounds__(256) void score_csr(
    const int* __restrict__ row_start, const int* __restrict__ csr_src,
    const float* __restrict__ ts, const float* __restrict__ td,
    const float* __restrict__ bp, float* __restrict__ score, int n)
{
    int i = blockIdx.x * 256 + threadIdx.x;
    if (i >= n) return;
    int beg = row_start[i], end = row_start[i + 1];
    float s = td[i] + bp[0] - ts[i];
    for (int j = beg; j < end; ++j) s += ts[csr_src[j]];
    score[i] = s;
}

// ---------------- precompute: va_l = W_l @ a; pad Wl/bl; zero deg ----------------
__global__ __launch_bounds__(256) void precompute(
    const float* __restrict__ W1, const float* __restrict__ a1s, const float* __restrict__ a1d,
    const float* __restrict__ W2, const float* __restrict__ a2s, const float* __restrict__ a2d,
    const float* __restrict__ W3, const float* __restrict__ a3s, const float* __restrict__ a3d,
    const float* __restrict__ Wl, const float* __restrict__ bl,
    float* __restrict__ va1, float* __restrict__ vb1,
    float* __restrict__ va2, float* __restrict__ vb2,
    float* __restrict__ va3, float* __restrict__ vb3,
    float* __restrict__ Wlp, float* __restrict__ blp,
    int* __restrict__ deg, int n)
{
    int t = blockIdx.x * 256 + threadIdx.x;
    if (t < n) deg[t] = 0;
    if (t < 128) {
        float sa = 0.f, sb = 0.f;
        for (int j = 0; j < 64; ++j) {
            float w = W1[t * 64 + j];
            sa = fmaf(w, a1s[j], sa); sb = fmaf(w, a1d[j], sb);
        }
        va1[t] = sa; vb1[t] = sb;
    } else if (t < 192) {
        int k = t - 128;
        float sa = 0.f, sb = 0.f;
        for (int j = 0; j < 128; ++j) {
            float w = W2[k * 128 + j];
            sa = fmaf(w, a2s[j], sa); sb = fmaf(w, a2d[j], sb);
        }
        va2[k] = sa; vb2[k] = sb;
    } else if (t < 320) {
        int k = t - 192;
        float sa = 0.f, sb = 0.f;
        for (int j = 0; j < 128; ++j) {
            float w = W3[k * 128 + j];
            sa = fmaf(w, a3s[j], sa); sb = fmaf(w, a3d[j], sb);
        }
        va3[k] = sa; vb3[k] = sb;
    } else if (t < 320 + 2048) {
        int i = t - 320;
        int k = i >> 4, c = i & 15;
        Wlp[i] = (c < 10) ? Wl[k * 10 + c] : 0.f;
    } else if (t < 320 + 2048 + 16) {
        int c = t - (320 + 2048);
        blp[c] = (c < 10) ? bl[c] : 0.f;
    }
}

extern "C" void kernel_launch(void* const* d_in, const int* in_sizes, int n_in,
                              void* d_out, int out_size, void* d_ws, size_t ws_size,
                              hipStream_t stream) {
    const float* x   = (const float*)d_in[0];
    const int*   ei  = (const int*)d_in[1];
    const float* W1  = (const float*)d_in[4];
    const float* a1s = (const float*)d_in[5];
    const float* a1d = (const float*)d_in[6];
    const float* b1  = (const float*)d_in[7];
    const float* W2  = (const float*)d_in[8];
    const float* a2s = (const float*)d_in[9];
    const float* a2d = (const float*)d_in[10];
    const float* b2  = (const float*)d_in[11];
    const float* W3  = (const float*)d_in[12];
    const float* a3s = (const float*)d_in[13];
    const float* a3d = (const float*)d_in[14];
    const float* b3  = (const float*)d_in[15];
    const float* wpr = (const float*)d_in[16];
    const float* wpo = (const float*)d_in[17];
    const float* bp  = (const float*)d_in[18];
    const float* Wl  = (const float*)d_in[19];
    const float* bl  = (const float*)d_in[20];

    const int n = in_sizes[0] / 128;   // 40000
    const int E = in_sizes[1] / 2;     // 640000
    const int Esl = E + n;
    const int* src = ei;
    const int* dst = ei + E;

    float* ws = (float*)d_ws;
    const size_t nd = (size_t)n * 128;
    float* bufA      = ws;                          // [n,128]
    float* bufB      = bufA + nd;                   // [n,128]
    float* asv       = bufB + nd;                   // [n]
    float* adv       = asv + n;                     // [n]
    float* tsv       = adv + n;                     // [n]
    float* tdv       = tsv + n;                     // [n]
    float* score     = tdv + n;                     // [n]
    int*   deg       = (int*)(score + n);           // [n]
    int*   row_start = deg + n;                     // [n+1]
    int*   cursor    = row_start + n + 1;           // [n]
    int*   blocksum  = cursor + n;                  // [<=256]
    int*   csr_src   = blocksum + 256;              // [Esl]
    float* va1       = (float*)(csr_src + Esl);     // [128]
    float* vb1       = va1 + 128;                   // [128]
    float* va2       = vb1 + 128;                   // [64]
    float* vb2       = va2 + 64;                    // [64]
    float* va3       = vb2 + 64;                    // [128]
    float* vb3       = va3 + 128;                   // [128]
    float* Wlp       = vb3 + 128;                   // [128*16]
    float* blp       = Wlp + 128 * 16;              // [16]

    const unsigned EB = (unsigned)((Esl + 255) / 256);
    const unsigned NB = (unsigned)((n + 255) / 256);
    const unsigned MB = (unsigned)((n + 63) / 64);   // 625
    const unsigned WB = (unsigned)(((size_t)n * 64 + 255) / 256);

    // ---------- precompute (+deg zero) + CSR build ----------
    precompute<<<NB, 256, 0, stream>>>(W1, a1s, a1d, W2, a2s, a2d, W3, a3s, a3d, Wl, bl,
                                       va1, vb1, va2, vb2, va3, vb3, Wlp, blp, deg, n);
    hist_deg<<<EB, 256, 0, stream>>>(dst, deg, E, n);
    scan_local<<<NB, 256, 0, stream>>>(deg, row_start, blocksum, n);
    scan_blocks<<<1, 256, 0, stream>>>(blocksum, (int)NB);
    scan_add<<<NB, 256, 0, stream>>>(row_start, cursor, blocksum, n, Esl);
    fill_csr<<<EB, 256, 0, stream>>>(src, dst, cursor, csr_src, E, n);

    // ---------- Layer 1: 128 -> 64 ----------
    gemm_rt<128, 64><<<MB, 128, 0, stream>>>(x, W1, bufA, n, va1, vb1, asv, adv);
    gat_aggregate<64, false><<<WB, 256, 0, stream>>>(row_start, csr_src, asv, adv, bufA, b1, bufB,
                                                     nullptr, nullptr, nullptr, nullptr, n);

    // ---------- Layer 2: 64 -> 128 ----------
    gemm_rt<64, 128><<<MB, 128, 0, stream>>>(bufB, W2, bufA, n, va2, vb2, asv, adv);
    gat_aggregate<128, false><<<WB, 256, 0, stream>>>(row_start, csr_src, asv, adv, bufA, b2, bufB,
                                                      nullptr, nullptr, nullptr, nullptr, n);

    // ---------- Layer 3: 128 -> 128 (+ fused pooling dots) ----------
    gemm_rt<128, 128><<<MB, 128, 0, stream>>>(bufB, W3, bufA, n, va3, vb3, asv, adv);
    gat_aggregate<128, true><<<WB, 256, 0, stream>>>(row_start, csr_src, asv, adv, bufA, b3, bufB,
                                                     wpr, wpo, tsv, tdv, n);

    // ---------- SAGPool score + final linear ----------
    score_csr<<<NB, 256, 0, stream>>>(row_start, csr_src, tsv, tdv, bp, score, n);
    gemm_tile<128, 16, 16><<<MB, 256, 0, stream>>>(bufB, Wlp, (float*)d_out, n, blp, score, 10);
}

// Round 9
// 308.512 us; speedup vs baseline: 3.8315x; 1.0762x over previous
//
#include <hip/hip_runtime.h>
#include <math.h>

// ---------------- register-tiled GEMM v2: C[M,N] = A[M,K] @ B[K,N] ----------------
// BM=64 rows/block, threads = 2N (TC=N/8 cols-threads x TR=16 row-threads).
// Per-thread MR=4 rows x NR=8 cols. Reg->LDS double-buffered staging (chunk k+1
// global loads issued before chunk k math). A transposed in LDS [k][row].
// Optional: input dots (iva/ivb over K -> ioa/iob), epilogue bias+relu (ebias),
// output dots (eva/evb over N -> eoa/eob).
template<int K, int N>
__global__ __launch_bounds__(2 * N) void gemm_rt(
    const float* __restrict__ A, const float* __restrict__ B,
    float* __restrict__ C, int M,
    const float* __restrict__ iva, const float* __restrict__ ivb,
    float* __restrict__ ioa, float* __restrict__ iob,
    const float* __restrict__ ebias,
    const float* __restrict__ eva, const float* __restrict__ evb,
    float* __restrict__ eoa, float* __restrict__ eob)
{
    constexpr int KC = 32;            // k per chunk
    constexpr int NC = K / KC;        // chunks
    constexpr int TC = N / 8;         // 8 (N=64) or 16 (N=128)
    constexpr int NT = 2 * N;         // threads: 128 or 256
    constexpr int KT = KC / TC;       // k-slice per tc for input dots
    constexpr int AST = 68;           // AsT row stride (floats), 16B-aligned, odd/4
    constexpr int A_F4 = 512 / NT;    // A float4s per thread per chunk (4 or 2)
    constexpr int B_F4 = 4;           // B float4s per thread per chunk (8N/(2N))

    __shared__ float AsT[KC * AST];   // [k][row]
    __shared__ float Bs[KC * N];      // [k][col]

    const int tid = threadIdx.x;
    const int base = blockIdx.x * 64;
    const int tc = tid % TC;
    const int tr = tid / TC;          // 0..15

    float acc[4][8];
#pragma unroll
    for (int m = 0; m < 4; ++m)
#pragma unroll
        for (int j = 0; j < 8; ++j) acc[m][j] = 0.f;
    float sa[4], sb[4];
#pragma unroll
    for (int m = 0; m < 4; ++m) { sa[m] = 0.f; sb[m] = 0.f; }

    float4 ra[A_F4], rb[B_F4];

    // ---- stage 0 loads ----
#pragma unroll
    for (int j = 0; j < A_F4; ++j) {
        int i = tid + j * NT; int row = i >> 3; int q = i & 7;
        int gr = base + row;
        ra[j] = (gr < M) ? *(const float4*)(A + (size_t)gr * K + 4 * q)
                         : make_float4(0.f, 0.f, 0.f, 0.f);
    }
#pragma unroll
    for (int j = 0; j < B_F4; ++j) {
        int i = tid + j * NT; int kk_ = i / (N / 4); int c4 = i % (N / 4);
        rb[j] = *(const float4*)(B + (size_t)kk_ * N + 4 * c4);
    }

    for (int ch = 0; ch < NC; ++ch) {
        // ---- write staged regs to LDS ----
#pragma unroll
        for (int j = 0; j < A_F4; ++j) {
            int i = tid + j * NT; int row = i >> 3; int q = i & 7;
            AsT[(4 * q + 0) * AST + row] = ra[j].x;
            AsT[(4 * q + 1) * AST + row] = ra[j].y;
            AsT[(4 * q + 2) * AST + row] = ra[j].z;
            AsT[(4 * q + 3) * AST + row] = ra[j].w;
        }
#pragma unroll
        for (int j = 0; j < B_F4; ++j) {
            int i = tid + j * NT; int kk_ = i / (N / 4); int c4 = i % (N / 4);
            *(float4*)(Bs + kk_ * N + 4 * c4) = rb[j];
        }
        __syncthreads();

        // ---- issue next chunk's global loads (fly under the math) ----
        if (ch + 1 < NC) {
            const int k0 = (ch + 1) * KC;
#pragma unroll
            for (int j = 0; j < A_F4; ++j) {
                int i = tid + j * NT; int row = i >> 3; int q = i & 7;
                int gr = base + row;
                ra[j] = (gr < M) ? *(const float4*)(A + (size_t)gr * K + k0 + 4 * q)
                                 : make_float4(0.f, 0.f, 0.f, 0.f);
            }
#pragma unroll
            for (int j = 0; j < B_F4; ++j) {
                int i = tid + j * NT; int kk_ = i / (N / 4); int c4 = i % (N / 4);
                rb[j] = *(const float4*)(B + (size_t)(k0 + kk_) * N + 4 * c4);
            }
        }

        // ---- math over the LDS chunk ----
#pragma unroll 8
        for (int kk = 0; kk < KC; ++kk) {
            float4 a0 = *(const float4*)(AsT + kk * AST + 4 * tr);
            const float* bp = Bs + kk * N + 8 * tc;
            float4 b0 = *(const float4*)(bp);
            float4 b1 = *(const float4*)(bp + 4);
#pragma unroll
            for (int m = 0; m < 4; ++m) {
                float av = ((const float*)&a0)[m];
                acc[m][0] = fmaf(av, b0.x, acc[m][0]);
                acc[m][1] = fmaf(av, b0.y, acc[m][1]);
                acc[m][2] = fmaf(av, b0.z, acc[m][2]);
                acc[m][3] = fmaf(av, b0.w, acc[m][3]);
                acc[m][4] = fmaf(av, b1.x, acc[m][4]);
                acc[m][5] = fmaf(av, b1.y, acc[m][5]);
                acc[m][6] = fmaf(av, b1.z, acc[m][6]);
                acc[m][7] = fmaf(av, b1.w, acc[m][7]);
            }
        }

        // ---- fused input dots from AsT (tc-partitioned k) ----
        if (iva != nullptr) {
            const int k0 = ch * KC;
#pragma unroll
            for (int kl = 0; kl < KT; ++kl) {
                int k = tc * KT + kl;
                float av_ = iva[k0 + k];
                float bv_ = ivb[k0 + k];
#pragma unroll
                for (int m = 0; m < 4; ++m) {
                    float aval = AsT[k * AST + 4 * tr + m];
                    sa[m] = fmaf(aval, av_, sa[m]);
                    sb[m] = fmaf(aval, bv_, sb[m]);
                }
            }
        }
        __syncthreads();
    }

    // ---- epilogue: optional bias+relu, C write, optional output dots ----
    float pa[4], pb[4];
#pragma unroll
    for (int m = 0; m < 4; ++m) { pa[m] = 0.f; pb[m] = 0.f; }
#pragma unroll
    for (int m = 0; m < 4; ++m) {
        int gr = base + 4 * tr + m;
        float o[8];
#pragma unroll
        for (int j = 0; j < 8; ++j) o[j] = acc[m][j];
        if (ebias != nullptr) {
#pragma unroll
            for (int j = 0; j < 8; ++j) o[j] = fmaxf(o[j] + ebias[8 * tc + j], 0.f);
        }
        if (gr < M) {
            *(float4*)(C + (size_t)gr * N + 8 * tc) = make_float4(o[0], o[1], o[2], o[3]);
            *(float4*)(C + (size_t)gr * N + 8 * tc + 4) = make_float4(o[4], o[5], o[6], o[7]);
        }
        if (eva != nullptr) {
#pragma unroll
            for (int j = 0; j < 8; ++j) {
                pa[m] = fmaf(o[j], eva[8 * tc + j], pa[m]);
                pb[m] = fmaf(o[j], evb[8 * tc + j], pb[m]);
            }
        }
    }
    if (eva != nullptr) {
#pragma unroll
        for (int m = 0; m < 4; ++m) {
#pragma unroll
            for (int off = TC / 2; off; off >>= 1) {
                pa[m] += __shfl_xor(pa[m], off);
                pb[m] += __shfl_xor(pb[m], off);
            }
        }
        if (tc == 0) {
#pragma unroll
            for (int m = 0; m < 4; ++m) {
                int gr = base + 4 * tr + m;
                if (gr < M) { eoa[gr] = pa[m]; eob[gr] = pb[m]; }
            }
        }
    }
    if (iva != nullptr) {
#pragma unroll
        for (int m = 0; m < 4; ++m) {
#pragma unroll
            for (int off = TC / 2; off; off >>= 1) {
                sa[m] += __shfl_xor(sa[m], off);
                sb[m] += __shfl_xor(sb[m], off);
            }
        }
        if (tc == 0) {
#pragma unroll
            for (int m = 0; m < 4; ++m) {
                int gr = base + 4 * tr + m;
                if (gr < M) { ioa[gr] = sa[m]; iob[gr] = sb[m]; }
            }
        }
    }
}

// ---------------- small GEMM (final layer) ----------------
template<int K, int N, int NT>
__global__ __launch_bounds__(256) void gemm_tile(
    const float* __restrict__ A, const float* __restrict__ B,
    float* __restrict__ C, int M,
    const float* __restrict__ bias, const float* __restrict__ score, int outN)
{
    __shared__ float As[64 * K];
    const int tid = threadIdx.x;
    const int base = blockIdx.x * 64;
    for (int idx = tid; idx < 64 * K; idx += 256) {
        int r = idx / K, k = idx - r * K;
        int gr = base + r;
        As[idx] = (gr < M) ? A[(size_t)gr * K + k] : 0.f;
    }
    __syncthreads();
    constexpr int RSTEP = 256 / NT;
    constexpr int NR = 64 / RSTEP;
    const int c = tid % NT;
    const int r0 = tid / NT;
    float acc[NR];
#pragma unroll
    for (int i = 0; i < NR; ++i) acc[i] = 0.f;
    const float4* As4 = reinterpret_cast<const float4*>(As);
    const float* Bc = B + c;
    float b0 = Bc[0 * N], b1 = Bc[1 * N], b2 = Bc[2 * N], b3 = Bc[3 * N];
    for (int k = 0; k < K; k += 4) {
        const int kn = (k + 4 < K) ? (k + 4) : k;
        float n0 = Bc[(kn + 0) * N];
        float n1 = Bc[(kn + 1) * N];
        float n2 = Bc[(kn + 2) * N];
        float n3 = Bc[(kn + 3) * N];
#pragma unroll
        for (int i = 0; i < NR; ++i) {
            float4 a = As4[((r0 + i * RSTEP) * K + k) >> 2];
            acc[i] = fmaf(a.x, b0, acc[i]);
            acc[i] = fmaf(a.y, b1, acc[i]);
            acc[i] = fmaf(a.z, b2, acc[i]);
            acc[i] = fmaf(a.w, b3, acc[i]);
        }
        b0 = n0; b1 = n1; b2 = n2; b3 = n3;
    }
    if (c < outN) {
#pragma unroll
        for (int i = 0; i < NR; ++i) {
            int gr = base + r0 + i * RSTEP;
            if (gr < M) {
                float v = tanhf(score[gr]) * acc[i] + bias[c];
                C[(size_t)gr * outN + c] = fmaxf(v, 0.f);
            }
        }
    }
}

// ---------------- CSR build ----------------
__global__ __launch_bounds__(256) void hist_deg(
    const int* __restrict__ dst, int* __restrict__ deg, int E, int n)
{
    int e = blockIdx.x * 256 + threadIdx.x;
    if (e >= E + n) return;
    int d = (e < E) ? dst[e] : (e - E);
    atomicAdd(deg + d, 1);
}

__global__ __launch_bounds__(256) void scan_local(
    const int* __restrict__ deg, int* __restrict__ row_start, int* __restrict__ blocksum, int n)
{
    __shared__ int s[256];
    const int t = threadIdx.x;
    const int i = blockIdx.x * 256 + t;
    int v = (i < n) ? deg[i] : 0;
    s[t] = v;
    __syncthreads();
#pragma unroll
    for (int off = 1; off < 256; off <<= 1) {
        int u = (t >= off) ? s[t - off] : 0;
        __syncthreads();
        s[t] += u;
        __syncthreads();
    }
    if (i < n) row_start[i] = s[t] - v;
    if (t == 255) blocksum[blockIdx.x] = s[255];
}

__global__ __launch_bounds__(256) void scan_blocks(int* __restrict__ blocksum, int nb)
{
    __shared__ int s[256];
    const int t = threadIdx.x;
    int v = (t < nb) ? blocksum[t] : 0;
    s[t] = v;
    __syncthreads();
#pragma unroll
    for (int off = 1; off < 256; off <<= 1) {
        int u = (t >= off) ? s[t - off] : 0;
        __syncthreads();
        s[t] += u;
        __syncthreads();
    }
    if (t < nb) blocksum[t] = s[t] - v;
}

__global__ __launch_bounds__(256) void scan_add(
    int* __restrict__ row_start, int* __restrict__ cursor,
    const int* __restrict__ blocksum, int n, int total)
{
    const int i = blockIdx.x * 256 + threadIdx.x;
    if (i < n) {
        int v = row_start[i] + blocksum[blockIdx.x];
        row_start[i] = v;
        cursor[i] = v;
    } else if (i == n) {
        row_start[n] = total;
    }
}

__global__ __launch_bounds__(256) void fill_csr(
    const int* __restrict__ src, const int* __restrict__ dst,
    int* __restrict__ cursor, int* __restrict__ csr_src, int E, int n)
{
    int e = blockIdx.x * 256 + threadIdx.x;
    if (e >= E + n) return;
    int s, d;
    if (e < E) { s = src[e]; d = dst[e]; } else { s = d = e - E; }
    int pos = atomicAdd(cursor + d, 1);
    csr_src[pos] = s;
}

// ---------------- fused GAT aggregation: one wave per node ----------------
template<int D, bool POOL>
__global__ __launch_bounds__(256) void gat_aggregate(
    const int* __restrict__ row_start, const int* __restrict__ csr_src,
    const float* __restrict__ asv, const float* __restrict__ adv,
    const float* __restrict__ h, const float* __restrict__ bias,
    float* __restrict__ out,
    const float* __restrict__ wpr, const float* __restrict__ wpo,
    float* __restrict__ poolA, float* __restrict__ poolB, int n)
{
    __shared__ float lds_e[4][128];
    __shared__ int   lds_i[4][128];
    const int node = (blockIdx.x * 256 + threadIdx.x) >> 6;
    const int lane = threadIdx.x & 63;
    const int w = threadIdx.x >> 6;
    if (node >= n) return;
    const int beg = row_start[node];
    const int deg = row_start[node + 1] - beg;
    const float advv = adv[node];
    const bool fast = (deg <= 128);

    float amax = -INFINITY;
    if (fast) {
        for (int j = lane; j < deg; j += 64) {
            int s = csr_src[beg + j];
            lds_i[w][j] = s;
            float a = asv[s] + advv;
            a = (a >= 0.f) ? a : 0.2f * a;
            lds_e[w][j] = a;
            amax = fmaxf(amax, a);
        }
    } else {
        for (int j = lane; j < deg; j += 64) {
            float a = asv[csr_src[beg + j]] + advv;
            a = (a >= 0.f) ? a : 0.2f * a;
            amax = fmaxf(amax, a);
        }
    }
#pragma unroll
    for (int off = 32; off; off >>= 1) amax = fmaxf(amax, __shfl_xor(amax, off));

    float ssum = 0.f;
    if (fast) {
        for (int j = lane; j < deg; j += 64) {
            float ev = expf(lds_e[w][j] - amax);
            lds_e[w][j] = ev;
            ssum += ev;
        }
    } else {
        for (int j = lane; j < deg; j += 64) {
            float a = asv[csr_src[beg + j]] + advv;
            a = (a >= 0.f) ? a : 0.2f * a;
            ssum += expf(a - amax);
        }
    }
#pragma unroll
    for (int off = 32; off; off >>= 1) ssum += __shfl_xor(ssum, off);
    const float inv = 1.f / (ssum + 1e-16f);

    if (fast) {
        if constexpr (D == 128) {
            const float4* h4 = reinterpret_cast<const float4*>(h);
            const int half = lane >> 5;
            const int fl = lane & 31;
            float4 a0 = {0,0,0,0}, a1 = {0,0,0,0}, a2 = {0,0,0,0}, a3 = {0,0,0,0};
            int j = 0;
            for (; j + 8 <= deg; j += 8) {
                int e0 = j + half, e1 = j + 2 + half, e2 = j + 4 + half, e3 = j + 6 + half;
                int s0 = lds_i[w][e0], s1 = lds_i[w][e1], s2 = lds_i[w][e2], s3 = lds_i[w][e3];
                float c0 = lds_e[w][e0] * inv, c1 = lds_e[w][e1] * inv;
                float c2 = lds_e[w][e2] * inv, c3 = lds_e[w][e3] * inv;
                float4 v0 = h4[(size_t)s0 * 32 + fl];
                float4 v1 = h4[(size_t)s1 * 32 + fl];
                float4 v2 = h4[(size_t)s2 * 32 + fl];
                float4 v3 = h4[(size_t)s3 * 32 + fl];
                a0.x = fmaf(v0.x, c0, a0.x); a0.y = fmaf(v0.y, c0, a0.y);
                a0.z = fmaf(v0.z, c0, a0.z); a0.w = fmaf(v0.w, c0, a0.w);
                a1.x = fmaf(v1.x, c1, a1.x); a1.y = fmaf(v1.y, c1, a1.y);
                a1.z = fmaf(v1.z, c1, a1.z); a1.w = fmaf(v1.w, c1, a1.w);
                a2.x = fmaf(v2.x, c2, a2.x); a2.y = fmaf(v2.y, c2, a2.y);
                a2.z = fmaf(v2.z, c2, a2.z); a2.w = fmaf(v2.w, c2, a2.w);
                a3.x = fmaf(v3.x, c3, a3.x); a3.y = fmaf(v3.y, c3, a3.y);
                a3.z = fmaf(v3.z, c3, a3.z); a3.w = fmaf(v3.w, c3, a3.w);
            }
            for (; j < deg; j += 2) {
                int e = j + half;
                bool ok = (e < deg);
                int s = lds_i[w][ok ? e : 0];
                float c = ok ? lds_e[w][e] * inv : 0.f;
                float4 v = h4[(size_t)s * 32 + fl];
                a0.x = fmaf(v.x, c, a0.x); a0.y = fmaf(v.y, c, a0.y);
                a0.z = fmaf(v.z, c, a0.z); a0.w = fmaf(v.w, c, a0.w);
            }
            float4 t;
            t.x = (a0.x + a1.x) + (a2.x + a3.x);
            t.y = (a0.y + a1.y) + (a2.y + a3.y);
            t.z = (a0.z + a1.z) + (a2.z + a3.z);
            t.w = (a0.w + a1.w) + (a2.w + a3.w);
            t.x += __shfl_xor(t.x, 32);
            t.y += __shfl_xor(t.y, 32);
            t.z += __shfl_xor(t.z, 32);
            t.w += __shfl_xor(t.w, 32);
            const float4 b4 = reinterpret_cast<const float4*>(bias)[fl];
            float4 o;
            o.x = fmaxf(t.x + b4.x, 0.f);
            o.y = fmaxf(t.y + b4.y, 0.f);
            o.z = fmaxf(t.z + b4.z, 0.f);
            o.w = fmaxf(t.w + b4.w, 0.f);
            if (half == 0)
                reinterpret_cast<float4*>(out)[(size_t)node * 32 + fl] = o;
            if constexpr (POOL) {
                const float4 r4 = reinterpret_cast<const float4*>(wpr)[fl];
                const float4 q4 = reinterpret_cast<const float4*>(wpo)[fl];
                float pa = o.x * r4.x + o.y * r4.y + o.z * r4.z + o.w * r4.w;
                float pb = o.x * q4.x + o.y * q4.y + o.z * q4.z + o.w * q4.w;
#pragma unroll
                for (int off = 16; off; off >>= 1) {
                    pa += __shfl_xor(pa, off);
                    pb += __shfl_xor(pb, off);
                }
                if (lane == 0) { poolA[node] = pa; poolB[node] = pb; }
            }
        } else {
            const float4* h4 = reinterpret_cast<const float4*>(h);
            const int q = lane >> 4;
            const int fl = lane & 15;
            float4 a0 = {0,0,0,0}, a1 = {0,0,0,0};
            int j = 0;
            for (; j + 8 <= deg; j += 8) {
                int e0 = j + q, e1 = j + 4 + q;
                int s0 = lds_i[w][e0], s1 = lds_i[w][e1];
                float c0 = lds_e[w][e0] * inv, c1 = lds_e[w][e1] * inv;
                float4 v0 = h4[(size_t)s0 * 16 + fl];
                float4 v1 = h4[(size_t)s1 * 16 + fl];
                a0.x = fmaf(v0.x, c0, a0.x); a0.y = fmaf(v0.y, c0, a0.y);
                a0.z = fmaf(v0.z, c0, a0.z); a0.w = fmaf(v0.w, c0, a0.w);
                a1.x = fmaf(v1.x, c1, a1.x); a1.y = fmaf(v1.y, c1, a1.y);
                a1.z = fmaf(v1.z, c1, a1.z); a1.w = fmaf(v1.w, c1, a1.w);
            }
            for (; j < deg; j += 4) {
                int e = j + q;
                bool ok = (e < deg);
                int s = lds_i[w][ok ? e : 0];
                float c = ok ? lds_e[w][e] * inv : 0.f;
                float4 v = h4[(size_t)s * 16 + fl];
                a0.x = fmaf(v.x, c, a0.x); a0.y = fmaf(v.y, c, a0.y);
                a0.z = fmaf(v.z, c, a0.z); a0.w = fmaf(v.w, c, a0.w);
            }
            float4 t;
            t.x = a0.x + a1.x; t.y = a0.y + a1.y; t.z = a0.z + a1.z; t.w = a0.w + a1.w;
            t.x += __shfl_xor(t.x, 16); t.x += __shfl_xor(t.x, 32);
            t.y += __shfl_xor(t.y, 16); t.y += __shfl_xor(t.y, 32);
            t.z += __shfl_xor(t.z, 16); t.z += __shfl_xor(t.z, 32);
            t.w += __shfl_xor(t.w, 16); t.w += __shfl_xor(t.w, 32);
            const float4 b4 = reinterpret_cast<const float4*>(bias)[fl];
            float4 o;
            o.x = fmaxf(t.x + b4.x, 0.f);
            o.y = fmaxf(t.y + b4.y, 0.f);
            o.z = fmaxf(t.z + b4.z, 0.f);
            o.w = fmaxf(t.w + b4.w, 0.f);
            if (q == 0)
                reinterpret_cast<float4*>(out)[(size_t)node * 16 + fl] = o;
        }
    } else {
        if constexpr (D == 128) {
            const float2* h2 = reinterpret_cast<const float2*>(h);
            float2 a0 = {0.f, 0.f};
            for (int j = 0; j < deg; ++j) {
                int s = csr_src[beg + j];
                float a = asv[s] + advv;
                a = (a >= 0.f) ? a : 0.2f * a;
                float c = expf(a - amax) * inv;
                float2 v = h2[(size_t)s * 64 + lane];
                a0.x = fmaf(v.x, c, a0.x); a0.y = fmaf(v.y, c, a0.y);
            }
            float2 o;
            o.x = fmaxf(a0.x + bias[2 * lane], 0.f);
            o.y = fmaxf(a0.y + bias[2 * lane + 1], 0.f);
            reinterpret_cast<float2*>(out)[(size_t)node * 64 + lane] = o;
            if constexpr (POOL) {
                float pa = fmaf(o.x, wpr[2 * lane], o.y * wpr[2 * lane + 1]);
                float pb = fmaf(o.x, wpo[2 * lane], o.y * wpo[2 * lane + 1]);
#pragma unroll
                for (int off = 32; off; off >>= 1) {
                    pa += __shfl_xor(pa, off);
                    pb += __shfl_xor(pb, off);
                }
                if (lane == 0) { poolA[node] = pa; poolB[node] = pb; }
            }
        } else {
            float a0 = 0.f;
            for (int j = 0; j < deg; ++j) {
                int s = csr_src[beg + j];
                float a = asv[s] + advv;
                a = (a >= 0.f) ? a : 0.2f * a;
                float c = expf(a - amax) * inv;
                a0 = fmaf(h[(size_t)s * D + lane], c, a0);
            }
            out[(size_t)node * D + lane] = fmaxf(a0 + bias[lane], 0.f);
        }
    }
}

// ---------------- pooling score via CSR ----------------
__global__ __launch_bounds__(256) void score_csr(
    const int* __restrict__ row_start, const int* __restrict__ csr_src,
    const float* __restrict__ ts, const float* __restrict__ td,
    const float* __restrict__ bp, float* __restrict__ score, int n)
{
    int i = blockIdx.x * 256 + threadIdx.x;
    if (i >= n) return;
    int beg = row_start[i], end = row_start[i + 1];
    float s = td[i] + bp[0] - ts[i];
    for (int j = beg; j < end; ++j) s += ts[csr_src[j]];
    score[i] = s;
}

// ---------------- precompute: va_l = W_l @ a; pad Wl/bl; zero deg ----------------
__global__ __launch_bounds__(256) void precompute(
    const float* __restrict__ W1, const float* __restrict__ a1s, const float* __restrict__ a1d,
    const float* __restrict__ W2, const float* __restrict__ a2s, const float* __restrict__ a2d,
    const float* __restrict__ W3, const float* __restrict__ a3s, const float* __restrict__ a3d,
    const float* __restrict__ Wl, const float* __restrict__ bl,
    float* __restrict__ va1, float* __restrict__ vb1,
    float* __restrict__ va2, float* __restrict__ vb2,
    float* __restrict__ va3, float* __restrict__ vb3,
    float* __restrict__ Wlp, float* __restrict__ blp,
    int* __restrict__ deg, int n)
{
    int t = blockIdx.x * 256 + threadIdx.x;
    if (t < n) deg[t] = 0;
    if (t < 128) {
        float sa = 0.f, sb = 0.f;
        for (int j = 0; j < 64; ++j) {
            float w = W1[t * 64 + j];
            sa = fmaf(w, a1s[j], sa); sb = fmaf(w, a1d[j], sb);
        }
        va1[t] = sa; vb1[t] = sb;
    } else if (t < 192) {
        int k = t - 128;
        float sa = 0.f, sb = 0.f;
        for (int j = 0; j < 128; ++j) {
            float w = W2[k * 128 + j];
            sa = fmaf(w, a2s[j], sa); sb = fmaf(w, a2d[j], sb);
        }
        va2[k] = sa; vb2[k] = sb;
    } else if (t < 320) {
        int k = t - 192;
        float sa = 0.f, sb = 0.f;
        for (int j = 0; j < 128; ++j) {
            float w = W3[k * 128 + j];
            sa = fmaf(w, a3s[j], sa); sb = fmaf(w, a3d[j], sb);
        }
        va3[k] = sa; vb3[k] = sb;
    } else if (t < 320 + 2048) {
        int i = t - 320;
        int k = i >> 4, c = i & 15;
        Wlp[i] = (c < 10) ? Wl[k * 10 + c] : 0.f;
    } else if (t < 320 + 2048 + 16) {
        int c = t - (320 + 2048);
        blp[c] = (c < 10) ? bl[c] : 0.f;
    }
}

extern "C" void kernel_launch(void* const* d_in, const int* in_sizes, int n_in,
                              void* d_out, int out_size, void* d_ws, size_t ws_size,
                              hipStream_t stream) {
    const float* x   = (const float*)d_in[0];
    const int*   ei  = (const int*)d_in[1];
    const float* W1  = (const float*)d_in[4];
    const float* a1s = (const float*)d_in[5];
    const float* a1d = (const float*)d_in[6];
    const float* b1  = (const float*)d_in[7];
    const float* W2  = (const float*)d_in[8];
    const float* a2s = (const float*)d_in[9];
    const float* a2d = (const float*)d_in[10];
    const float* b2  = (const float*)d_in[11];
    const float* W3  = (const float*)d_in[12];
    const float* a3s = (const float*)d_in[13];
    const float* a3d = (const float*)d_in[14];
    const float* b3  = (const float*)d_in[15];
    const float* wpr = (const float*)d_in[16];
    const float* wpo = (const float*)d_in[17];
    const float* bp  = (const float*)d_in[18];
    const float* Wl  = (const float*)d_in[19];
    const float* bl  = (const float*)d_in[20];

    const int n = in_sizes[0] / 128;   // 40000
    const int E = in_sizes[1] / 2;     // 640000
    const int Esl = E + n;
    const int* src = ei;
    const int* dst = ei + E;

    float* ws = (float*)d_ws;
    const size_t nd = (size_t)n * 128;
    float* bufA      = ws;                          // [n,128]
    float* bufB      = bufA + nd;                   // [n,128]
    float* asv       = bufB + nd;                   // [n]
    float* adv       = asv + n;                     // [n]
    float* tsv       = adv + n;                     // [n]
    float* tdv       = tsv + n;                     // [n]
    float* score     = tdv + n;                     // [n]
    int*   deg       = (int*)(score + n);           // [n]
    int*   row_start = deg + n;                     // [n+1]
    int*   cursor    = row_start + n + 1;           // [n]
    int*   blocksum  = cursor + n;                  // [<=256]
    int*   csr_src   = blocksum + 256;              // [Esl]
    float* va1       = (float*)(csr_src + Esl);     // [128]
    float* vb1       = va1 + 128;                   // [128]
    float* va2       = vb1 + 128;                   // [64]
    float* vb2       = va2 + 64;                    // [64]
    float* va3       = vb2 + 64;                    // [128]
    float* vb3       = va3 + 128;                   // [128]
    float* Wlp       = vb3 + 128;                   // [128*16]
    float* blp       = Wlp + 128 * 16;              // [16]

    const unsigned EB = (unsigned)((Esl + 255) / 256);
    const unsigned NB = (unsigned)((n + 255) / 256);
    const unsigned MB = (unsigned)((n + 63) / 64);   // 625
    const unsigned WB = (unsigned)(((size_t)n * 64 + 255) / 256);

    // ---------- precompute (+deg zero) + CSR build ----------
    precompute<<<NB, 256, 0, stream>>>(W1, a1s, a1d, W2, a2s, a2d, W3, a3s, a3d, Wl, bl,
                                       va1, vb1, va2, vb2, va3, vb3, Wlp, blp, deg, n);
    hist_deg<<<EB, 256, 0, stream>>>(dst, deg, E, n);
    scan_local<<<NB, 256, 0, stream>>>(deg, row_start, blocksum, n);
    scan_blocks<<<1, 256, 0, stream>>>(blocksum, (int)NB);
    scan_add<<<NB, 256, 0, stream>>>(row_start, cursor, blocksum, n, Esl);
    fill_csr<<<EB, 256, 0, stream>>>(src, dst, cursor, csr_src, E, n);

    // ---------- Layer 1: 128 -> 64 ----------
    gemm_rt<128, 64><<<MB, 128, 0, stream>>>(
        x, W1, bufA, n, va1, vb1, asv, adv, nullptr, nullptr, nullptr, nullptr, nullptr);
    gat_aggregate<64, false><<<WB, 256, 0, stream>>>(row_start, csr_src, asv, adv, bufA, b1, bufB,
                                                     nullptr, nullptr, nullptr, nullptr, n);

    // ---------- Layer 2: 64 -> 128 ----------
    gemm_rt<64, 128><<<MB, 256, 0, stream>>>(
        bufB, W2, bufA, n, va2, vb2, asv, adv, nullptr, nullptr, nullptr, nullptr, nullptr);
    gat_aggregate<128, false><<<WB, 256, 0, stream>>>(row_start, csr_src, asv, adv, bufA, b2, bufB,
                                                      nullptr, nullptr, nullptr, nullptr, n);

    // ---------- Layer 3: 128 -> 128 ----------
    gemm_rt<128, 128><<<MB, 256, 0, stream>>>(
        bufB, W3, bufA, n, va3, vb3, asv, adv, nullptr, nullptr, nullptr, nullptr, nullptr);
    gat_aggregate<128, true><<<WB, 256, 0, stream>>>(row_start, csr_src, asv, adv, bufA, b3, bufB,
                                                     wpr, wpo, tsv, tdv, n);

    // ---------- SAGPool score + final linear ----------
    score_csr<<<NB, 256, 0, stream>>>(row_start, csr_src, tsv, tdv, bp, score, n);
    gemm_tile<128, 16, 16><<<MB, 256, 0, stream>>>(bufB, Wlp, (float*)d_out, n, blp, score, 10);
}

// Round 10
// 296.256 us; speedup vs baseline: 3.9900x; 1.0414x over previous
//
#include <hip/hip_runtime.h>
#include <math.h>

// ---------------- register-tiled GEMM: C[M,N] = A[M,K] @ B[K,N] ----------------
// BM=64 rows/block, CPB cols/block (gridDim.y = N/CPB). 2*CPB threads,
// per-thread MR=4 rows x 8 cols. Reg->LDS double-buffered staging.
// iva != nullptr (y==0 only): input dots ioa[r]=A_row.iva, iob[r]=A_row.ivb.
template<int K, int N, int CPB>
__global__ __launch_bounds__(2 * CPB) void gemm_rt(
    const float* __restrict__ A, const float* __restrict__ B,
    float* __restrict__ C, int M,
    const float* __restrict__ iva, const float* __restrict__ ivb,
    float* __restrict__ ioa, float* __restrict__ iob)
{
    constexpr int KC = 32;            // k per chunk
    constexpr int NC = K / KC;        // chunks
    constexpr int TC = CPB / 8;       // col-threads (8)
    constexpr int NT = 2 * CPB;       // threads (128)
    constexpr int KT = KC / TC;       // k-slice per tc for input dots
    constexpr int AST = 68;           // AsT row stride
    constexpr int A_F4 = 512 / NT;    // A float4s/thread/chunk
    constexpr int B_F4 = (KC * CPB / 4) / NT;  // B float4s/thread/chunk

    __shared__ float AsT[KC * AST];   // [k][row]
    __shared__ float Bs[KC * CPB];    // [k][col]

    const int tid = threadIdx.x;
    const int base = blockIdx.x * 64;
    const int col0 = blockIdx.y * CPB;
    const int tc = tid % TC;
    const int tr = tid / TC;          // 0..15

    float acc[4][8];
#pragma unroll
    for (int m = 0; m < 4; ++m)
#pragma unroll
        for (int j = 0; j < 8; ++j) acc[m][j] = 0.f;
    float sa[4], sb[4];
#pragma unroll
    for (int m = 0; m < 4; ++m) { sa[m] = 0.f; sb[m] = 0.f; }

    float4 ra[A_F4], rb[B_F4];

#pragma unroll
    for (int j = 0; j < A_F4; ++j) {
        int i = tid + j * NT; int row = i >> 3; int q = i & 7;
        int gr = base + row;
        ra[j] = (gr < M) ? *(const float4*)(A + (size_t)gr * K + 4 * q)
                         : make_float4(0.f, 0.f, 0.f, 0.f);
    }
#pragma unroll
    for (int j = 0; j < B_F4; ++j) {
        int i = tid + j * NT; int kk_ = i / (CPB / 4); int c4 = i % (CPB / 4);
        rb[j] = *(const float4*)(B + (size_t)kk_ * N + col0 + 4 * c4);
    }

    for (int ch = 0; ch < NC; ++ch) {
#pragma unroll
        for (int j = 0; j < A_F4; ++j) {
            int i = tid + j * NT; int row = i >> 3; int q = i & 7;
            AsT[(4 * q + 0) * AST + row] = ra[j].x;
            AsT[(4 * q + 1) * AST + row] = ra[j].y;
            AsT[(4 * q + 2) * AST + row] = ra[j].z;
            AsT[(4 * q + 3) * AST + row] = ra[j].w;
        }
#pragma unroll
        for (int j = 0; j < B_F4; ++j) {
            int i = tid + j * NT; int kk_ = i / (CPB / 4); int c4 = i % (CPB / 4);
            *(float4*)(Bs + kk_ * CPB + 4 * c4) = rb[j];
        }
        __syncthreads();

        if (ch + 1 < NC) {
            const int k0 = (ch + 1) * KC;
#pragma unroll
            for (int j = 0; j < A_F4; ++j) {
                int i = tid + j * NT; int row = i >> 3; int q = i & 7;
                int gr = base + row;
                ra[j] = (gr < M) ? *(const float4*)(A + (size_t)gr * K + k0 + 4 * q)
                                 : make_float4(0.f, 0.f, 0.f, 0.f);
            }
#pragma unroll
            for (int j = 0; j < B_F4; ++j) {
                int i = tid + j * NT; int kk_ = i / (CPB / 4); int c4 = i % (CPB / 4);
                rb[j] = *(const float4*)(B + (size_t)(k0 + kk_) * N + col0 + 4 * c4);
            }
        }

#pragma unroll 8
        for (int kk = 0; kk < KC; ++kk) {
            float4 a0 = *(const float4*)(AsT + kk * AST + 4 * tr);
            const float* bp = Bs + kk * CPB + 8 * tc;
            float4 b0 = *(const float4*)(bp);
            float4 b1 = *(const float4*)(bp + 4);
#pragma unroll
            for (int m = 0; m < 4; ++m) {
                float av = ((const float*)&a0)[m];
                acc[m][0] = fmaf(av, b0.x, acc[m][0]);
                acc[m][1] = fmaf(av, b0.y, acc[m][1]);
                acc[m][2] = fmaf(av, b0.z, acc[m][2]);
                acc[m][3] = fmaf(av, b0.w, acc[m][3]);
                acc[m][4] = fmaf(av, b1.x, acc[m][4]);
                acc[m][5] = fmaf(av, b1.y, acc[m][5]);
                acc[m][6] = fmaf(av, b1.z, acc[m][6]);
                acc[m][7] = fmaf(av, b1.w, acc[m][7]);
            }
        }

        if (iva != nullptr && blockIdx.y == 0) {
            const int k0 = ch * KC;
#pragma unroll
            for (int kl = 0; kl < KT; ++kl) {
                int k = tc * KT + kl;
                float av_ = iva[k0 + k];
                float bv_ = ivb[k0 + k];
#pragma unroll
                for (int m = 0; m < 4; ++m) {
                    float aval = AsT[k * AST + 4 * tr + m];
                    sa[m] = fmaf(aval, av_, sa[m]);
                    sb[m] = fmaf(aval, bv_, sb[m]);
                }
            }
        }
        __syncthreads();
    }

#pragma unroll
    for (int m = 0; m < 4; ++m) {
        int gr = base + 4 * tr + m;
        if (gr < M) {
            *(float4*)(C + (size_t)gr * N + col0 + 8 * tc) =
                make_float4(acc[m][0], acc[m][1], acc[m][2], acc[m][3]);
            *(float4*)(C + (size_t)gr * N + col0 + 8 * tc + 4) =
                make_float4(acc[m][4], acc[m][5], acc[m][6], acc[m][7]);
        }
    }
    if (iva != nullptr && blockIdx.y == 0) {
#pragma unroll
        for (int m = 0; m < 4; ++m) {
#pragma unroll
            for (int off = TC / 2; off; off >>= 1) {
                sa[m] += __shfl_xor(sa[m], off);
                sb[m] += __shfl_xor(sb[m], off);
            }
        }
        if (tc == 0) {
#pragma unroll
            for (int m = 0; m < 4; ++m) {
                int gr = base + 4 * tr + m;
                if (gr < M) { ioa[gr] = sa[m]; iob[gr] = sb[m]; }
            }
        }
    }
}

// ---------------- small GEMM (final layer) ----------------
template<int K, int N, int NT>
__global__ __launch_bounds__(256) void gemm_tile(
    const float* __restrict__ A, const float* __restrict__ B,
    float* __restrict__ C, int M,
    const float* __restrict__ bias, const float* __restrict__ score, int outN)
{
    __shared__ float As[64 * K];
    const int tid = threadIdx.x;
    const int base = blockIdx.x * 64;
    for (int idx = tid; idx < 64 * K; idx += 256) {
        int r = idx / K, k = idx - r * K;
        int gr = base + r;
        As[idx] = (gr < M) ? A[(size_t)gr * K + k] : 0.f;
    }
    __syncthreads();
    constexpr int RSTEP = 256 / NT;
    constexpr int NR = 64 / RSTEP;
    const int c = tid % NT;
    const int r0 = tid / NT;
    float acc[NR];
#pragma unroll
    for (int i = 0; i < NR; ++i) acc[i] = 0.f;
    const float4* As4 = reinterpret_cast<const float4*>(As);
    const float* Bc = B + c;
    float b0 = Bc[0 * N], b1 = Bc[1 * N], b2 = Bc[2 * N], b3 = Bc[3 * N];
    for (int k = 0; k < K; k += 4) {
        const int kn = (k + 4 < K) ? (k + 4) : k;
        float n0 = Bc[(kn + 0) * N];
        float n1 = Bc[(kn + 1) * N];
        float n2 = Bc[(kn + 2) * N];
        float n3 = Bc[(kn + 3) * N];
#pragma unroll
        for (int i = 0; i < NR; ++i) {
            float4 a = As4[((r0 + i * RSTEP) * K + k) >> 2];
            acc[i] = fmaf(a.x, b0, acc[i]);
            acc[i] = fmaf(a.y, b1, acc[i]);
            acc[i] = fmaf(a.z, b2, acc[i]);
            acc[i] = fmaf(a.w, b3, acc[i]);
        }
        b0 = n0; b1 = n1; b2 = n2; b3 = n3;
    }
    if (c < outN) {
#pragma unroll
        for (int i = 0; i < NR; ++i) {
            int gr = base + r0 + i * RSTEP;
            if (gr < M) {
                float v = tanhf(score[gr]) * acc[i] + bias[c];
                C[(size_t)gr * outN + c] = fmaxf(v, 0.f);
            }
        }
    }
}

// ---------------- CSR build (ORIGINAL edges only; self-loops handled in-kernel) ----------------
__global__ __launch_bounds__(256) void hist_deg(
    const int* __restrict__ dst, int* __restrict__ deg, int E)
{
    int e = blockIdx.x * 256 + threadIdx.x;
    if (e < E) atomicAdd(deg + dst[e], 1);
}

__global__ __launch_bounds__(256) void scan_local(
    const int* __restrict__ deg, int* __restrict__ row_start, int* __restrict__ blocksum, int n)
{
    __shared__ int s[256];
    const int t = threadIdx.x;
    const int i = blockIdx.x * 256 + t;
    int v = (i < n) ? deg[i] : 0;
    s[t] = v;
    __syncthreads();
#pragma unroll
    for (int off = 1; off < 256; off <<= 1) {
        int u = (t >= off) ? s[t - off] : 0;
        __syncthreads();
        s[t] += u;
        __syncthreads();
    }
    if (i < n) row_start[i] = s[t] - v;
    if (t == 255) blocksum[blockIdx.x] = s[255];
}

__global__ __launch_bounds__(256) void scan_blocks(int* __restrict__ blocksum, int nb)
{
    __shared__ int s[256];
    const int t = threadIdx.x;
    int v = (t < nb) ? blocksum[t] : 0;
    s[t] = v;
    __syncthreads();
#pragma unroll
    for (int off = 1; off < 256; off <<= 1) {
        int u = (t >= off) ? s[t - off] : 0;
        __syncthreads();
        s[t] += u;
        __syncthreads();
    }
    if (t < nb) blocksum[t] = s[t] - v;
}

__global__ __launch_bounds__(256) void scan_add(
    int* __restrict__ row_start, int* __restrict__ cursor,
    const int* __restrict__ blocksum, int n, int total)
{
    const int i = blockIdx.x * 256 + threadIdx.x;
    if (i < n) {
        int v = row_start[i] + blocksum[blockIdx.x];
        row_start[i] = v;
        cursor[i] = v;
    } else if (i == n) {
        row_start[n] = total;
    }
}

__global__ __launch_bounds__(256) void fill_csr(
    const int* __restrict__ src, const int* __restrict__ dst,
    int* __restrict__ cursor, int* __restrict__ csr_src, int E)
{
    int e = blockIdx.x * 256 + threadIdx.x;
    if (e >= E) return;
    int pos = atomicAdd(cursor + dst[e], 1);
    csr_src[pos] = src[e];
}

// ---------------- fused GAT aggregation: one wave per node ----------------
// Merged exp+sum pass (no max subtraction: coef = exp(a)/Sum exp(a), exact in
// real arithmetic since exp(a-m)/Sum exp(a-m) cancels m; alpha bounded ~|2|).
// Self-loop handled in-register (CSR holds original edges only).
template<int D, bool POOL>
__global__ __launch_bounds__(256) void gat_aggregate(
    const int* __restrict__ row_start, const int* __restrict__ csr_src,
    const float* __restrict__ asv, const float* __restrict__ adv,
    const float* __restrict__ h, const float* __restrict__ bias,
    float* __restrict__ out,
    const float* __restrict__ wpr, const float* __restrict__ wpo,
    float* __restrict__ poolA, float* __restrict__ poolB, int n)
{
    __shared__ float lds_e[4][128];
    __shared__ int   lds_i[4][128];
    const int node = (blockIdx.x * 256 + threadIdx.x) >> 6;
    const int lane = threadIdx.x & 63;
    const int w = threadIdx.x >> 6;
    if (node >= n) return;
    const int beg = row_start[node];
    const int deg = row_start[node + 1] - beg;
    const float advv = adv[node];
    const bool fast = (deg <= 128);

    // self-loop term
    float a_self = asv[node] + advv;
    a_self = (a_self >= 0.f) ? a_self : 0.2f * a_self;
    const float ev_self = expf(a_self);

    // single pass: stage idx + exp(alpha) in LDS, accumulate sum
    float ssum = (lane == 0) ? ev_self : 0.f;
    if (fast) {
        for (int j = lane; j < deg; j += 64) {
            int s = csr_src[beg + j];
            lds_i[w][j] = s;
            float a = asv[s] + advv;
            a = (a >= 0.f) ? a : 0.2f * a;
            float ev = expf(a);
            lds_e[w][j] = ev;
            ssum += ev;
        }
    } else {
        for (int j = lane; j < deg; j += 64) {
            float a = asv[csr_src[beg + j]] + advv;
            a = (a >= 0.f) ? a : 0.2f * a;
            ssum += expf(a);
        }
    }
#pragma unroll
    for (int off = 32; off; off >>= 1) ssum += __shfl_xor(ssum, off);
    const float inv = 1.f / (ssum + 1e-16f);

    if (fast) {
        if constexpr (D == 128) {
            const float4* h4 = reinterpret_cast<const float4*>(h);
            const int half = lane >> 5;
            const int fl = lane & 31;
            float4 a0 = {0,0,0,0}, a1 = {0,0,0,0}, a2 = {0,0,0,0}, a3 = {0,0,0,0};
            int j = 0;
            for (; j + 8 <= deg; j += 8) {
                int e0 = j + half, e1 = j + 2 + half, e2 = j + 4 + half, e3 = j + 6 + half;
                int s0 = lds_i[w][e0], s1 = lds_i[w][e1], s2 = lds_i[w][e2], s3 = lds_i[w][e3];
                float c0 = lds_e[w][e0] * inv, c1 = lds_e[w][e1] * inv;
                float c2 = lds_e[w][e2] * inv, c3 = lds_e[w][e3] * inv;
                float4 v0 = h4[(size_t)s0 * 32 + fl];
                float4 v1 = h4[(size_t)s1 * 32 + fl];
                float4 v2 = h4[(size_t)s2 * 32 + fl];
                float4 v3 = h4[(size_t)s3 * 32 + fl];
                a0.x = fmaf(v0.x, c0, a0.x); a0.y = fmaf(v0.y, c0, a0.y);
                a0.z = fmaf(v0.z, c0, a0.z); a0.w = fmaf(v0.w, c0, a0.w);
                a1.x = fmaf(v1.x, c1, a1.x); a1.y = fmaf(v1.y, c1, a1.y);
                a1.z = fmaf(v1.z, c1, a1.z); a1.w = fmaf(v1.w, c1, a1.w);
                a2.x = fmaf(v2.x, c2, a2.x); a2.y = fmaf(v2.y, c2, a2.y);
                a2.z = fmaf(v2.z, c2, a2.z); a2.w = fmaf(v2.w, c2, a2.w);
                a3.x = fmaf(v3.x, c3, a3.x); a3.y = fmaf(v3.y, c3, a3.y);
                a3.z = fmaf(v3.z, c3, a3.z); a3.w = fmaf(v3.w, c3, a3.w);
            }
            for (; j < deg; j += 2) {
                int e = j + half;
                bool ok = (e < deg);
                int s = lds_i[w][ok ? e : 0];
                float c = ok ? lds_e[w][e] * inv : 0.f;
                float4 v = h4[(size_t)s * 32 + fl];
                a0.x = fmaf(v.x, c, a0.x); a0.y = fmaf(v.y, c, a0.y);
                a0.z = fmaf(v.z, c, a0.z); a0.w = fmaf(v.w, c, a0.w);
            }
            {   // self-loop (half 0 only; counted once)
                float c = (half == 0) ? ev_self * inv : 0.f;
                float4 v = h4[(size_t)node * 32 + fl];
                a1.x = fmaf(v.x, c, a1.x); a1.y = fmaf(v.y, c, a1.y);
                a1.z = fmaf(v.z, c, a1.z); a1.w = fmaf(v.w, c, a1.w);
            }
            float4 t;
            t.x = (a0.x + a1.x) + (a2.x + a3.x);
            t.y = (a0.y + a1.y) + (a2.y + a3.y);
            t.z = (a0.z + a1.z) + (a2.z + a3.z);
            t.w = (a0.w + a1.w) + (a2.w + a3.w);
            t.x += __shfl_xor(t.x, 32);
            t.y += __shfl_xor(t.y, 32);
            t.z += __shfl_xor(t.z, 32);
            t.w += __shfl_xor(t.w, 32);
            const float4 b4 = reinterpret_cast<const float4*>(bias)[fl];
            float4 o;
            o.x = fmaxf(t.x + b4.x, 0.f);
            o.y = fmaxf(t.y + b4.y, 0.f);
            o.z = fmaxf(t.z + b4.z, 0.f);
            o.w = fmaxf(t.w + b4.w, 0.f);
            if (half == 0)
                reinterpret_cast<float4*>(out)[(size_t)node * 32 + fl] = o;
            if constexpr (POOL) {
                const float4 r4 = reinterpret_cast<const float4*>(wpr)[fl];
                const float4 q4 = reinterpret_cast<const float4*>(wpo)[fl];
                float pa = o.x * r4.x + o.y * r4.y + o.z * r4.z + o.w * r4.w;
                float pb = o.x * q4.x + o.y * q4.y + o.z * q4.z + o.w * q4.w;
#pragma unroll
                for (int off = 16; off; off >>= 1) {
                    pa += __shfl_xor(pa, off);
                    pb += __shfl_xor(pb, off);
                }
                if (lane == 0) { poolA[node] = pa; poolB[node] = pb; }
            }
        } else {
            const float4* h4 = reinterpret_cast<const float4*>(h);
            const int q = lane >> 4;
            const int fl = lane & 15;
            float4 a0 = {0,0,0,0}, a1 = {0,0,0,0};
            int j = 0;
            for (; j + 8 <= deg; j += 8) {
                int e0 = j + q, e1 = j + 4 + q;
                int s0 = lds_i[w][e0], s1 = lds_i[w][e1];
                float c0 = lds_e[w][e0] * inv, c1 = lds_e[w][e1] * inv;
                float4 v0 = h4[(size_t)s0 * 16 + fl];
                float4 v1 = h4[(size_t)s1 * 16 + fl];
                a0.x = fmaf(v0.x, c0, a0.x); a0.y = fmaf(v0.y, c0, a0.y);
                a0.z = fmaf(v0.z, c0, a0.z); a0.w = fmaf(v0.w, c0, a0.w);
                a1.x = fmaf(v1.x, c1, a1.x); a1.y = fmaf(v1.y, c1, a1.y);
                a1.z = fmaf(v1.z, c1, a1.z); a1.w = fmaf(v1.w, c1, a1.w);
            }
            for (; j < deg; j += 4) {
                int e = j + q;
                bool ok = (e < deg);
                int s = lds_i[w][ok ? e : 0];
                float c = ok ? lds_e[w][e] * inv : 0.f;
                float4 v = h4[(size_t)s * 16 + fl];
                a0.x = fmaf(v.x, c, a0.x); a0.y = fmaf(v.y, c, a0.y);
                a0.z = fmaf(v.z, c, a0.z); a0.w = fmaf(v.w, c, a0.w);
            }
            {   // self-loop (q 0 only)
                float c = (q == 0) ? ev_self * inv : 0.f;
                float4 v = h4[(size_t)node * 16 + fl];
                a1.x = fmaf(v.x, c, a1.x); a1.y = fmaf(v.y, c, a1.y);
                a1.z = fmaf(v.z, c, a1.z); a1.w = fmaf(v.w, c, a1.w);
            }
            float4 t;
            t.x = a0.x + a1.x; t.y = a0.y + a1.y; t.z = a0.z + a1.z; t.w = a0.w + a1.w;
            t.x += __shfl_xor(t.x, 16); t.x += __shfl_xor(t.x, 32);
            t.y += __shfl_xor(t.y, 16); t.y += __shfl_xor(t.y, 32);
            t.z += __shfl_xor(t.z, 16); t.z += __shfl_xor(t.z, 32);
            t.w += __shfl_xor(t.w, 16); t.w += __shfl_xor(t.w, 32);
            const float4 b4 = reinterpret_cast<const float4*>(bias)[fl];
            float4 o;
            o.x = fmaxf(t.x + b4.x, 0.f);
            o.y = fmaxf(t.y + b4.y, 0.f);
            o.z = fmaxf(t.z + b4.z, 0.f);
            o.w = fmaxf(t.w + b4.w, 0.f);
            if (q == 0)
                reinterpret_cast<float4*>(out)[(size_t)node * 16 + fl] = o;
        }
    } else {
        // slow path (deg > 128): recompute exp per edge
        if constexpr (D == 128) {
            const float2* h2 = reinterpret_cast<const float2*>(h);
            float2 a0 = {0.f, 0.f};
            for (int j = 0; j < deg; ++j) {
                int s = csr_src[beg + j];
                float a = asv[s] + advv;
                a = (a >= 0.f) ? a : 0.2f * a;
                float c = expf(a) * inv;
                float2 v = h2[(size_t)s * 64 + lane];
                a0.x = fmaf(v.x, c, a0.x); a0.y = fmaf(v.y, c, a0.y);
            }
            {
                float c = ev_self * inv;
                float2 v = h2[(size_t)node * 64 + lane];
                a0.x = fmaf(v.x, c, a0.x); a0.y = fmaf(v.y, c, a0.y);
            }
            float2 o;
            o.x = fmaxf(a0.x + bias[2 * lane], 0.f);
            o.y = fmaxf(a0.y + bias[2 * lane + 1], 0.f);
            reinterpret_cast<float2*>(out)[(size_t)node * 64 + lane] = o;
            if constexpr (POOL) {
                float pa = fmaf(o.x, wpr[2 * lane], o.y * wpr[2 * lane + 1]);
                float pb = fmaf(o.x, wpo[2 * lane], o.y * wpo[2 * lane + 1]);
#pragma unroll
                for (int off = 32; off; off >>= 1) {
                    pa += __shfl_xor(pa, off);
                    pb += __shfl_xor(pb, off);
                }
                if (lane == 0) { poolA[node] = pa; poolB[node] = pb; }
            }
        } else {
            float a0 = 0.f;
            for (int j = 0; j < deg; ++j) {
                int s = csr_src[beg + j];
                float a = asv[s] + advv;
                a = (a >= 0.f) ? a : 0.2f * a;
                a0 = fmaf(h[(size_t)s * D + lane], expf(a) * inv, a0);
            }
            a0 = fmaf(h[(size_t)node * D + lane], ev_self * inv, a0);
            out[(size_t)node * D + lane] = fmaxf(a0 + bias[lane], 0.f);
        }
    }
}

// ---------------- pooling score via CSR (original edges; no self-loops here) ----------------
__global__ __launch_bounds__(256) void score_csr(
    const int* __restrict__ row_start, const int* __restrict__ csr_src,
    const float* __restrict__ ts, const float* __restrict__ td,
    const float* __restrict__ bp, float* __restrict__ score, int n)
{
    int i = blockIdx.x * 256 + threadIdx.x;
    if (i >= n) return;
    int beg = row_start[i], end = row_start[i + 1];
    float s = td[i] + bp[0];
    for (int j = beg; j < end; ++j) s += ts[csr_src[j]];
    score[i] = s;
}

// ---------------- precompute: va_l = W_l @ a; pad Wl/bl; zero deg ----------------
__global__ __launch_bounds__(256) void precompute(
    const float* __restrict__ W1, const float* __restrict__ a1s, const float* __restrict__ a1d,
    const float* __restrict__ W2, const float* __restrict__ a2s, const float* __restrict__ a2d,
    const float* __restrict__ W3, const float* __restrict__ a3s, const float* __restrict__ a3d,
    const float* __restrict__ Wl, const float* __restrict__ bl,
    float* __restrict__ va1, float* __restrict__ vb1,
    float* __restrict__ va2, float* __restrict__ vb2,
    float* __restrict__ va3, float* __restrict__ vb3,
    float* __restrict__ Wlp, float* __restrict__ blp,
    int* __restrict__ deg, int n)
{
    int t = blockIdx.x * 256 + threadIdx.x;
    if (t < n) deg[t] = 0;
    if (t < 128) {
        float sa = 0.f, sb = 0.f;
        for (int j = 0; j < 64; ++j) {
            float w = W1[t * 64 + j];
            sa = fmaf(w, a1s[j], sa); sb = fmaf(w, a1d[j], sb);
        }
        va1[t] = sa; vb1[t] = sb;
    } else if (t < 192) {
        int k = t - 128;
        float sa = 0.f, sb = 0.f;
        for (int j = 0; j < 128; ++j) {
            float w = W2[k * 128 + j];
            sa = fmaf(w, a2s[j], sa); sb = fmaf(w, a2d[j], sb);
        }
        va2[k] = sa; vb2[k] = sb;
    } else if (t < 320) {
        int k = t - 192;
        float sa = 0.f, sb = 0.f;
        for (int j = 0; j < 128; ++j) {
            float w = W3[k * 128 + j];
            sa = fmaf(w, a3s[j], sa); sb = fmaf(w, a3d[j], sb);
        }
        va3[k] = sa; vb3[k] = sb;
    } else if (t < 320 + 2048) {
        int i = t - 320;
        int k = i >> 4, c = i & 15;
        Wlp[i] = (c < 10) ? Wl[k * 10 + c] : 0.f;
    } else if (t < 320 + 2048 + 16) {
        int c = t - (320 + 2048);
        blp[c] = (c < 10) ? bl[c] : 0.f;
    }
}

extern "C" void kernel_launch(void* const* d_in, const int* in_sizes, int n_in,
                              void* d_out, int out_size, void* d_ws, size_t ws_size,
                              hipStream_t stream) {
    const float* x   = (const float*)d_in[0];
    const int*   ei  = (const int*)d_in[1];
    const float* W1  = (const float*)d_in[4];
    const float* a1s = (const float*)d_in[5];
    const float* a1d = (const float*)d_in[6];
    const float* b1  = (const float*)d_in[7];
    const float* W2  = (const float*)d_in[8];
    const float* a2s = (const float*)d_in[9];
    const float* a2d = (const float*)d_in[10];
    const float* b2  = (const float*)d_in[11];
    const float* W3  = (const float*)d_in[12];
    const float* a3s = (const float*)d_in[13];
    const float* a3d = (const float*)d_in[14];
    const float* b3  = (const float*)d_in[15];
    const float* wpr = (const float*)d_in[16];
    const float* wpo = (const float*)d_in[17];
    const float* bp  = (const float*)d_in[18];
    const float* Wl  = (const float*)d_in[19];
    const float* bl  = (const float*)d_in[20];

    const int n = in_sizes[0] / 128;   // 40000
    const int E = in_sizes[1] / 2;     // 640000
    const int* src = ei;
    const int* dst = ei + E;

    float* ws = (float*)d_ws;
    const size_t nd = (size_t)n * 128;
    float* bufA      = ws;                          // [n,128]
    float* bufB      = bufA + nd;                   // [n,128]
    float* asv       = bufB + nd;                   // [n]
    float* adv       = asv + n;                     // [n]
    float* tsv       = adv + n;                     // [n]
    float* tdv       = tsv + n;                     // [n]
    float* score     = tdv + n;                     // [n]
    int*   deg       = (int*)(score + n);           // [n]
    int*   row_start = deg + n;                     // [n+1]
    int*   cursor    = row_start + n + 1;           // [n]
    int*   blocksum  = cursor + n;                  // [<=256]
    int*   csr_src   = blocksum + 256;              // [E]
    float* va1       = (float*)(csr_src + E);       // [128]
    float* vb1       = va1 + 128;                   // [128]
    float* va2       = vb1 + 128;                   // [64]
    float* vb2       = va2 + 64;                    // [64]
    float* va3       = vb2 + 64;                    // [128]
    float* vb3       = va3 + 128;                   // [128]
    float* Wlp       = vb3 + 128;                   // [128*16]
    float* blp       = Wlp + 128 * 16;              // [16]

    const unsigned EB = (unsigned)((E + 255) / 256);
    const unsigned NB = (unsigned)((n + 255) / 256);
    const unsigned MB = (unsigned)((n + 63) / 64);   // 625
    const unsigned WB = (unsigned)(((size_t)n * 64 + 255) / 256);

    // ---------- precompute (+deg zero) + CSR build (original edges) ----------
    precompute<<<NB, 256, 0, stream>>>(W1, a1s, a1d, W2, a2s, a2d, W3, a3s, a3d, Wl, bl,
                                       va1, vb1, va2, vb2, va3, vb3, Wlp, blp, deg, n);
    hist_deg<<<EB, 256, 0, stream>>>(dst, deg, E);
    scan_local<<<NB, 256, 0, stream>>>(deg, row_start, blocksum, n);
    scan_blocks<<<1, 256, 0, stream>>>(blocksum, (int)NB);
    scan_add<<<NB, 256, 0, stream>>>(row_start, cursor, blocksum, n, E);
    fill_csr<<<EB, 256, 0, stream>>>(src, dst, cursor, csr_src, E);

    // ---------- Layer 1: 128 -> 64 ----------
    gemm_rt<128, 64, 64><<<dim3(MB, 1), 128, 0, stream>>>(
        x, W1, bufA, n, va1, vb1, asv, adv);
    gat_aggregate<64, false><<<WB, 256, 0, stream>>>(row_start, csr_src, asv, adv, bufA, b1, bufB,
                                                     nullptr, nullptr, nullptr, nullptr, n);

    // ---------- Layer 2: 64 -> 128 ----------
    gemm_rt<64, 128, 64><<<dim3(MB, 2), 128, 0, stream>>>(
        bufB, W2, bufA, n, va2, vb2, asv, adv);
    gat_aggregate<128, false><<<WB, 256, 0, stream>>>(row_start, csr_src, asv, adv, bufA, b2, bufB,
                                                      nullptr, nullptr, nullptr, nullptr, n);

    // ---------- Layer 3: 128 -> 128 ----------
    gemm_rt<128, 128, 64><<<dim3(MB, 2), 128, 0, stream>>>(
        bufB, W3, bufA, n, va3, vb3, asv, adv);
    gat_aggregate<128, true><<<WB, 256, 0, stream>>>(row_start, csr_src, asv, adv, bufA, b3, bufB,
                                                     wpr, wpo, tsv, tdv, n);

    // ---------- SAGPool score + final linear ----------
    score_csr<<<NB, 256, 0, stream>>>(row_start, csr_src, tsv, tdv, bp, score, n);
    gemm_tile<128, 16, 16><<<MB, 256, 0, stream>>>(bufB, Wlp, (float*)d_out, n, blp, score, 10);
}